// Round 4
// baseline (49149.579 us; speedup 1.0000x reference)
//
#include <hip/hip_runtime.h>
#include <math.h>

// DTYPE COMMITMENTS (evidence-backed):
//   inputs  = f32  (round-1 bf16 decode -> NaN; f32 decode -> finite)
//   output  = f32  (round-2 bf16 store read back as f32 garbage ~3.1; harness read path is np.float32)
// WS BUDGET: <= ~210 MB (round-2's 215 MB ran; round-3's 370 MB faulted)

#define T_ 16
#define N_ 64
#define NN_ 32
#define D_ 512
#define H_ 8
#define DK_ 64
#define DFF_ 2048
#define L_ 2
#define NPRED_ 20

__device__ __forceinline__ float ntn(float v) {
    if (isnan(v)) return 0.0f;
    if (isinf(v)) return v > 0.0f ? 3.4028234663852886e38f : -3.4028234663852886e38f;
    return v;
}

// ---------------- positional encoding ------------------------------------------------
__global__ void pe_kernel(float* pe) {
    int i = blockIdx.x * blockDim.x + threadIdx.x;
    if (i >= T_ * 256) return;
    int t = i >> 8, j = i & 255;
    float dv = (float)pow(10000.0, (double)j / 256.0);
    float a = (float)t * dv;               // f32 argument, like np
    double ad = (double)a;
    pe[t * D_ + 2 * j]     = (float)sin(ad);
    pe[t * D_ + 2 * j + 1] = (float)cos(ad);
}

// ---------------- x features + embed (xemb[n][t][d]) ---------------------------------
__global__ void xemb_kernel(const float* x, const float* Wx, const float* bx,
                            const float* pe, float* xemb) {
    int row = blockIdx.x;              // t*N + n
    int t = row / N_, n = row % N_;
    float x0 = x[row * 6 + 0], x1 = x[row * 6 + 1];
    float x2 = x[row * 6 + 2], x3 = x[row * 6 + 3];
    float x4 = x[row * 6 + 4], x5 = x[row * 6 + 5];
    float vel = sqrtf(x2 * x2 + x3 * x3);
    float ang = atanf(x5 / x4);
    float f0 = ntn(x0), f1 = ntn(x1), f2 = ntn(vel), f3 = ntn(ang);
    for (int d = threadIdx.x; d < D_; d += blockDim.x) {
        xemb[((size_t)n * T_ + t) * D_ + d] =
            f0 * Wx[0 * D_ + d] + f1 * Wx[1 * D_ + d]
          + f2 * Wx[2 * D_ + d] + f3 * Wx[3 * D_ + d]
          + bx[d] + pe[t * D_ + d];
    }
}

// ---------------- neighbor features + mask -------------------------------------------
__global__ void nbr_kernel(const float* x, const float* nbr, float* nf, float* maskf) {
    int idx = blockIdx.x * blockDim.x + threadIdx.x;   // t*N*NN + n*NN + m
    if (idx >= T_ * N_ * NN_) return;
    int m = idx % NN_;
    int tn = idx / NN_;
    int n = tn % N_, t = tn / N_;
    float px = x[((size_t)t * N_ + n) * 6 + 0];
    float py = x[((size_t)t * N_ + n) * 6 + 1];
    float vx, vy;
    if (t == 0) {
        vx = x[((size_t)1 * N_ + n) * 6 + 2];   // v[0] = x[1,:,2:4]
        vy = x[((size_t)1 * N_ + n) * 6 + 3];
    } else {
        vx = px - x[((size_t)(t - 1) * N_ + n) * 6 + 0];
        vy = py - x[((size_t)(t - 1) * N_ + n) * 6 + 1];
    }
    float nx  = nbr[(size_t)idx * 4 + 0], ny  = nbr[(size_t)idx * 4 + 1];
    float nvx = nbr[(size_t)idx * 4 + 2], nvy = nbr[(size_t)idx * 4 + 3];
    float dpx = nx - px, dpy = ny - py;
    float dvx = nvx - vx, dvy = nvy - vy;
    float dist = sqrtf(dpx * dpx + dpy * dpy);
    maskf[((size_t)n * NN_ + m) * T_ + t] = (dist <= 2.0f) ? 1.0f : 0.0f;
    float vn = sqrtf(vx * vx + vy * vy);
    float bearing = (dpx * vx + dpy * vy) / (dist * vn);
    if (isnan(bearing)) bearing = 0.0f;
    float dvn = sqrtf(dvx * dvx + dvy * dvy);
    float tau = -(dpx * dvx + dpy * dvy) / dvn;
    if (isnan(tau)) tau = 0.0f;
    tau = fminf(fmaxf(tau, 0.0f), 7.0f);
    float mx_ = dpx + tau * dvx, my_ = dpy + tau * dvy;
    float mpd = sqrtf(mx_ * mx_ + my_ * my_);
    nf[(size_t)idx * 3 + 0] = ntn(dist);
    nf[(size_t)idx * 3 + 1] = ntn(bearing);
    nf[(size_t)idx * 3 + 2] = ntn(mpd);
}

// ---------------- neighbor embed (A[bm][t][d], bm = b*NN+m) --------------------------
__global__ void nemb_kernel(const float* nf, const float* Wn, const float* bn,
                            const float* pe, float* nemb) {
    int row = blockIdx.x;              // (b*NN+m)*T + t
    int t = row % T_;
    int bm = row / T_;
    int m = bm % NN_, b = bm / NN_;
    size_t nfrow = (((size_t)t * N_ + b) * NN_ + m) * 3;
    float f0 = nf[nfrow], f1 = nf[nfrow + 1], f2 = nf[nfrow + 2];
    for (int d = threadIdx.x; d < D_; d += blockDim.x) {
        nemb[(size_t)row * D_ + d] =
            f0 * Wn[d] + f1 * Wn[D_ + d] + f2 * Wn[2 * D_ + d] + bn[d] + pe[t * D_ + d];
    }
}

// ---------------- per-head attention stages (naive, deterministic) -------------------
// qh[bm][t][dk] = sum_j A[bm][t][j] * W[j][h*64+dk]
__global__ void qkv_h_kernel(const float* A, const float* W, int h, float* out) {
    int bm = blockIdx.x;
    int tid = threadIdx.x;
    for (int rep = 0; rep < 4; ++rep) {
        int i = rep * 256 + tid;          // 0..1023
        int t = i >> 6, dk = i & 63;
        const float* a = A + ((size_t)bm * T_ + t) * D_;
        float acc = 0.f;
        for (int j = 0; j < D_; ++j) acc += a[j] * W[(size_t)j * 512 + h * DK_ + dk];
        out[((size_t)bm * T_ + t) * DK_ + dk] = acc;
    }
}

// sc[bm][q][k] = (qh[bm][q]·kh[bm][k]) * sk, masked on q
__global__ void score_h_kernel(const float* qh, const float* kh, const float* maskf, float* sc) {
    int bm = blockIdx.x;
    int tid = threadIdx.x;               // q*16+k
    int q = tid >> 4, k = tid & 15;
    const float* qr = qh + ((size_t)bm * T_ + q) * DK_;
    const float* kr = kh + ((size_t)bm * T_ + k) * DK_;
    float acc = 0.f;
    for (int j = 0; j < DK_; ++j) acc += qr[j] * kr[j];
    acc *= 0.125f;
    if (maskf[(size_t)bm * T_ + q] == 0.0f) acc = -1e9f;
    sc[(size_t)bm * 256 + tid] = acc;
}

// in-place softmax over rows of 16
__global__ void softmax16_kernel(float* p_, int nrows) {
    int r = blockIdx.x * blockDim.x + threadIdx.x;
    if (r >= nrows) return;
    float* p = p_ + (size_t)r * 16;
    float mx = p[0];
    for (int k = 1; k < 16; ++k) mx = fmaxf(mx, p[k]);
    float e[16], s = 0.f;
    for (int k = 0; k < 16; ++k) { e[k] = expf(p[k] - mx); s += e[k]; }
    float inv = 1.0f / s;
    for (int k = 0; k < 16; ++k) p[k] = e[k] * inv;
}

// att_sum[b][h][qk] = mean_m sc[b*32+m][qk]
__global__ void attsum_h_kernel(const float* sc, int h, float* att_sum) {
    int i = blockIdx.x * blockDim.x + threadIdx.x;   // b*256 + qk
    if (i >= N_ * 256) return;
    int b = i >> 8, qk = i & 255;
    float s = 0.f;
    for (int m = 0; m < NN_; ++m) s += sc[((size_t)(b * NN_ + m)) * 256 + qk];
    att_sum[((size_t)b * H_ + h) * 256 + qk] = s * (1.0f / 32.0f);
}

// ctxh[bm][t][dk] = sum_k sc[bm][t][k] * vh[bm][k][dk]
__global__ void ctx_h_kernel(const float* sc, const float* vh, float* ctxh) {
    int bm = blockIdx.x;
    int tid = threadIdx.x;
    for (int rep = 0; rep < 4; ++rep) {
        int i = rep * 256 + tid;
        int t = i >> 6, dk = i & 63;
        float acc = 0.f;
        for (int k = 0; k < T_; ++k)
            acc += sc[(size_t)bm * 256 + t * 16 + k] * vh[((size_t)bm * T_ + k) * DK_ + dk];
        ctxh[((size_t)bm * T_ + t) * DK_ + dk] = acc;
    }
}

// B[row][d] += ctxh[row]·Wfc[h*64 .. h*64+63][d]   (B pre-seeded with n_emb residual)
__global__ void fcacc_h_kernel(const float* ctxh, const float* Wfc, int h, float* B) {
    size_t i = (size_t)blockIdx.x * 256 + threadIdx.x;   // row*512 + d
    int d = (int)(i & 511);
    size_t row = i >> 9;
    const float* c = ctxh + row * DK_;
    float acc = 0.f;
    for (int j = 0; j < DK_; ++j) acc += c[j] * Wfc[(size_t)(h * DK_ + j) * 512 + d];
    B[i] += acc;
}

// per-row LayerNorm (one thread per row; in-place safe)
__global__ void ln_kernel(const float* X, const float* g, const float* b, float* out, int nrows) {
    int r = blockIdx.x * blockDim.x + threadIdx.x;
    if (r >= nrows) return;
    const float* p = X + (size_t)r * D_;
    float s = 0.f;
    for (int j = 0; j < D_; ++j) s += p[j];
    float mean = s * (1.0f / 512.0f);
    float v = 0.f;
    for (int j = 0; j < D_; ++j) { float d = p[j] - mean; v += d * d; }
    float rstd = rsqrtf(v * (1.0f / 512.0f) + 1e-5f);
    float* o = out + (size_t)r * D_;
    for (int j = 0; j < D_; ++j) o[j] = (p[j] - mean) * rstd * g[j] + b[j];
}

// ---------------- self attention (naive) ---------------------------------------------
__global__ void selfscore_kernel(const float* xemb, float* ss) {
    int i = blockIdx.x * blockDim.x + threadIdx.x;   // n*256 + q*16 + k
    if (i >= N_ * 256) return;
    int n = i >> 8, q = (i >> 4) & 15, k = i & 15;
    const float* a = xemb + ((size_t)n * T_ + q) * D_;
    const float* b = xemb + ((size_t)n * T_ + k) * D_;
    float acc = 0.f;
    for (int j = 0; j < D_; ++j) acc += a[j] * b[j];
    ss[i] = acc * 0.04419417382415922f;
}

__global__ void combine_kernel(const float* ss, const float* att_sum, const float* attf, float* att) {
    int i = blockIdx.x * blockDim.x + threadIdx.x;   // n*2048 + h*256 + qk
    if (i >= N_ * H_ * 256) return;
    int n = i >> 11, qk = i & 255;
    att[i] = ss[n * 256 + qk] + attf[0] * att_sum[i];
}

// si[n*16+q][h*512+d] = sum_t att[n][h][q*16+t] * xemb[n][t][d]
__global__ void si_naive_kernel(const float* att, const float* xemb, float* si) {
    size_t i = (size_t)blockIdx.x * 256 + threadIdx.x;
    int hd = (int)(i & 4095);
    int h = hd >> 9, d = hd & 511;
    size_t nq = i >> 12;
    int n = (int)(nq >> 4), q = (int)(nq & 15);
    float acc = 0.f;
    for (int t = 0; t < T_; ++t)
        acc += att[((size_t)n * H_ + h) * 256 + q * 16 + t] * xemb[((size_t)n * T_ + t) * D_ + d];
    si[i] = acc;
}

// xnew[row][col] = si[row]·WSI[:,col]  (K = 4096)
__global__ void gemm_naive_kernel(const float* A, const float* Bm, float* C) {
    size_t i = (size_t)blockIdx.x * 256 + threadIdx.x;   // row*512 + col
    int col = (int)(i & 511);
    size_t row = i >> 9;
    const float* a = A + row * 4096;
    float acc = 0.f;
    for (int j = 0; j < 4096; ++j) acc += a[j] * Bm[(size_t)j * 512 + col];
    C[i] = acc;
}

// ---------------- FFN stages (naive, row-chunked) ------------------------------------
__global__ void ffn1_kernel(const float* X, const float* w1, float* Hh, int row0, int nrows) {
    size_t i = (size_t)blockIdx.x * 256 + threadIdx.x;   // local r*2048 + f
    if (i >= (size_t)nrows * DFF_) return;
    int f = (int)(i & 2047);
    size_t r = (size_t)row0 + (i >> 11);
    const float* xr = X + r * D_;
    float acc = 0.f;
    for (int j = 0; j < D_; ++j) acc += xr[j] * w1[(size_t)j * DFF_ + f];
    Hh[i] = fmaxf(acc, 0.f);
}

__global__ void ffn2_kernel(const float* Hh, const float* w2, const float* X, float* Y,
                            int row0, int nrows) {
    size_t i = (size_t)blockIdx.x * 256 + threadIdx.x;   // local r*512 + d
    if (i >= (size_t)nrows * D_) return;
    int d = (int)(i & 511);
    size_t rl = i >> 9;
    size_t r = (size_t)row0 + rl;
    const float* hr = Hh + rl * DFF_;
    float acc = 0.f;
    for (int j = 0; j < DFF_; ++j) acc += hr[j] * w2[(size_t)j * D_ + d];
    Y[r * D_ + d] = acc + X[r * D_ + d];
}

// ---------------- prediction head + broadcast (f32 out) ------------------------------
__global__ void pred_kernel(const float* xemb, const float* Wp, const float* bp, float* o) {
    int idx = blockIdx.x * blockDim.x + threadIdx.x;
    if (idx >= N_ * T_ * 2) return;
    int c = idx & 1;
    int nt = idx >> 1;
    float acc = bp[c];
    for (int j = 0; j < D_; ++j) acc += xemb[(size_t)nt * D_ + j] * Wp[(size_t)j * 2 + c];
    o[idx] = acc;
}

__global__ void bcast_kernel(const float* o, float* out) {
    int idx = blockIdx.x * blockDim.x + threadIdx.x;   // ((p*T+t)*N+n)*2+c
    if (idx >= NPRED_ * T_ * N_ * 2) return;
    int c = idx & 1;
    int rest = idx >> 1;
    int n = rest % N_;
    rest /= N_;
    int t = rest % T_;
    out[idx] = o[((size_t)n * T_ + t) * 2 + c];
}

extern "C" void kernel_launch(void* const* d_in, const int* in_sizes, int n_in,
                              void* d_out, int out_size, void* d_ws, size_t ws_size,
                              hipStream_t stream) {
    (void)in_sizes; (void)n_in; (void)out_size; (void)ws_size;

    const float* x    = (const float*)d_in[0];
    const float* nbr  = (const float*)d_in[1];
    const float* attf = (const float*)d_in[2];
    const float* Wx   = (const float*)d_in[3];
    const float* bx   = (const float*)d_in[4];
    const float* Wn   = (const float*)d_in[5];
    const float* bn   = (const float*)d_in[6];
    const float* Wp   = (const float*)d_in[7];
    const float* bp   = (const float*)d_in[8];
    const float* WQ   = (const float*)d_in[9];
    const float* WK   = (const float*)d_in[10];
    const float* WV   = (const float*)d_in[11];
    const float* Wfc  = (const float*)d_in[12];
    const float* mlng = (const float*)d_in[13];
    const float* mlnb = (const float*)d_in[14];
    const float* WSI  = (const float*)d_in[15];
    const float* fsw1 = (const float*)d_in[16];
    const float* fsw2 = (const float*)d_in[17];
    const float* fsg  = (const float*)d_in[18];
    const float* fsb  = (const float*)d_in[19];
    const float* fiw1 = (const float*)d_in[20];
    const float* fiw2 = (const float*)d_in[21];
    const float* fig  = (const float*)d_in[22];
    const float* fib  = (const float*)d_in[23];

    char* w = (char*)d_ws;
    size_t off = 0;
    auto alloc = [&](size_t bytes) -> void* {
        void* p = w + off;
        off = (off + bytes + 255) & ~(size_t)255;
        return p;
    };

    const int BM = N_ * NN_;          // 2048 (b,m) blocks
    const int ROWS_I = BM * T_;       // 32768 neighbor-stream rows
    const int CH = 2048;              // ffi hidden chunk rows

    float* pe      = (float*)alloc((size_t)T_ * D_ * 4);
    float* xemb    = (float*)alloc((size_t)N_ * T_ * D_ * 4);
    float* nf      = (float*)alloc((size_t)T_ * N_ * NN_ * 3 * 4);
    float* maskf   = (float*)alloc((size_t)N_ * NN_ * T_ * 4);
    float* A       = (float*)alloc((size_t)ROWS_I * D_ * 4);     // n_emb         64 MB
    float* B       = (float*)alloc((size_t)ROWS_I * D_ * 4);     // res_inter     64 MB
    float* qh      = (float*)alloc((size_t)ROWS_I * DK_ * 4);    //                8 MB
    float* kh      = (float*)alloc((size_t)ROWS_I * DK_ * 4);
    float* vh      = (float*)alloc((size_t)ROWS_I * DK_ * 4);
    float* ctxh    = (float*)alloc((size_t)ROWS_I * DK_ * 4);
    float* sc      = (float*)alloc((size_t)BM * 256 * 4);        //                2 MB
    float* att_sum = (float*)alloc((size_t)N_ * H_ * 256 * 4);
    float* ss      = (float*)alloc((size_t)N_ * 256 * 4);
    float* att     = (float*)alloc((size_t)N_ * H_ * 256 * 4);
    float* si      = (float*)alloc((size_t)N_ * T_ * 4096 * 4);  //               16 MB
    float* xnew    = (float*)alloc((size_t)N_ * T_ * D_ * 4);
    float* hidden  = (float*)alloc((size_t)CH * DFF_ * 4);       //               16 MB
    float* osm     = (float*)alloc((size_t)N_ * T_ * 2 * 4);
    // total ~ 209 MB, within the proven-safe ws region

    pe_kernel<<<16, 256, 0, stream>>>(pe);
    xemb_kernel<<<T_ * N_, 256, 0, stream>>>(x, Wx, bx, pe, xemb);
    nbr_kernel<<<(T_ * N_ * NN_ + 255) / 256, 256, 0, stream>>>(x, nbr, nf, maskf);
    nemb_kernel<<<N_ * NN_ * T_, 256, 0, stream>>>(nf, Wn, bn, pe, A);

    for (int l = 0; l < L_; ++l) {
        const float* WQl  = WQ  + (size_t)l * D_ * 512;
        const float* WKl  = WK  + (size_t)l * D_ * 512;
        const float* WVl  = WV  + (size_t)l * D_ * 512;
        const float* Wfcl = Wfc + (size_t)l * 512 * D_;
        const float* WSIl = WSI + (size_t)l * H_ * D_ * D_;

        // seed B with the residual (n_emb); heads accumulate fc contributions into it
        hipMemcpyAsync(B, A, (size_t)ROWS_I * D_ * 4, hipMemcpyDeviceToDevice, stream);

        for (int h = 0; h < H_; ++h) {
            qkv_h_kernel<<<BM, 256, 0, stream>>>(A, WQl, h, qh);
            qkv_h_kernel<<<BM, 256, 0, stream>>>(A, WKl, h, kh);
            qkv_h_kernel<<<BM, 256, 0, stream>>>(A, WVl, h, vh);
            score_h_kernel<<<BM, 256, 0, stream>>>(qh, kh, maskf, sc);
            softmax16_kernel<<<(BM * T_ + 255) / 256, 256, 0, stream>>>(sc, BM * T_);
            attsum_h_kernel<<<(N_ * 256 + 255) / 256, 256, 0, stream>>>(sc, h, att_sum);
            ctx_h_kernel<<<BM, 256, 0, stream>>>(sc, vh, ctxh);
            fcacc_h_kernel<<<(int)(((size_t)ROWS_I * D_) / 256), 256, 0, stream>>>(
                ctxh, Wfcl, h, B);
        }
        ln_kernel<<<(ROWS_I + 255) / 256, 256, 0, stream>>>(
            B, mlng + l * D_, mlnb + l * D_, B, ROWS_I);    // B = res_inter

        selfscore_kernel<<<(N_ * 256 + 255) / 256, 256, 0, stream>>>(xemb, ss);
        softmax16_kernel<<<(N_ * T_ + 255) / 256, 256, 0, stream>>>(ss, N_ * T_);
        combine_kernel<<<(N_ * H_ * 256 + 255) / 256, 256, 0, stream>>>(ss, att_sum, attf, att);
        si_naive_kernel<<<(int)(((size_t)N_ * T_ * 4096) / 256), 256, 0, stream>>>(att, xemb, si);
        gemm_naive_kernel<<<(int)(((size_t)N_ * T_ * D_) / 256), 256, 0, stream>>>(si, WSIl, xnew);

        // ffs: xemb = LN(relu(xnew@w1)@w2 + xnew)
        ffn1_kernel<<<(int)(((size_t)N_ * T_ * DFF_) / 256), 256, 0, stream>>>(
            xnew, fsw1 + (size_t)l * D_ * DFF_, hidden, 0, N_ * T_);
        ffn2_kernel<<<(int)(((size_t)N_ * T_ * D_) / 256), 256, 0, stream>>>(
            hidden, fsw2 + (size_t)l * DFF_ * D_, xnew, xemb, 0, N_ * T_);
        ln_kernel<<<(N_ * T_ + 255) / 256, 256, 0, stream>>>(
            xemb, fsg + l * D_, fsb + l * D_, xemb, N_ * T_);

        // ffi: A = LN(relu(B@w1)@w2 + B), chunked hidden
        for (int c = 0; c < ROWS_I / CH; ++c) {
            ffn1_kernel<<<(int)(((size_t)CH * DFF_) / 256), 256, 0, stream>>>(
                B, fiw1 + (size_t)l * D_ * DFF_, hidden, c * CH, CH);
            ffn2_kernel<<<(int)(((size_t)CH * D_) / 256), 256, 0, stream>>>(
                hidden, fiw2 + (size_t)l * DFF_ * D_, B, A, c * CH, CH);
        }
        ln_kernel<<<(ROWS_I + 255) / 256, 256, 0, stream>>>(
            A, fig + l * D_, fib + l * D_, A, ROWS_I);
    }

    pred_kernel<<<(N_ * T_ * 2 + 255) / 256, 256, 0, stream>>>(xemb, Wp, bp, osm);
    bcast_kernel<<<(NPRED_ * T_ * N_ * 2 + 255) / 256, 256, 0, stream>>>(osm, (float*)d_out);
}

// Round 5
// 2023.774 us; speedup vs baseline: 24.2861x; 24.2861x over previous
//
#include <hip/hip_runtime.h>
#include <math.h>

// DTYPE COMMITMENTS (evidence-backed): inputs f32, output f32 (round-4 PASS).
// WS BUDGET: <= ~210 MB (215 ran, 370 faulted). This version uses ~186 MB.

#define T_ 16
#define N_ 64
#define NN_ 32
#define D_ 512
#define H_ 8
#define DK_ 64
#define DFF_ 2048
#define L_ 2
#define NPRED_ 20

typedef unsigned short u16;
typedef unsigned int u32;
typedef __attribute__((ext_vector_type(8))) short short8;
typedef __attribute__((ext_vector_type(4))) float f32x4;

__device__ __forceinline__ u16 f2bf(float f) {
    u32 u = __float_as_uint(f);
    u32 r = u + 0x7fffu + ((u >> 16) & 1u);
    return (u16)(r >> 16);
}
__device__ __forceinline__ float bfv(u16 v) {
    return __uint_as_float(((u32)v) << 16);
}
__device__ __forceinline__ float ntn(float v) {
    if (isnan(v)) return 0.0f;
    if (isinf(v)) return v > 0.0f ? 3.4028234663852886e38f : -3.4028234663852886e38f;
    return v;
}
__device__ __forceinline__ float wave_sum(float v) {
    #pragma unroll
    for (int o = 32; o > 0; o >>= 1) v += __shfl_xor(v, o, 64);
    return v;
}

// ============ MFMA GEMM: C[M x N] = A[M x K] @ B[K x N] (+res / relu) ===============
// 64x64 tile, 4 waves, each wave a 32x32 quadrant (2x2 mfma_f32_16x16x32_bf16).
// A: f32 or bf16 (A_BF16). B: f32 weights, converted to bf16 at staging.
// EPI: 0 none, 1 relu, 2 +residual(f32). OUT_BF16: write bf16 or f32.
// M, N divisible by 64; K divisible by 32.
template<int A_BF16, int EPI, int OUT_BF16>
__global__ __launch_bounds__(256) void mfma_gemm(
    const void* __restrict__ Ag, const float* __restrict__ Bg,
    void* __restrict__ Cg, const float* __restrict__ Rg,
    int K, int lda, int ldb, int ldc)
{
    // pad to 40 shorts (80B rows, 16B-aligned): frag reads stride 20 dw -> 2-way (free)
    __shared__ __align__(16) u16 As[64][40];
    __shared__ __align__(16) u16 Bs[64][40];   // stored transposed: Bs[n][k]
    int tid = threadIdx.x;
    int lane = tid & 63;
    int quad = lane >> 4, l16 = lane & 15;
    int wave = tid >> 6;
    int wm = (wave >> 1) * 32, wn = (wave & 1) * 32;
    size_t row0 = (size_t)blockIdx.y * 64;
    size_t col0 = (size_t)blockIdx.x * 64;

    f32x4 acc[2][2] = {{{0.f,0.f,0.f,0.f},{0.f,0.f,0.f,0.f}},
                       {{0.f,0.f,0.f,0.f},{0.f,0.f,0.f,0.f}}};

    int am = tid >> 2, ak = (tid & 3) * 8;       // A: 64 rows x 32 k, 8/thread
    int bn = tid & 63, bk0 = (tid >> 6) * 8;     // B: 64 n x 32 k, 8 k-consecutive/thread

    for (int k0 = 0; k0 < K; k0 += 32) {
        if (A_BF16) {
            const u16* Ab = (const u16*)Ag;
            uint4 v = *(const uint4*)(Ab + (row0 + am) * (size_t)lda + k0 + ak);
            *(uint4*)&As[am][ak] = v;
        } else {
            const float* Af = (const float*)Ag;
            const float* p = Af + (row0 + am) * (size_t)lda + k0 + ak;
            float4 v0 = *(const float4*)p;
            float4 v1 = *(const float4*)(p + 4);
            u16 tmp[8] = {f2bf(v0.x), f2bf(v0.y), f2bf(v0.z), f2bf(v0.w),
                          f2bf(v1.x), f2bf(v1.y), f2bf(v1.z), f2bf(v1.w)};
            *(uint4*)&As[am][ak] = *(uint4*)tmp;
        }
        {
            // 8 coalesced dword loads (lane-contiguous in n), one b128 LDS write
            u16 tmp[8];
            #pragma unroll
            for (int j = 0; j < 8; ++j)
                tmp[j] = f2bf(Bg[(size_t)(k0 + bk0 + j) * ldb + col0 + bn]);
            *(uint4*)&Bs[bn][bk0] = *(uint4*)tmp;
        }
        __syncthreads();
        short8 af0 = *(short8*)&As[wm + l16][quad * 8];
        short8 af1 = *(short8*)&As[wm + 16 + l16][quad * 8];
        short8 bf0 = *(short8*)&Bs[wn + l16][quad * 8];
        short8 bf1 = *(short8*)&Bs[wn + 16 + l16][quad * 8];
        acc[0][0] = __builtin_amdgcn_mfma_f32_16x16x32_bf16(af0, bf0, acc[0][0], 0, 0, 0);
        acc[0][1] = __builtin_amdgcn_mfma_f32_16x16x32_bf16(af0, bf1, acc[0][1], 0, 0, 0);
        acc[1][0] = __builtin_amdgcn_mfma_f32_16x16x32_bf16(af1, bf0, acc[1][0], 0, 0, 0);
        acc[1][1] = __builtin_amdgcn_mfma_f32_16x16x32_bf16(af1, bf1, acc[1][1], 0, 0, 0);
        __syncthreads();
    }
    // C/D layout (m89-verified): col = lane&15, row = quad*4 + reg
    #pragma unroll
    for (int i = 0; i < 2; ++i)
        #pragma unroll
        for (int j = 0; j < 2; ++j)
            #pragma unroll
            for (int reg = 0; reg < 4; ++reg) {
                size_t row = row0 + wm + i * 16 + quad * 4 + reg;
                size_t col = col0 + wn + j * 16 + l16;
                float v = acc[i][j][reg];
                if (EPI == 2) v += Rg[row * (size_t)ldc + col];
                if (EPI == 1) v = fmaxf(v, 0.f);
                if (OUT_BF16) ((u16*)Cg)[row * (size_t)ldc + col] = f2bf(v);
                else          ((float*)Cg)[row * (size_t)ldc + col] = v;
            }
}

// ---------------- positional encoding ------------------------------------------------
__global__ void pe_kernel(float* pe) {
    int i = blockIdx.x * blockDim.x + threadIdx.x;
    if (i >= T_ * 256) return;
    int t = i >> 8, j = i & 255;
    float dv = (float)pow(10000.0, (double)j / 256.0);
    float a = (float)t * dv;
    double ad = (double)a;
    pe[t * D_ + 2 * j]     = (float)sin(ad);
    pe[t * D_ + 2 * j + 1] = (float)cos(ad);
}

// ---------------- x features + embed -------------------------------------------------
__global__ void xemb_kernel(const float* x, const float* Wx, const float* bx,
                            const float* pe, float* xemb) {
    int row = blockIdx.x;              // t*N + n
    int t = row / N_, n = row % N_;
    float x0 = x[row * 6 + 0], x1 = x[row * 6 + 1];
    float x2 = x[row * 6 + 2], x3 = x[row * 6 + 3];
    float x4 = x[row * 6 + 4], x5 = x[row * 6 + 5];
    float vel = sqrtf(x2 * x2 + x3 * x3);
    float ang = atanf(x5 / x4);
    float f0 = ntn(x0), f1 = ntn(x1), f2 = ntn(vel), f3 = ntn(ang);
    for (int d = threadIdx.x; d < D_; d += blockDim.x) {
        xemb[((size_t)n * T_ + t) * D_ + d] =
            f0 * Wx[0 * D_ + d] + f1 * Wx[1 * D_ + d]
          + f2 * Wx[2 * D_ + d] + f3 * Wx[3 * D_ + d]
          + bx[d] + pe[t * D_ + d];
    }
}

// ---------------- neighbor features + mask -------------------------------------------
__global__ void nbr_kernel(const float* x, const float* nbr, float* nf, float* maskf) {
    int idx = blockIdx.x * blockDim.x + threadIdx.x;   // t*N*NN + n*NN + m
    if (idx >= T_ * N_ * NN_) return;
    int m = idx % NN_;
    int tn = idx / NN_;
    int n = tn % N_, t = tn / N_;
    float px = x[((size_t)t * N_ + n) * 6 + 0];
    float py = x[((size_t)t * N_ + n) * 6 + 1];
    float vx, vy;
    if (t == 0) {
        vx = x[((size_t)1 * N_ + n) * 6 + 2];
        vy = x[((size_t)1 * N_ + n) * 6 + 3];
    } else {
        vx = px - x[((size_t)(t - 1) * N_ + n) * 6 + 0];
        vy = py - x[((size_t)(t - 1) * N_ + n) * 6 + 1];
    }
    float nx  = nbr[(size_t)idx * 4 + 0], ny  = nbr[(size_t)idx * 4 + 1];
    float nvx = nbr[(size_t)idx * 4 + 2], nvy = nbr[(size_t)idx * 4 + 3];
    float dpx = nx - px, dpy = ny - py;
    float dvx = nvx - vx, dvy = nvy - vy;
    float dist = sqrtf(dpx * dpx + dpy * dpy);
    maskf[((size_t)n * NN_ + m) * T_ + t] = (dist <= 2.0f) ? 1.0f : 0.0f;
    float vn = sqrtf(vx * vx + vy * vy);
    float bearing = (dpx * vx + dpy * vy) / (dist * vn);
    if (isnan(bearing)) bearing = 0.0f;
    float dvn = sqrtf(dvx * dvx + dvy * dvy);
    float tau = -(dpx * dvx + dpy * dvy) / dvn;
    if (isnan(tau)) tau = 0.0f;
    tau = fminf(fmaxf(tau, 0.0f), 7.0f);
    float mx_ = dpx + tau * dvx, my_ = dpy + tau * dvy;
    float mpd = sqrtf(mx_ * mx_ + my_ * my_);
    nf[(size_t)idx * 3 + 0] = ntn(dist);
    nf[(size_t)idx * 3 + 1] = ntn(bearing);
    nf[(size_t)idx * 3 + 2] = ntn(mpd);
}

// ---------------- neighbor embed -----------------------------------------------------
__global__ void nemb_kernel(const float* nf, const float* Wn, const float* bn,
                            const float* pe, float* nemb) {
    int row = blockIdx.x;              // (b*NN+m)*T + t
    int t = row % T_;
    int bm = row / T_;
    int m = bm % NN_, b = bm / NN_;
    size_t nfrow = (((size_t)t * N_ + b) * NN_ + m) * 3;
    float f0 = nf[nfrow], f1 = nf[nfrow + 1], f2 = nf[nfrow + 2];
    for (int d = threadIdx.x; d < D_; d += blockDim.x) {
        nemb[(size_t)row * D_ + d] =
            f0 * Wn[d] + f1 * Wn[D_ + d] + f2 * Wn[2 * D_ + d] + bn[d] + pe[t * D_ + d];
    }
}

// ---------------- scores from bf16 Q,K (chunk-local) ---------------------------------
__global__ void score_b_kernel(const u16* Qb, const u16* Kb, const float* maskf,
                               int bm0, float* sc) {
    int bx = blockIdx.x;            // bm_local*8 + h
    int bm_l = bx >> 3, h = bx & 7;
    int tid = threadIdx.x;          // q*16 + k
    int q = tid >> 4, k = tid & 15;
    const u16* qr = Qb + ((size_t)bm_l * T_ + q) * D_ + h * DK_;
    const u16* kr = Kb + ((size_t)bm_l * T_ + k) * D_ + h * DK_;
    float acc = 0.f;
    #pragma unroll
    for (int j = 0; j < DK_; ++j) acc += bfv(qr[j]) * bfv(kr[j]);
    acc *= 0.125f;
    if (maskf[(size_t)(bm0 + bm_l) * T_ + q] == 0.0f) acc = -1e9f;
    sc[(size_t)bx * 256 + tid] = acc;
}

// in-place softmax over rows of 16
__global__ void softmax16_kernel(float* p_, int nrows) {
    int r = blockIdx.x * blockDim.x + threadIdx.x;
    if (r >= nrows) return;
    float* p = p_ + (size_t)r * 16;
    float mx = p[0];
    for (int k = 1; k < 16; ++k) mx = fmaxf(mx, p[k]);
    float e[16], s = 0.f;
    for (int k = 0; k < 16; ++k) { e[k] = expf(p[k] - mx); s += e[k]; }
    float inv = 1.0f / s;
    for (int k = 0; k < 16; ++k) p[k] = e[k] * inv;
}

// att_sum[b][h][qk] = mean_m sc[(bm_l*8+h)][qk], 16 b's per chunk
__global__ void attsum_b_kernel(const float* sc, int b0, float* att_sum) {
    int i = blockIdx.x * blockDim.x + threadIdx.x;   // b_l*2048 + h*256 + qk
    if (i >= 16 * H_ * 256) return;
    int b_l = i >> 11;
    int h = (i >> 8) & 7, qk = i & 255;
    float s = 0.f;
    for (int m = 0; m < NN_; ++m)
        s += sc[((size_t)((b_l * NN_ + m) * H_ + h)) * 256 + qk];
    att_sum[((size_t)(b0 + b_l) * H_ + h) * 256 + qk] = s * (1.0f / 32.0f);
}

// ctx[bm_l*16+t][h*64+dk] = sum_k sc[bm_l,h][t][k] * V[bm_l*16+k][h*64+dk]  (bf16 out)
__global__ void ctx_b_kernel(const float* sc, const u16* Vb, u16* ctxb) {
    int bx = blockIdx.x;            // bm_l*8 + h
    int bm_l = bx >> 3, h = bx & 7;
    int tid = threadIdx.x;
    #pragma unroll
    for (int rep = 0; rep < 4; ++rep) {
        int i = rep * 256 + tid;
        int t = i >> 6, dk = i & 63;
        float acc = 0.f;
        #pragma unroll
        for (int k = 0; k < T_; ++k)
            acc += sc[(size_t)bx * 256 + t * 16 + k]
                 * bfv(Vb[((size_t)bm_l * T_ + k) * D_ + h * DK_ + dk]);
        ctxb[((size_t)bm_l * T_ + t) * D_ + h * DK_ + dk] = f2bf(acc);
    }
}

// ---------------- LayerNorm, one wave per row ----------------------------------------
__global__ __launch_bounds__(256) void ln_fast_kernel(
    const float* X, const float* g, const float* b, float* out, int nrows) {
    int row = blockIdx.x * 4 + (threadIdx.x >> 6);
    if (row >= nrows) return;
    int lane = threadIdx.x & 63;
    const float* p = X + (size_t)row * D_;
    float v[8];
    float s = 0.f;
    #pragma unroll
    for (int r = 0; r < 8; ++r) { v[r] = p[lane + r * 64]; s += v[r]; }
    s = wave_sum(s);
    float mean = s * (1.0f / 512.0f);
    float vs = 0.f;
    #pragma unroll
    for (int r = 0; r < 8; ++r) { float d = v[r] - mean; vs += d * d; }
    vs = wave_sum(vs);
    float rstd = rsqrtf(vs * (1.0f / 512.0f) + 1e-5f);
    float* o = out + (size_t)row * D_;
    #pragma unroll
    for (int r = 0; r < 8; ++r) {
        int d = lane + r * 64;
        o[d] = (v[r] - mean) * rstd * g[d] + b[d];
    }
}

// ---------------- self attention (naive, proven) -------------------------------------
__global__ void selfscore_kernel(const float* xemb, float* ss) {
    int i = blockIdx.x * blockDim.x + threadIdx.x;   // n*256 + q*16 + k
    if (i >= N_ * 256) return;
    int n = i >> 8, q = (i >> 4) & 15, k = i & 15;
    const float* a = xemb + ((size_t)n * T_ + q) * D_;
    const float* b = xemb + ((size_t)n * T_ + k) * D_;
    float acc = 0.f;
    for (int j = 0; j < D_; ++j) acc += a[j] * b[j];
    ss[i] = acc * 0.04419417382415922f;
}

__global__ void combine_kernel(const float* ss, const float* att_sum, const float* attf, float* att) {
    int i = blockIdx.x * blockDim.x + threadIdx.x;   // n*2048 + h*256 + qk
    if (i >= N_ * H_ * 256) return;
    int n = i >> 11, qk = i & 255;
    att[i] = ss[n * 256 + qk] + attf[0] * att_sum[i];
}

// si[n*16+q][h*512+d] = sum_t att[n][h][q*16+t] * xemb[n][t][d]
__global__ void si_naive_kernel(const float* att, const float* xemb, float* si) {
    size_t i = (size_t)blockIdx.x * 256 + threadIdx.x;
    int hd = (int)(i & 4095);
    int h = hd >> 9, d = hd & 511;
    size_t nq = i >> 12;
    int n = (int)(nq >> 4), q = (int)(nq & 15);
    float acc = 0.f;
    #pragma unroll
    for (int t = 0; t < T_; ++t)
        acc += att[((size_t)n * H_ + h) * 256 + q * 16 + t] * xemb[((size_t)n * T_ + t) * D_ + d];
    si[i] = acc;
}

// ---------------- prediction head + broadcast (f32 out) ------------------------------
__global__ void pred_kernel(const float* xemb, const float* Wp, const float* bp, float* o) {
    int idx = blockIdx.x * blockDim.x + threadIdx.x;
    if (idx >= N_ * T_ * 2) return;
    int c = idx & 1;
    int nt = idx >> 1;
    float acc = bp[c];
    for (int j = 0; j < D_; ++j) acc += xemb[(size_t)nt * D_ + j] * Wp[(size_t)j * 2 + c];
    o[idx] = acc;
}

__global__ void bcast_kernel(const float* o, float* out) {
    int idx = blockIdx.x * blockDim.x + threadIdx.x;   // ((p*T+t)*N+n)*2+c
    if (idx >= NPRED_ * T_ * N_ * 2) return;
    int c = idx & 1;
    int rest = idx >> 1;
    int n = rest % N_;
    rest /= N_;
    int t = rest % T_;
    out[idx] = o[((size_t)n * T_ + t) * 2 + c];
}

extern "C" void kernel_launch(void* const* d_in, const int* in_sizes, int n_in,
                              void* d_out, int out_size, void* d_ws, size_t ws_size,
                              hipStream_t stream) {
    (void)in_sizes; (void)n_in; (void)out_size; (void)ws_size;

    const float* x    = (const float*)d_in[0];
    const float* nbr  = (const float*)d_in[1];
    const float* attf = (const float*)d_in[2];
    const float* Wx   = (const float*)d_in[3];
    const float* bx   = (const float*)d_in[4];
    const float* Wn   = (const float*)d_in[5];
    const float* bn   = (const float*)d_in[6];
    const float* Wp   = (const float*)d_in[7];
    const float* bp   = (const float*)d_in[8];
    const float* WQ   = (const float*)d_in[9];
    const float* WK   = (const float*)d_in[10];
    const float* WV   = (const float*)d_in[11];
    const float* Wfc  = (const float*)d_in[12];
    const float* mlng = (const float*)d_in[13];
    const float* mlnb = (const float*)d_in[14];
    const float* WSI  = (const float*)d_in[15];
    const float* fsw1 = (const float*)d_in[16];
    const float* fsw2 = (const float*)d_in[17];
    const float* fsg  = (const float*)d_in[18];
    const float* fsb  = (const float*)d_in[19];
    const float* fiw1 = (const float*)d_in[20];
    const float* fiw2 = (const float*)d_in[21];
    const float* fig  = (const float*)d_in[22];
    const float* fib  = (const float*)d_in[23];

    char* w = (char*)d_ws;
    size_t off = 0;
    auto alloc = [&](size_t bytes) -> void* {
        void* p = w + off;
        off = (off + bytes + 255) & ~(size_t)255;
        return p;
    };

    const int BM = N_ * NN_;          // 2048 (b,m) pairs
    const int ROWS_I = BM * T_;       // 32768 neighbor rows
    const int CB = 512;               // bm per chunk (16 b's)
    const int RC = CB * T_;           // 8192 rows per chunk

    float* pe      = (float*)alloc((size_t)T_ * D_ * 4);
    float* xemb    = (float*)alloc((size_t)N_ * T_ * D_ * 4);
    float* nf      = (float*)alloc((size_t)T_ * N_ * NN_ * 3 * 4);
    float* maskf   = (float*)alloc((size_t)BM * T_ * 4);
    float* A       = (float*)alloc((size_t)ROWS_I * D_ * 4);     // n_emb      64 MB
    float* B       = (float*)alloc((size_t)ROWS_I * D_ * 4);     // res_inter  64 MB
    // scratch union: attention-phase (QKV/ctx bf16 + sc) vs ffn-phase (hidden bf16)
    char*  SCR     = (char*)alloc(36u * 1024 * 1024);            //            36 MB
    u16*   Qb      = (u16*)SCR;                                  //  8 MB
    u16*   Kb      = (u16*)(SCR + 8u * 1024 * 1024);             //  8 MB
    u16*   Vb      = (u16*)(SCR + 16u * 1024 * 1024);            //  8 MB
    u16*   ctxb    = (u16*)(SCR + 24u * 1024 * 1024);            //  8 MB
    float* sc      = (float*)(SCR + 32u * 1024 * 1024);          //  4 MB
    u16*   hid     = (u16*)SCR;                                  // 32 MB (aliases QKV/ctx)
    float* att_sum = (float*)alloc((size_t)N_ * H_ * 256 * 4);
    float* ss      = (float*)alloc((size_t)N_ * 256 * 4);
    float* att     = (float*)alloc((size_t)N_ * H_ * 256 * 4);
    float* si      = (float*)alloc((size_t)N_ * T_ * 4096 * 4);  // 16 MB
    float* xnew    = (float*)alloc((size_t)N_ * T_ * D_ * 4);
    float* osm     = (float*)alloc((size_t)N_ * T_ * 2 * 4);
    // total ~ 186 MB

    pe_kernel<<<16, 256, 0, stream>>>(pe);
    xemb_kernel<<<T_ * N_, 256, 0, stream>>>(x, Wx, bx, pe, xemb);
    nbr_kernel<<<(T_ * N_ * NN_ + 255) / 256, 256, 0, stream>>>(x, nbr, nf, maskf);
    nemb_kernel<<<BM * T_, 256, 0, stream>>>(nf, Wn, bn, pe, A);

    for (int l = 0; l < L_; ++l) {
        const float* WQl  = WQ  + (size_t)l * D_ * 512;
        const float* WKl  = WK  + (size_t)l * D_ * 512;
        const float* WVl  = WV  + (size_t)l * D_ * 512;
        const float* Wfcl = Wfc + (size_t)l * 512 * D_;
        const float* WSIl = WSI + (size_t)l * H_ * D_ * D_;

        // ---- attention over the neighbor stream, chunked ----
        for (int c = 0; c < ROWS_I / RC; ++c) {
            const float* Ac = A + (size_t)c * RC * D_;
            mfma_gemm<0, 0, 1><<<dim3(8, RC / 64), 256, 0, stream>>>(
                Ac, WQl, Qb, nullptr, 512, 512, 512, 512);
            mfma_gemm<0, 0, 1><<<dim3(8, RC / 64), 256, 0, stream>>>(
                Ac, WKl, Kb, nullptr, 512, 512, 512, 512);
            if (l == 0)   // V/ctx/fc feed only res_inter->ffi, dead at l=1
                mfma_gemm<0, 0, 1><<<dim3(8, RC / 64), 256, 0, stream>>>(
                    Ac, WVl, Vb, nullptr, 512, 512, 512, 512);
            score_b_kernel<<<CB * H_, 256, 0, stream>>>(Qb, Kb, maskf, c * CB, sc);
            softmax16_kernel<<<(CB * H_ * 16 + 255) / 256, 256, 0, stream>>>(sc, CB * H_ * 16);
            attsum_b_kernel<<<(16 * H_ * 256) / 256, 256, 0, stream>>>(sc, c * 16, att_sum);
            if (l == 0) {
                ctx_b_kernel<<<CB * H_, 256, 0, stream>>>(sc, Vb, ctxb);
                mfma_gemm<1, 2, 0><<<dim3(8, RC / 64), 256, 0, stream>>>(
                    ctxb, Wfcl, B + (size_t)c * RC * D_, Ac, 512, 512, 512, 512);
            }
        }
        if (l == 0)
            ln_fast_kernel<<<ROWS_I / 4, 256, 0, stream>>>(
                B, mlng + l * D_, mlnb + l * D_, B, ROWS_I);   // B = res_inter

        // ---- self-attention + si + ffs (updates xemb) ----
        selfscore_kernel<<<(N_ * 256 + 255) / 256, 256, 0, stream>>>(xemb, ss);
        softmax16_kernel<<<(N_ * T_ + 255) / 256, 256, 0, stream>>>(ss, N_ * T_);
        combine_kernel<<<(N_ * H_ * 256 + 255) / 256, 256, 0, stream>>>(ss, att_sum, attf, att);
        si_naive_kernel<<<(int)(((size_t)N_ * T_ * 4096) / 256), 256, 0, stream>>>(att, xemb, si);
        mfma_gemm<0, 0, 0><<<dim3(8, 16), 256, 0, stream>>>(
            si, WSIl, xnew, nullptr, 4096, 4096, 512, 512);
        mfma_gemm<0, 1, 1><<<dim3(32, 16), 256, 0, stream>>>(
            xnew, fsw1 + (size_t)l * D_ * DFF_, hid, nullptr, 512, 512, 2048, 2048);
        mfma_gemm<1, 2, 0><<<dim3(8, 16), 256, 0, stream>>>(
            hid, fsw2 + (size_t)l * DFF_ * D_, xemb, xnew, 2048, 2048, 512, 512);
        ln_fast_kernel<<<(N_ * T_) / 4, 256, 0, stream>>>(
            xemb, fsg + l * D_, fsb + l * D_, xemb, N_ * T_);

        // ---- ffi (next-layer n_emb); dead at l=1 ----
        if (l == 0) {
            for (int c = 0; c < ROWS_I / RC; ++c) {
                mfma_gemm<0, 1, 1><<<dim3(32, RC / 64), 256, 0, stream>>>(
                    B + (size_t)c * RC * D_, fiw1 + (size_t)l * D_ * DFF_,
                    hid, nullptr, 512, 512, 2048, 2048);
                mfma_gemm<1, 2, 0><<<dim3(8, RC / 64), 256, 0, stream>>>(
                    hid, fiw2 + (size_t)l * DFF_ * D_,
                    A + (size_t)c * RC * D_, B + (size_t)c * RC * D_, 2048, 2048, 512, 512);
            }
            ln_fast_kernel<<<ROWS_I / 4, 256, 0, stream>>>(
                A, fig + l * D_, fib + l * D_, A, ROWS_I);
        }
    }

    pred_kernel<<<(N_ * T_ * 2 + 255) / 256, 256, 0, stream>>>(xemb, Wp, bp, osm);
    bcast_kernel<<<(NPRED_ * T_ * N_ * 2 + 255) / 256, 256, 0, stream>>>(osm, (float*)d_out);
}

// Round 6
// 1496.177 us; speedup vs baseline: 32.8501x; 1.3526x over previous
//
#include <hip/hip_runtime.h>
#include <math.h>

// DTYPE COMMITMENTS (evidence-backed): inputs f32, output f32 (rounds 4/5 PASS).
// WS BUDGET: <= ~210 MB decimal (209 proven OK, 370 faults). This build: ~199.8 MiB.

#define T_ 16
#define N_ 64
#define NN_ 32
#define D_ 512
#define H_ 8
#define DK_ 64
#define DFF_ 2048
#define L_ 2
#define NPRED_ 20

typedef unsigned short u16;
typedef unsigned int u32;
typedef __attribute__((ext_vector_type(8))) short short8;
typedef __attribute__((ext_vector_type(4))) float f32x4;

__device__ __forceinline__ u16 f2bf(float f) {
    u32 u = __float_as_uint(f);
    u32 r = u + 0x7fffu + ((u >> 16) & 1u);
    return (u16)(r >> 16);
}
__device__ __forceinline__ float bfv(u16 v) {
    return __uint_as_float(((u32)v) << 16);
}
__device__ __forceinline__ float ntn(float v) {
    if (isnan(v)) return 0.0f;
    if (isinf(v)) return v > 0.0f ? 3.4028234663852886e38f : -3.4028234663852886e38f;
    return v;
}
__device__ __forceinline__ float wave_sum(float v) {
    #pragma unroll
    for (int o = 32; o > 0; o >>= 1) v += __shfl_xor(v, o, 64);
    return v;
}

// ============ weight convert+transpose: in[K][N] f32 -> out[N][K] bf16 ==============
__global__ __launch_bounds__(256) void wconv_kernel(const float* in, u16* out, int K, int N) {
    __shared__ float tile[32][33];
    int kb = blockIdx.y * 32, nb = blockIdx.x * 32;
    int tx = threadIdx.x & 31, ty = threadIdx.x >> 5;   // ty 0..7
    #pragma unroll
    for (int r = ty; r < 32; r += 8)
        tile[r][tx] = in[(size_t)(kb + r) * N + nb + tx];
    __syncthreads();
    #pragma unroll
    for (int r = ty; r < 32; r += 8)
        out[(size_t)(nb + r) * K + kb + tx] = f2bf(tile[tx][r]);
}

// ============ MFMA GEMM (m93-style): C[MxN] = A[MxK] @ Bt[NxK]^T ====================
// A, Bt bf16 row-major in K. 128x128 tile, BK=64, 4 waves each 64x64 (4x4 MFMA tiles).
// EPI: 0 none, 1 relu, 2 +residual(f32). WF32/WBF16: which outputs to write.
// M, N divisible by 128; K divisible by 64.
template<int EPI, int WF32, int WBF16>
__global__ __launch_bounds__(256) void gemm_bt(
    const u16* __restrict__ Ab, const u16* __restrict__ Btb,
    float* __restrict__ Cf, u16* __restrict__ Cb, const float* __restrict__ Rg,
    int K, int ldc)
{
    // 72-short row stride (144 B, 16B-aligned): frag reads land 2-way on banks (free)
    __shared__ __align__(16) u16 As[128][72];
    __shared__ __align__(16) u16 Bs[128][72];
    int tid = threadIdx.x;
    int lane = tid & 63, wave = tid >> 6;
    int quad = lane >> 4, l16 = lane & 15;
    int wm = (wave >> 1) * 64, wn = (wave & 1) * 64;
    size_t row0 = (size_t)blockIdx.y * 128;
    size_t col0 = (size_t)blockIdx.x * 128;

    f32x4 acc[4][4];
    #pragma unroll
    for (int i = 0; i < 4; ++i)
        #pragma unroll
        for (int j = 0; j < 4; ++j)
            acc[i][j] = (f32x4){0.f, 0.f, 0.f, 0.f};

    int sr = tid >> 2;            // staging row 0..63 (+64 second pass)
    int sq = tid & 3;             // 32B chunk within the 128B k-slab
    const u16* Abase = Ab  + (row0 + sr) * (size_t)K + sq * 16;
    const u16* Bbase = Btb + (col0 + sr) * (size_t)K + sq * 16;

    for (int k0 = 0; k0 < K; k0 += 64) {
        __syncthreads();
        #pragma unroll
        for (int p = 0; p < 2; ++p) {
            const u16* ga = Abase + (size_t)p * 64 * K + k0;
            uint4 va0 = *(const uint4*)ga;
            uint4 va1 = *(const uint4*)(ga + 8);
            const u16* gb = Bbase + (size_t)p * 64 * K + k0;
            uint4 vb0 = *(const uint4*)gb;
            uint4 vb1 = *(const uint4*)(gb + 8);
            *(uint4*)&As[sr + p * 64][sq * 16]     = va0;
            *(uint4*)&As[sr + p * 64][sq * 16 + 8] = va1;
            *(uint4*)&Bs[sr + p * 64][sq * 16]     = vb0;
            *(uint4*)&Bs[sr + p * 64][sq * 16 + 8] = vb1;
        }
        __syncthreads();
        #pragma unroll
        for (int s = 0; s < 2; ++s) {
            short8 af[4], bf[4];
            #pragma unroll
            for (int i = 0; i < 4; ++i) {
                af[i] = *(short8*)&As[wm + i * 16 + l16][s * 32 + quad * 8];
                bf[i] = *(short8*)&Bs[wn + i * 16 + l16][s * 32 + quad * 8];
            }
            #pragma unroll
            for (int i = 0; i < 4; ++i)
                #pragma unroll
                for (int j = 0; j < 4; ++j)
                    acc[i][j] = __builtin_amdgcn_mfma_f32_16x16x32_bf16(
                        af[i], bf[j], acc[i][j], 0, 0, 0);
        }
    }
    // C/D layout (on-target verified round 5): col = lane&15, row = quad*4 + reg
    #pragma unroll
    for (int i = 0; i < 4; ++i)
        #pragma unroll
        for (int j = 0; j < 4; ++j)
            #pragma unroll
            for (int reg = 0; reg < 4; ++reg) {
                size_t row = row0 + wm + i * 16 + quad * 4 + reg;
                size_t col = col0 + wn + j * 16 + l16;
                float v = acc[i][j][reg];
                if (EPI == 2) v += Rg[row * (size_t)ldc + col];
                if (EPI == 1) v = fmaxf(v, 0.f);
                if (WF32)  Cf[row * (size_t)ldc + col] = v;
                if (WBF16) Cb[row * (size_t)ldc + col] = f2bf(v);
            }
}

// ---------------- positional encoding ------------------------------------------------
__global__ void pe_kernel(float* pe) {
    int i = blockIdx.x * blockDim.x + threadIdx.x;
    if (i >= T_ * 256) return;
    int t = i >> 8, j = i & 255;
    float dv = (float)pow(10000.0, (double)j / 256.0);
    float a = (float)t * dv;
    double ad = (double)a;
    pe[t * D_ + 2 * j]     = (float)sin(ad);
    pe[t * D_ + 2 * j + 1] = (float)cos(ad);
}

// ---------------- x features + embed -------------------------------------------------
__global__ void xemb_kernel(const float* x, const float* Wx, const float* bx,
                            const float* pe, float* xemb) {
    int row = blockIdx.x;              // t*N + n
    int t = row / N_, n = row % N_;
    float x0 = x[row * 6 + 0], x1 = x[row * 6 + 1];
    float x2 = x[row * 6 + 2], x3 = x[row * 6 + 3];
    float x4 = x[row * 6 + 4], x5 = x[row * 6 + 5];
    float vel = sqrtf(x2 * x2 + x3 * x3);
    float ang = atanf(x5 / x4);
    float f0 = ntn(x0), f1 = ntn(x1), f2 = ntn(vel), f3 = ntn(ang);
    for (int d = threadIdx.x; d < D_; d += blockDim.x) {
        xemb[((size_t)n * T_ + t) * D_ + d] =
            f0 * Wx[0 * D_ + d] + f1 * Wx[1 * D_ + d]
          + f2 * Wx[2 * D_ + d] + f3 * Wx[3 * D_ + d]
          + bx[d] + pe[t * D_ + d];
    }
}

// ---------------- neighbor features + mask -------------------------------------------
__global__ void nbr_kernel(const float* x, const float* nbr, float* nf, float* maskf) {
    int idx = blockIdx.x * blockDim.x + threadIdx.x;   // t*N*NN + n*NN + m
    if (idx >= T_ * N_ * NN_) return;
    int m = idx % NN_;
    int tn = idx / NN_;
    int n = tn % N_, t = tn / N_;
    float px = x[((size_t)t * N_ + n) * 6 + 0];
    float py = x[((size_t)t * N_ + n) * 6 + 1];
    float vx, vy;
    if (t == 0) {
        vx = x[((size_t)1 * N_ + n) * 6 + 2];
        vy = x[((size_t)1 * N_ + n) * 6 + 3];
    } else {
        vx = px - x[((size_t)(t - 1) * N_ + n) * 6 + 0];
        vy = py - x[((size_t)(t - 1) * N_ + n) * 6 + 1];
    }
    float nx  = nbr[(size_t)idx * 4 + 0], ny  = nbr[(size_t)idx * 4 + 1];
    float nvx = nbr[(size_t)idx * 4 + 2], nvy = nbr[(size_t)idx * 4 + 3];
    float dpx = nx - px, dpy = ny - py;
    float dvx = nvx - vx, dvy = nvy - vy;
    float dist = sqrtf(dpx * dpx + dpy * dpy);
    maskf[((size_t)n * NN_ + m) * T_ + t] = (dist <= 2.0f) ? 1.0f : 0.0f;
    float vn = sqrtf(vx * vx + vy * vy);
    float bearing = (dpx * vx + dpy * vy) / (dist * vn);
    if (isnan(bearing)) bearing = 0.0f;
    float dvn = sqrtf(dvx * dvx + dvy * dvy);
    float tau = -(dpx * dvx + dpy * dvy) / dvn;
    if (isnan(tau)) tau = 0.0f;
    tau = fminf(fmaxf(tau, 0.0f), 7.0f);
    float mx_ = dpx + tau * dvx, my_ = dpy + tau * dvy;
    float mpd = sqrtf(mx_ * mx_ + my_ * my_);
    nf[(size_t)idx * 3 + 0] = ntn(dist);
    nf[(size_t)idx * 3 + 1] = ntn(bearing);
    nf[(size_t)idx * 3 + 2] = ntn(mpd);
}

// ---------------- neighbor embed: writes f32 A and bf16 Ab ---------------------------
__global__ void nemb_kernel(const float* nf, const float* Wn, const float* bn,
                            const float* pe, float* A, u16* Ab) {
    int row = blockIdx.x;              // (b*NN+m)*T + t
    int t = row % T_;
    int bm = row / T_;
    int m = bm % NN_, b = bm / NN_;
    size_t nfrow = (((size_t)t * N_ + b) * NN_ + m) * 3;
    float f0 = nf[nfrow], f1 = nf[nfrow + 1], f2 = nf[nfrow + 2];
    for (int d = threadIdx.x; d < D_; d += blockDim.x) {
        float v = f0 * Wn[d] + f1 * Wn[D_ + d] + f2 * Wn[2 * D_ + d]
                + bn[d] + pe[t * D_ + d];
        A[(size_t)row * D_ + d] = v;
        Ab[(size_t)row * D_ + d] = f2bf(v);
    }
}

// ---------------- scores from bf16 Q,K (chunk-local) ---------------------------------
__global__ void score_b_kernel(const u16* Qb, const u16* Kb, const float* maskf,
                               int bm0, float* sc) {
    int bx = blockIdx.x;            // bm_local*8 + h
    int bm_l = bx >> 3, h = bx & 7;
    int tid = threadIdx.x;          // q*16 + k
    int q = tid >> 4, k = tid & 15;
    const u32* qu = (const u32*)(Qb + ((size_t)bm_l * T_ + q) * D_ + h * DK_);
    const u32* ku = (const u32*)(Kb + ((size_t)bm_l * T_ + k) * D_ + h * DK_);
    float acc = 0.f;
    #pragma unroll
    for (int j = 0; j < 32; ++j) {
        u32 a = qu[j], b = ku[j];
        acc += bfv((u16)(a & 0xffff)) * bfv((u16)(b & 0xffff));
        acc += bfv((u16)(a >> 16))   * bfv((u16)(b >> 16));
    }
    acc *= 0.125f;
    if (maskf[(size_t)(bm0 + bm_l) * T_ + q] == 0.0f) acc = -1e9f;
    sc[(size_t)bx * 256 + tid] = acc;
}

// in-place softmax over rows of 16
__global__ void softmax16_kernel(float* p_, int nrows) {
    int r = blockIdx.x * blockDim.x + threadIdx.x;
    if (r >= nrows) return;
    float* p = p_ + (size_t)r * 16;
    float mx = p[0];
    for (int k = 1; k < 16; ++k) mx = fmaxf(mx, p[k]);
    float e[16], s = 0.f;
    for (int k = 0; k < 16; ++k) { e[k] = expf(p[k] - mx); s += e[k]; }
    float inv = 1.0f / s;
    for (int k = 0; k < 16; ++k) p[k] = e[k] * inv;
}

// att_sum[b][h][qk] = mean_m sc[(bm_l*8+h)][qk], 16 b's per chunk
__global__ void attsum_b_kernel(const float* sc, int b0, float* att_sum) {
    int i = blockIdx.x * blockDim.x + threadIdx.x;   // b_l*2048 + h*256 + qk
    if (i >= 16 * H_ * 256) return;
    int b_l = i >> 11;
    int h = (i >> 8) & 7, qk = i & 255;
    float s = 0.f;
    for (int m = 0; m < NN_; ++m)
        s += sc[((size_t)((b_l * NN_ + m) * H_ + h)) * 256 + qk];
    att_sum[((size_t)(b0 + b_l) * H_ + h) * 256 + qk] = s * (1.0f / 32.0f);
}

// ctx (bf16) = attn @ V per (bm,h)
__global__ void ctx_b_kernel(const float* sc, const u16* Vb, u16* ctxb) {
    int bx = blockIdx.x;            // bm_l*8 + h
    int bm_l = bx >> 3, h = bx & 7;
    int tid = threadIdx.x;
    #pragma unroll
    for (int rep = 0; rep < 4; ++rep) {
        int i = rep * 256 + tid;
        int t = i >> 6, dk = i & 63;
        float acc = 0.f;
        #pragma unroll
        for (int k = 0; k < T_; ++k)
            acc += sc[(size_t)bx * 256 + t * 16 + k]
                 * bfv(Vb[((size_t)bm_l * T_ + k) * D_ + h * DK_ + dk]);
        ctxb[((size_t)bm_l * T_ + t) * D_ + h * DK_ + dk] = f2bf(acc);
    }
}

// ---------------- LayerNorm, one wave per row, dual-width output ---------------------
__global__ __launch_bounds__(256) void ln_dual_kernel(
    const float* X, const float* g, const float* b, float* outF, u16* outB, int nrows) {
    int row = blockIdx.x * 4 + (threadIdx.x >> 6);
    if (row >= nrows) return;
    int lane = threadIdx.x & 63;
    const float* p = X + (size_t)row * D_;
    float v[8];
    float s = 0.f;
    #pragma unroll
    for (int r = 0; r < 8; ++r) { v[r] = p[lane + r * 64]; s += v[r]; }
    s = wave_sum(s);
    float mean = s * (1.0f / 512.0f);
    float vs = 0.f;
    #pragma unroll
    for (int r = 0; r < 8; ++r) { float d = v[r] - mean; vs += d * d; }
    vs = wave_sum(vs);
    float rstd = rsqrtf(vs * (1.0f / 512.0f) + 1e-5f);
    #pragma unroll
    for (int r = 0; r < 8; ++r) {
        int d = lane + r * 64;
        float o = (v[r] - mean) * rstd * g[d] + b[d];
        if (outF) outF[(size_t)row * D_ + d] = o;
        if (outB) outB[(size_t)row * D_ + d] = f2bf(o);
    }
}

// ---------------- self attention (naive, proven) -------------------------------------
__global__ void selfscore_kernel(const float* xemb, float* ss) {
    int i = blockIdx.x * blockDim.x + threadIdx.x;   // n*256 + q*16 + k
    if (i >= N_ * 256) return;
    int n = i >> 8, q = (i >> 4) & 15, k = i & 15;
    const float* a = xemb + ((size_t)n * T_ + q) * D_;
    const float* b = xemb + ((size_t)n * T_ + k) * D_;
    float acc = 0.f;
    for (int j = 0; j < D_; ++j) acc += a[j] * b[j];
    ss[i] = acc * 0.04419417382415922f;
}

__global__ void combine_kernel(const float* ss, const float* att_sum, const float* attf, float* att) {
    int i = blockIdx.x * blockDim.x + threadIdx.x;   // n*2048 + h*256 + qk
    if (i >= N_ * H_ * 256) return;
    int n = i >> 11, qk = i & 255;
    att[i] = ss[n * 256 + qk] + attf[0] * att_sum[i];
}

// si (bf16) [n*16+q][h*512+d] = sum_t att[n][h][q*16+t] * xemb[n][t][d]
__global__ void si_naive_kernel(const float* att, const float* xemb, u16* sib) {
    size_t i = (size_t)blockIdx.x * 256 + threadIdx.x;
    int hd = (int)(i & 4095);
    int h = hd >> 9, d = hd & 511;
    size_t nq = i >> 12;
    int n = (int)(nq >> 4), q = (int)(nq & 15);
    float acc = 0.f;
    #pragma unroll
    for (int t = 0; t < T_; ++t)
        acc += att[((size_t)n * H_ + h) * 256 + q * 16 + t] * xemb[((size_t)n * T_ + t) * D_ + d];
    sib[i] = f2bf(acc);
}

// ---------------- prediction head + broadcast (f32 out) ------------------------------
__global__ void pred_kernel(const float* xemb, const float* Wp, const float* bp, float* o) {
    int idx = blockIdx.x * blockDim.x + threadIdx.x;
    if (idx >= N_ * T_ * 2) return;
    int c = idx & 1;
    int nt = idx >> 1;
    float acc = bp[c];
    for (int j = 0; j < D_; ++j) acc += xemb[(size_t)nt * D_ + j] * Wp[(size_t)j * 2 + c];
    o[idx] = acc;
}

__global__ void bcast_kernel(const float* o, float* out) {
    int idx = blockIdx.x * blockDim.x + threadIdx.x;   // ((p*T+t)*N+n)*2+c
    if (idx >= NPRED_ * T_ * N_ * 2) return;
    int c = idx & 1;
    int rest = idx >> 1;
    int n = rest % N_;
    rest /= N_;
    int t = rest % T_;
    out[idx] = o[((size_t)n * T_ + t) * 2 + c];
}

extern "C" void kernel_launch(void* const* d_in, const int* in_sizes, int n_in,
                              void* d_out, int out_size, void* d_ws, size_t ws_size,
                              hipStream_t stream) {
    (void)in_sizes; (void)n_in; (void)out_size; (void)ws_size;

    const float* x    = (const float*)d_in[0];
    const float* nbr  = (const float*)d_in[1];
    const float* attf = (const float*)d_in[2];
    const float* Wx   = (const float*)d_in[3];
    const float* bx   = (const float*)d_in[4];
    const float* Wn   = (const float*)d_in[5];
    const float* bn   = (const float*)d_in[6];
    const float* Wp   = (const float*)d_in[7];
    const float* bp   = (const float*)d_in[8];
    const float* WQ   = (const float*)d_in[9];
    const float* WK   = (const float*)d_in[10];
    const float* WV   = (const float*)d_in[11];
    const float* Wfc  = (const float*)d_in[12];
    const float* mlng = (const float*)d_in[13];
    const float* mlnb = (const float*)d_in[14];
    const float* WSI  = (const float*)d_in[15];
    const float* fsw1 = (const float*)d_in[16];
    const float* fsw2 = (const float*)d_in[17];
    const float* fsg  = (const float*)d_in[18];
    const float* fsb  = (const float*)d_in[19];
    const float* fiw1 = (const float*)d_in[20];
    const float* fiw2 = (const float*)d_in[21];
    const float* fig  = (const float*)d_in[22];
    const float* fib  = (const float*)d_in[23];

    char* w = (char*)d_ws;
    size_t off = 0;
    auto alloc = [&](size_t bytes) -> void* {
        void* p = w + off;
        off = (off + bytes + 255) & ~(size_t)255;
        return p;
    };
    const size_t MiB = 1024 * 1024;

    const int BM = N_ * NN_;          // 2048 (b,m) pairs
    const int ROWS_I = BM * T_;       // 32768 neighbor rows
    const int CB = 512;               // bm per chunk (16 b's)
    const int RC = CB * T_;           // 8192 rows per chunk
    const int NCH = ROWS_I / RC;      // 4 chunks

    float* pe      = (float*)alloc((size_t)T_ * D_ * 4);
    float* xemb    = (float*)alloc((size_t)N_ * T_ * D_ * 4);
    float* nf      = (float*)alloc((size_t)T_ * N_ * NN_ * 3 * 4);
    float* maskf   = (float*)alloc((size_t)BM * T_ * 4);
    float* A       = (float*)alloc((size_t)ROWS_I * D_ * 4);   // n_emb f32   64 MiB
    u16*   Ab      = (u16*)alloc((size_t)ROWS_I * D_ * 2);     // n_emb bf16  32 MiB
    // bf16 transposed weights
    u16* tWQ[2], *tWK[2], *tWSI[2], *tfs1[2], *tfs2[2];
    for (int l = 0; l < 2; ++l) {
        tWQ[l]  = (u16*)alloc((size_t)512 * 512 * 2);
        tWK[l]  = (u16*)alloc((size_t)512 * 512 * 2);
        tWSI[l] = (u16*)alloc((size_t)512 * 4096 * 2);
        tfs1[l] = (u16*)alloc((size_t)2048 * 512 * 2);
        tfs2[l] = (u16*)alloc((size_t)512 * 2048 * 2);
    }
    u16* tWV  = (u16*)alloc((size_t)512 * 512 * 2);    // l=0 only (dead at l=1)
    u16* tWfc = (u16*)alloc((size_t)512 * 512 * 2);
    u16* tfi1 = (u16*)alloc((size_t)2048 * 512 * 2);
    u16* tfi2 = (u16*)alloc((size_t)512 * 2048 * 2);
    // scratch union: attention (Q,K,V,ctx bf16 + sc f32) vs FFN hidden (bf16)
    char* SCR  = (char*)alloc(36 * MiB);
    u16*   Qb   = (u16*)SCR;
    u16*   Kb   = (u16*)(SCR + 8 * MiB);
    u16*   Vb   = (u16*)(SCR + 16 * MiB);
    u16*   ctxb = (u16*)(SCR + 24 * MiB);
    float* sc   = (float*)(SCR + 32 * MiB);            // 4 MiB
    u16*   hid  = (u16*)SCR;                           // 32 MiB, aliases Q/K/V/ctx
    float* Bch  = (float*)alloc((size_t)RC * D_ * 4);  // res_inter chunk f32  16 MiB
    u16*   Bbch = (u16*)alloc((size_t)RC * D_ * 2);    // res_inter chunk bf16  8 MiB
    float* att_sum = (float*)alloc((size_t)N_ * H_ * 256 * 4);
    float* ss      = (float*)alloc((size_t)N_ * 256 * 4);
    float* att     = (float*)alloc((size_t)N_ * H_ * 256 * 4);
    u16*   sib     = (u16*)alloc((size_t)N_ * T_ * 4096 * 2);  // 8 MiB
    float* xnew    = (float*)alloc((size_t)N_ * T_ * D_ * 4);
    u16*   xnb     = (u16*)alloc((size_t)N_ * T_ * D_ * 2);
    float* osm     = (float*)alloc((size_t)N_ * T_ * 2 * 4);
    // total ~199.8 MiB

    // ---- one-time weight conversion (transposed bf16) ----
    auto wT = [&](const float* src, u16* dst, int K, int N) {
        wconv_kernel<<<dim3(N / 32, K / 32), 256, 0, stream>>>(src, dst, K, N);
    };
    for (int l = 0; l < 2; ++l) {
        wT(WQ   + (size_t)l * 512 * 512,  tWQ[l],  512, 512);
        wT(WK   + (size_t)l * 512 * 512,  tWK[l],  512, 512);
        wT(WSI  + (size_t)l * 4096 * 512, tWSI[l], 4096, 512);
        wT(fsw1 + (size_t)l * 512 * 2048, tfs1[l], 512, 2048);
        wT(fsw2 + (size_t)l * 2048 * 512, tfs2[l], 2048, 512);
    }
    wT(WV, tWV, 512, 512);
    wT(Wfc, tWfc, 512, 512);
    wT(fiw1, tfi1, 512, 2048);
    wT(fiw2, tfi2, 2048, 512);

    pe_kernel<<<16, 256, 0, stream>>>(pe);
    xemb_kernel<<<T_ * N_, 256, 0, stream>>>(x, Wx, bx, pe, xemb);
    nbr_kernel<<<(T_ * N_ * NN_ + 255) / 256, 256, 0, stream>>>(x, nbr, nf, maskf);
    nemb_kernel<<<BM * T_, 256, 0, stream>>>(nf, Wn, bn, pe, A, Ab);

    for (int l = 0; l < L_; ++l) {
        for (int c = 0; c < NCH; ++c) {
            const u16*   Acb = Ab + (size_t)c * RC * D_;
            float*       Acf = A  + (size_t)c * RC * D_;
            gemm_bt<0, 0, 1><<<dim3(4, RC / 128), 256, 0, stream>>>(
                Acb, tWQ[l], nullptr, Qb, nullptr, 512, 512);
            gemm_bt<0, 0, 1><<<dim3(4, RC / 128), 256, 0, stream>>>(
                Acb, tWK[l], nullptr, Kb, nullptr, 512, 512);
            if (l == 0)
                gemm_bt<0, 0, 1><<<dim3(4, RC / 128), 256, 0, stream>>>(
                    Acb, tWV, nullptr, Vb, nullptr, 512, 512);
            score_b_kernel<<<CB * H_, 256, 0, stream>>>(Qb, Kb, maskf, c * CB, sc);
            softmax16_kernel<<<(CB * H_ * 16 + 255) / 256, 256, 0, stream>>>(sc, CB * H_ * 16);
            attsum_b_kernel<<<(16 * H_ * 256) / 256, 256, 0, stream>>>(sc, c * 16, att_sum);
            if (l == 0) {
                ctx_b_kernel<<<CB * H_, 256, 0, stream>>>(sc, Vb, ctxb);
                // fc + residual(n_emb f32) -> Bch f32
                gemm_bt<2, 1, 0><<<dim3(4, RC / 128), 256, 0, stream>>>(
                    ctxb, tWfc, Bch, nullptr, Acf, 512, 512);
                // LN -> res_inter: Bch f32 (residual for ffi2), Bbch bf16 (ffi1 input)
                ln_dual_kernel<<<RC / 4, 256, 0, stream>>>(
                    Bch, mlng, mlnb, Bch, Bbch, RC);
                // ffi1: relu -> hid (Q/K/V/ctx now dead; hid aliases them)
                gemm_bt<1, 0, 1><<<dim3(16, RC / 128), 256, 0, stream>>>(
                    Bbch, tfi1, nullptr, hid, nullptr, 512, 2048);
                // ffi2 + residual(res_inter) -> pre-LN into the dead f32 n_emb chunk
                gemm_bt<2, 1, 0><<<dim3(4, RC / 128), 256, 0, stream>>>(
                    hid, tfi2, Acf, nullptr, Bch, 2048, 512);
                // LN -> new n_emb (bf16 only; f32 n_emb dead from here on)
                ln_dual_kernel<<<RC / 4, 256, 0, stream>>>(
                    Acf, fig, fib, nullptr, (u16*)Acb, RC);
            }
        }

        // ---- self-attention + si + ffs (updates xemb) ----
        selfscore_kernel<<<(N_ * 256 + 255) / 256, 256, 0, stream>>>(xemb, ss);
        softmax16_kernel<<<(N_ * T_ + 255) / 256, 256, 0, stream>>>(ss, N_ * T_);
        combine_kernel<<<(N_ * H_ * 256 + 255) / 256, 256, 0, stream>>>(ss, att_sum, attf, att);
        si_naive_kernel<<<(int)(((size_t)N_ * T_ * 4096) / 256), 256, 0, stream>>>(att, xemb, sib);
        gemm_bt<0, 1, 1><<<dim3(4, 8), 256, 0, stream>>>(
            sib, tWSI[l], xnew, xnb, nullptr, 4096, 512);
        gemm_bt<1, 0, 1><<<dim3(16, 8), 256, 0, stream>>>(
            xnb, tfs1[l], nullptr, hid, nullptr, 512, 2048);
        gemm_bt<2, 1, 0><<<dim3(4, 8), 256, 0, stream>>>(
            hid, tfs2[l], xemb, nullptr, xnew, 2048, 512);
        ln_dual_kernel<<<(N_ * T_) / 4, 256, 0, stream>>>(
            xemb, fsg + l * D_, fsb + l * D_, xemb, nullptr, N_ * T_);
    }

    pred_kernel<<<(N_ * T_ * 2 + 255) / 256, 256, 0, stream>>>(xemb, Wp, bp, osm);
    bcast_kernel<<<(NPRED_ * T_ * N_ * 2 + 255) / 256, 256, 0, stream>>>(osm, (float*)d_out);
}

// Round 7
// 1283.067 us; speedup vs baseline: 38.3063x; 1.1661x over previous
//
#include <hip/hip_runtime.h>
#include <math.h>

// DTYPE COMMITMENTS (evidence-backed): inputs f32, output f32 (rounds 4/5/6 PASS).
// WS BUDGET: <= ~210 MB decimal; this build ~196 MiB.

#define T_ 16
#define N_ 64
#define NN_ 32
#define D_ 512
#define H_ 8
#define DK_ 64
#define DFF_ 2048
#define L_ 2
#define NPRED_ 20

typedef unsigned short u16;
typedef unsigned int u32;
typedef __attribute__((ext_vector_type(8))) short short8;
typedef __attribute__((ext_vector_type(4))) float f32x4;

__device__ __forceinline__ u16 f2bf(float f) {
    u32 u = __float_as_uint(f);
    u32 r = u + 0x7fffu + ((u >> 16) & 1u);
    return (u16)(r >> 16);
}
__device__ __forceinline__ float bfv(u16 v) {
    return __uint_as_float(((u32)v) << 16);
}
__device__ __forceinline__ float ntn(float v) {
    if (isnan(v)) return 0.0f;
    if (isinf(v)) return v > 0.0f ? 3.4028234663852886e38f : -3.4028234663852886e38f;
    return v;
}
__device__ __forceinline__ float wave_sum(float v) {
    #pragma unroll
    for (int o = 32; o > 0; o >>= 1) v += __shfl_xor(v, o, 64);
    return v;
}

// ============ weight convert+transpose: in[K][N] f32 -> out[N][K] bf16 ==============
__global__ __launch_bounds__(256) void wconv_kernel(const float* in, u16* out, int K, int N) {
    __shared__ float tile[32][33];
    int kb = blockIdx.y * 32, nb = blockIdx.x * 32;
    int tx = threadIdx.x & 31, ty = threadIdx.x >> 5;
    #pragma unroll
    for (int r = ty; r < 32; r += 8)
        tile[r][tx] = in[(size_t)(kb + r) * N + nb + tx];
    __syncthreads();
    #pragma unroll
    for (int r = ty; r < 32; r += 8)
        out[(size_t)(nb + r) * K + kb + tx] = f2bf(tile[tx][r]);
}

// ============ MFMA GEMM: C[MxN] = A[MxK] @ Bt[NxK]^T, tile TM x TN, BK=64 ===========
// 4 waves in 2x2; wave tile (TM/2)x(TN/2); per-wave MFMA tiles WR x WC (16x16x32).
// EPI: 0 none, 1 relu, 2 +residual f32. WF32/WBF16 select output widths.
// Grid: (N/TN, M/TM). M%TM==0, N%TN==0, K%64==0.
template<int TM, int TN, int EPI, int WF32, int WBF16>
__global__ __launch_bounds__(256) void gemm_bt(
    const u16* __restrict__ Ab, const u16* __restrict__ Btb,
    float* __restrict__ Cf, u16* __restrict__ Cb, const float* __restrict__ Rg,
    int K, int ldc)
{
    constexpr int WR = TM / 32, WC = TN / 32;
    constexpr int PA = TM / 64, PB = TN / 64;
    __shared__ __align__(16) u16 As[TM][72];   // 72-short stride: 2-way banks (free)
    __shared__ __align__(16) u16 Bs[TN][72];
    int tid = threadIdx.x;
    int lane = tid & 63, wave = tid >> 6;
    int quad = lane >> 4, l16 = lane & 15;
    int wm = (wave >> 1) * (TM / 2), wn = (wave & 1) * (TN / 2);
    size_t row0 = (size_t)blockIdx.y * TM;
    size_t col0 = (size_t)blockIdx.x * TN;

    f32x4 acc[WR][WC];
    #pragma unroll
    for (int i = 0; i < WR; ++i)
        #pragma unroll
        for (int j = 0; j < WC; ++j)
            acc[i][j] = (f32x4){0.f, 0.f, 0.f, 0.f};

    int sr = tid >> 2, sq = tid & 3;
    const u16* Abase = Ab  + (row0 + sr) * (size_t)K + sq * 16;
    const u16* Bbase = Btb + (col0 + sr) * (size_t)K + sq * 16;

    for (int k0 = 0; k0 < K; k0 += 64) {
        __syncthreads();
        #pragma unroll
        for (int p = 0; p < PA; ++p) {
            const u16* g = Abase + (size_t)p * 64 * K + k0;
            uint4 v0 = *(const uint4*)g;
            uint4 v1 = *(const uint4*)(g + 8);
            *(uint4*)&As[sr + p * 64][sq * 16]     = v0;
            *(uint4*)&As[sr + p * 64][sq * 16 + 8] = v1;
        }
        #pragma unroll
        for (int p = 0; p < PB; ++p) {
            const u16* g = Bbase + (size_t)p * 64 * K + k0;
            uint4 v0 = *(const uint4*)g;
            uint4 v1 = *(const uint4*)(g + 8);
            *(uint4*)&Bs[sr + p * 64][sq * 16]     = v0;
            *(uint4*)&Bs[sr + p * 64][sq * 16 + 8] = v1;
        }
        __syncthreads();
        #pragma unroll
        for (int s = 0; s < 2; ++s) {
            short8 af[WR], bf[WC];
            #pragma unroll
            for (int i = 0; i < WR; ++i)
                af[i] = *(short8*)&As[wm + i * 16 + l16][s * 32 + quad * 8];
            #pragma unroll
            for (int j = 0; j < WC; ++j)
                bf[j] = *(short8*)&Bs[wn + j * 16 + l16][s * 32 + quad * 8];
            #pragma unroll
            for (int i = 0; i < WR; ++i)
                #pragma unroll
                for (int j = 0; j < WC; ++j)
                    acc[i][j] = __builtin_amdgcn_mfma_f32_16x16x32_bf16(
                        af[i], bf[j], acc[i][j], 0, 0, 0);
        }
    }
    // C/D layout (on-target verified): col = lane&15, row = quad*4 + reg
    #pragma unroll
    for (int i = 0; i < WR; ++i)
        #pragma unroll
        for (int j = 0; j < WC; ++j)
            #pragma unroll
            for (int reg = 0; reg < 4; ++reg) {
                size_t row = row0 + wm + i * 16 + quad * 4 + reg;
                size_t col = col0 + wn + j * 16 + l16;
                float v = acc[i][j][reg];
                if (EPI == 2) v += Rg[row * (size_t)ldc + col];
                if (EPI == 1) v = fmaxf(v, 0.f);
                if (WF32)  Cf[row * (size_t)ldc + col] = v;
                if (WBF16) Cb[row * (size_t)ldc + col] = f2bf(v);
            }
}

// ============ fused attention per (b,m): scores+softmax+att_sum+ctx =================
// QKVb: [RC rows][1536] bf16 (Q cols 0..511, K 512..1023, V 1024..1535 by h*64+dk).
// One block per chunk-local bm. CTX=1: also compute ctx (bf16, ld 512).
template<int CTX>
__global__ __launch_bounds__(256) void attn_fused_kernel(
    const u16* __restrict__ QKVb, const float* __restrict__ maskf, int bm0,
    float* __restrict__ att_sum, u16* __restrict__ ctxb)
{
    __shared__ __align__(16) u16 sQ[16][520];   // +8 pad: score reads 2/4-way max
    __shared__ __align__(16) u16 sK[16][520];
    __shared__ __align__(16) u16 sV[CTX ? 16 : 1][520];
    __shared__ float s_p[16][17];
    int bm_l = blockIdx.x;
    int tid = threadIdx.x;
    int t = tid >> 4, ch = (tid & 15) * 32;     // 32 u16 = 4x uint4 per thread
    const u16* base = QKVb + ((size_t)bm_l * T_ + t) * 1536;
    #pragma unroll
    for (int c = 0; c < 4; ++c) {
        *(uint4*)&sQ[t][ch + c * 8] = *(const uint4*)(base + ch + c * 8);
        *(uint4*)&sK[t][ch + c * 8] = *(const uint4*)(base + 512 + ch + c * 8);
        if (CTX) *(uint4*)&sV[t][ch + c * 8] = *(const uint4*)(base + 1024 + ch + c * 8);
    }
    __syncthreads();

    int q = tid >> 4, k = tid & 15;
    float maskq = maskf[(size_t)(bm0 + bm_l) * T_ + q];
    int b = (bm0 + bm_l) >> 5;                  // bm = b*NN + m

    for (int h = 0; h < H_; ++h) {
        // scores
        {
            const u32* qu = (const u32*)&sQ[q][0] + h * 32;
            const u32* ku = (const u32*)&sK[k][0] + h * 32;
            float acc = 0.f;
            #pragma unroll
            for (int j = 0; j < 32; ++j) {
                u32 a = qu[j], bb = ku[j];
                acc += bfv((u16)(a & 0xffff)) * bfv((u16)(bb & 0xffff));
                acc += bfv((u16)(a >> 16))    * bfv((u16)(bb >> 16));
            }
            acc *= 0.125f;
            if (maskq == 0.0f) acc = -1e9f;
            s_p[q][k] = acc;
        }
        __syncthreads();
        if (tid < T_) {
            float mx = -3.4e38f;
            #pragma unroll
            for (int kk = 0; kk < 16; ++kk) mx = fmaxf(mx, s_p[tid][kk]);
            float e[16], s = 0.f;
            #pragma unroll
            for (int kk = 0; kk < 16; ++kk) { e[kk] = expf(s_p[tid][kk] - mx); s += e[kk]; }
            float inv = 1.0f / s;
            #pragma unroll
            for (int kk = 0; kk < 16; ++kk) s_p[tid][kk] = e[kk] * inv;
        }
        __syncthreads();
        atomicAdd(&att_sum[(((size_t)b * H_ + h) * T_ + q) * T_ + k], s_p[q][k]);
        if (CTX) {
            #pragma unroll
            for (int rep = 0; rep < 4; ++rep) {
                int i = rep * 256 + tid;
                int tt = i >> 6, dk = i & 63;
                float acc = 0.f;
                #pragma unroll
                for (int kk = 0; kk < 16; ++kk)
                    acc += s_p[tt][kk] * bfv(sV[kk][h * DK_ + dk]);
                ctxb[((size_t)bm_l * T_ + tt) * D_ + h * DK_ + dk] = f2bf(acc);
            }
        }
        __syncthreads();
    }
}

// ============ fused self-attention + combine + si, one block per n ==================
__global__ __launch_bounds__(256) void siatt_kernel(
    const float* __restrict__ xemb, const float* __restrict__ att_sum,
    const float* __restrict__ attf, u16* __restrict__ sib)
{
    __shared__ float sX[16][516];    // +4 pad
    __shared__ float sS[16][17];
    __shared__ float sA[H_][16][17];
    int n = blockIdx.x, tid = threadIdx.x;
    int t = tid >> 4, ch = (tid & 15) * 32;
    const float* src = xemb + ((size_t)n * T_ + t) * D_;
    #pragma unroll
    for (int c = 0; c < 8; ++c)
        *(float4*)&sX[t][ch + c * 4] = *(const float4*)(src + ch + c * 4);
    __syncthreads();
    int q = tid >> 4, k = tid & 15;
    {
        float acc = 0.f;
        for (int d = 0; d < D_; ++d) acc += sX[q][d] * sX[k][d];
        sS[q][k] = acc * 0.04419417382415922f;
    }
    __syncthreads();
    if (tid < T_) {
        float mx = -3.4e38f;
        #pragma unroll
        for (int kk = 0; kk < 16; ++kk) mx = fmaxf(mx, sS[tid][kk]);
        float e[16], s = 0.f;
        #pragma unroll
        for (int kk = 0; kk < 16; ++kk) { e[kk] = expf(sS[tid][kk] - mx); s += e[kk]; }
        float inv = 1.0f / s;
        #pragma unroll
        for (int kk = 0; kk < 16; ++kk) sS[tid][kk] = e[kk] * inv;
    }
    __syncthreads();
    float f = attf[0] * (1.0f / 32.0f);
    #pragma unroll
    for (int rep = 0; rep < 8; ++rep) {
        int i = rep * 256 + tid;          // h*256 + q*16 + t
        int h = i >> 8, qq = (i >> 4) & 15, tt = i & 15;
        sA[h][qq][tt] = sS[qq][tt] + f * att_sum[((size_t)n * H_ + h) * 256 + qq * 16 + tt];
    }
    __syncthreads();
    for (int rep = 0; rep < 256; ++rep) {
        int i = rep * 256 + tid;          // q*4096 + h*512 + d
        int qq = i >> 12, h = (i >> 9) & 7, d = i & 511;
        float acc = 0.f;
        #pragma unroll
        for (int tt = 0; tt < 16; ++tt) acc += sA[h][qq][tt] * sX[tt][d];
        sib[(size_t)n * T_ * 4096 + i] = f2bf(acc);
    }
}

// ---------------- positional encoding ------------------------------------------------
__global__ void pe_kernel(float* pe) {
    int i = blockIdx.x * blockDim.x + threadIdx.x;
    if (i >= T_ * 256) return;
    int t = i >> 8, j = i & 255;
    float dv = (float)pow(10000.0, (double)j / 256.0);
    float a = (float)t * dv;
    double ad = (double)a;
    pe[t * D_ + 2 * j]     = (float)sin(ad);
    pe[t * D_ + 2 * j + 1] = (float)cos(ad);
}

// ---------------- x features + embed -------------------------------------------------
__global__ void xemb_kernel(const float* x, const float* Wx, const float* bx,
                            const float* pe, float* xemb) {
    int row = blockIdx.x;              // t*N + n
    int t = row / N_, n = row % N_;
    float x0 = x[row * 6 + 0], x1 = x[row * 6 + 1];
    float x2 = x[row * 6 + 2], x3 = x[row * 6 + 3];
    float x4 = x[row * 6 + 4], x5 = x[row * 6 + 5];
    float vel = sqrtf(x2 * x2 + x3 * x3);
    float ang = atanf(x5 / x4);
    float f0 = ntn(x0), f1 = ntn(x1), f2 = ntn(vel), f3 = ntn(ang);
    for (int d = threadIdx.x; d < D_; d += blockDim.x) {
        xemb[((size_t)n * T_ + t) * D_ + d] =
            f0 * Wx[0 * D_ + d] + f1 * Wx[1 * D_ + d]
          + f2 * Wx[2 * D_ + d] + f3 * Wx[3 * D_ + d]
          + bx[d] + pe[t * D_ + d];
    }
}

// ---------------- neighbor features + mask -------------------------------------------
__global__ void nbr_kernel(const float* x, const float* nbr, float* nf, float* maskf) {
    int idx = blockIdx.x * blockDim.x + threadIdx.x;   // t*N*NN + n*NN + m
    if (idx >= T_ * N_ * NN_) return;
    int m = idx % NN_;
    int tn = idx / NN_;
    int n = tn % N_, t = tn / N_;
    float px = x[((size_t)t * N_ + n) * 6 + 0];
    float py = x[((size_t)t * N_ + n) * 6 + 1];
    float vx, vy;
    if (t == 0) {
        vx = x[((size_t)1 * N_ + n) * 6 + 2];
        vy = x[((size_t)1 * N_ + n) * 6 + 3];
    } else {
        vx = px - x[((size_t)(t - 1) * N_ + n) * 6 + 0];
        vy = py - x[((size_t)(t - 1) * N_ + n) * 6 + 1];
    }
    float nx  = nbr[(size_t)idx * 4 + 0], ny  = nbr[(size_t)idx * 4 + 1];
    float nvx = nbr[(size_t)idx * 4 + 2], nvy = nbr[(size_t)idx * 4 + 3];
    float dpx = nx - px, dpy = ny - py;
    float dvx = nvx - vx, dvy = nvy - vy;
    float dist = sqrtf(dpx * dpx + dpy * dpy);
    maskf[((size_t)n * NN_ + m) * T_ + t] = (dist <= 2.0f) ? 1.0f : 0.0f;
    float vn = sqrtf(vx * vx + vy * vy);
    float bearing = (dpx * vx + dpy * vy) / (dist * vn);
    if (isnan(bearing)) bearing = 0.0f;
    float dvn = sqrtf(dvx * dvx + dvy * dvy);
    float tau = -(dpx * dvx + dpy * dvy) / dvn;
    if (isnan(tau)) tau = 0.0f;
    tau = fminf(fmaxf(tau, 0.0f), 7.0f);
    float mx_ = dpx + tau * dvx, my_ = dpy + tau * dvy;
    float mpd = sqrtf(mx_ * mx_ + my_ * my_);
    nf[(size_t)idx * 3 + 0] = ntn(dist);
    nf[(size_t)idx * 3 + 1] = ntn(bearing);
    nf[(size_t)idx * 3 + 2] = ntn(mpd);
}

// ---------------- neighbor embed: writes f32 A and bf16 Ab ---------------------------
__global__ void nemb_kernel(const float* nf, const float* Wn, const float* bn,
                            const float* pe, float* A, u16* Ab) {
    int row = blockIdx.x;              // (b*NN+m)*T + t
    int t = row % T_;
    int bm = row / T_;
    int m = bm % NN_, b = bm / NN_;
    size_t nfrow = (((size_t)t * N_ + b) * NN_ + m) * 3;
    float f0 = nf[nfrow], f1 = nf[nfrow + 1], f2 = nf[nfrow + 2];
    for (int d = threadIdx.x; d < D_; d += blockDim.x) {
        float v = f0 * Wn[d] + f1 * Wn[D_ + d] + f2 * Wn[2 * D_ + d]
                + bn[d] + pe[t * D_ + d];
        A[(size_t)row * D_ + d] = v;
        Ab[(size_t)row * D_ + d] = f2bf(v);
    }
}

// ---------------- LayerNorm, one wave per row, dual-width output ---------------------
__global__ __launch_bounds__(256) void ln_dual_kernel(
    const float* X, const float* g, const float* b, float* outF, u16* outB, int nrows) {
    int row = blockIdx.x * 4 + (threadIdx.x >> 6);
    if (row >= nrows) return;
    int lane = threadIdx.x & 63;
    const float* p = X + (size_t)row * D_;
    float v[8];
    float s = 0.f;
    #pragma unroll
    for (int r = 0; r < 8; ++r) { v[r] = p[lane + r * 64]; s += v[r]; }
    s = wave_sum(s);
    float mean = s * (1.0f / 512.0f);
    float vs = 0.f;
    #pragma unroll
    for (int r = 0; r < 8; ++r) { float d = v[r] - mean; vs += d * d; }
    vs = wave_sum(vs);
    float rstd = rsqrtf(vs * (1.0f / 512.0f) + 1e-5f);
    #pragma unroll
    for (int r = 0; r < 8; ++r) {
        int d = lane + r * 64;
        float o = (v[r] - mean) * rstd * g[d] + b[d];
        if (outF) outF[(size_t)row * D_ + d] = o;
        if (outB) outB[(size_t)row * D_ + d] = f2bf(o);
    }
}

// ---------------- prediction head + broadcast (f32 out) ------------------------------
__global__ void pred_kernel(const float* xemb, const float* Wp, const float* bp, float* o) {
    int idx = blockIdx.x * blockDim.x + threadIdx.x;
    if (idx >= N_ * T_ * 2) return;
    int c = idx & 1;
    int nt = idx >> 1;
    float acc = bp[c];
    for (int j = 0; j < D_; ++j) acc += xemb[(size_t)nt * D_ + j] * Wp[(size_t)j * 2 + c];
    o[idx] = acc;
}

__global__ void bcast_kernel(const float* o, float* out) {
    int idx = blockIdx.x * blockDim.x + threadIdx.x;   // ((p*T+t)*N+n)*2+c
    if (idx >= NPRED_ * T_ * N_ * 2) return;
    int c = idx & 1;
    int rest = idx >> 1;
    int n = rest % N_;
    rest /= N_;
    int t = rest % T_;
    out[idx] = o[((size_t)n * T_ + t) * 2 + c];
}

extern "C" void kernel_launch(void* const* d_in, const int* in_sizes, int n_in,
                              void* d_out, int out_size, void* d_ws, size_t ws_size,
                              hipStream_t stream) {
    (void)in_sizes; (void)n_in; (void)out_size; (void)ws_size;

    const float* x    = (const float*)d_in[0];
    const float* nbr  = (const float*)d_in[1];
    const float* attf = (const float*)d_in[2];
    const float* Wx   = (const float*)d_in[3];
    const float* bx   = (const float*)d_in[4];
    const float* Wn   = (const float*)d_in[5];
    const float* bn   = (const float*)d_in[6];
    const float* Wp   = (const float*)d_in[7];
    const float* bp   = (const float*)d_in[8];
    const float* WQ   = (const float*)d_in[9];
    const float* WK   = (const float*)d_in[10];
    const float* WV   = (const float*)d_in[11];
    const float* Wfc  = (const float*)d_in[12];
    const float* mlng = (const float*)d_in[13];
    const float* mlnb = (const float*)d_in[14];
    const float* WSI  = (const float*)d_in[15];
    const float* fsw1 = (const float*)d_in[16];
    const float* fsw2 = (const float*)d_in[17];
    const float* fsg  = (const float*)d_in[18];
    const float* fsb  = (const float*)d_in[19];
    const float* fiw1 = (const float*)d_in[20];
    const float* fiw2 = (const float*)d_in[21];
    const float* fig  = (const float*)d_in[22];
    const float* fib  = (const float*)d_in[23];

    char* w = (char*)d_ws;
    size_t off = 0;
    auto alloc = [&](size_t bytes) -> void* {
        void* p = w + off;
        off = (off + bytes + 255) & ~(size_t)255;
        return p;
    };
    const size_t MiB = 1024 * 1024;

    const int BM = N_ * NN_;          // 2048 (b,m) pairs
    const int ROWS_I = BM * T_;       // 32768 neighbor rows
    const int CB = 512;               // bm per chunk
    const int RC = CB * T_;           // 8192 rows per chunk
    const int NCH = ROWS_I / RC;      // 4

    float* pe      = (float*)alloc((size_t)T_ * D_ * 4);
    float* xemb    = (float*)alloc((size_t)N_ * T_ * D_ * 4);
    float* nf      = (float*)alloc((size_t)T_ * N_ * NN_ * 3 * 4);
    float* maskf   = (float*)alloc((size_t)BM * T_ * 4);
    float* A       = (float*)alloc((size_t)ROWS_I * D_ * 4);   // n_emb f32   64 MiB
    u16*   Ab      = (u16*)alloc((size_t)ROWS_I * D_ * 2);     // n_emb bf16  32 MiB
    // bf16 transposed weights; QKV concatenated [1536][512]
    u16* tQKV[2], *tWSI[2], *tfs1[2], *tfs2[2];
    for (int l = 0; l < 2; ++l) {
        tQKV[l] = (u16*)alloc((size_t)1536 * 512 * 2);
        tWSI[l] = (u16*)alloc((size_t)512 * 4096 * 2);
        tfs1[l] = (u16*)alloc((size_t)2048 * 512 * 2);
        tfs2[l] = (u16*)alloc((size_t)512 * 2048 * 2);
    }
    u16* tWfc = (u16*)alloc((size_t)512 * 512 * 2);
    u16* tfi1 = (u16*)alloc((size_t)2048 * 512 * 2);
    u16* tfi2 = (u16*)alloc((size_t)512 * 2048 * 2);
    // scratch union: QKVb (24 MiB) + ctxb (8 MiB)  vs  hid (32 MiB)
    char* SCR  = (char*)alloc(36 * MiB);
    u16*   QKVb = (u16*)SCR;
    u16*   ctxb = (u16*)(SCR + 24 * MiB);
    u16*   hid  = (u16*)SCR;
    float* Bch  = (float*)alloc((size_t)RC * D_ * 4);  // res_inter chunk f32  16 MiB
    u16*   Bbch = (u16*)alloc((size_t)RC * D_ * 2);    //                       8 MiB
    float* att_sum = (float*)alloc((size_t)N_ * H_ * 256 * 4);
    u16*   sib     = (u16*)alloc((size_t)N_ * T_ * 4096 * 2);  // 8 MiB
    float* xnew    = (float*)alloc((size_t)N_ * T_ * D_ * 4);
    u16*   xnb     = (u16*)alloc((size_t)N_ * T_ * D_ * 2);
    float* osm     = (float*)alloc((size_t)N_ * T_ * 2 * 4);
    // total ~196 MiB

    // ---- one-time weight conversion ----
    auto wT = [&](const float* src, u16* dst, int K, int N) {
        wconv_kernel<<<dim3(N / 32, K / 32), 256, 0, stream>>>(src, dst, K, N);
    };
    for (int l = 0; l < 2; ++l) {
        wT(WQ + (size_t)l * 512 * 512, tQKV[l],                  512, 512);
        wT(WK + (size_t)l * 512 * 512, tQKV[l] + 512 * 512,      512, 512);
        if (l == 0) wT(WV, tQKV[0] + 1024 * 512, 512, 512);      // V dead at l=1
        wT(WSI  + (size_t)l * 4096 * 512, tWSI[l], 4096, 512);
        wT(fsw1 + (size_t)l * 512 * 2048, tfs1[l], 512, 2048);
        wT(fsw2 + (size_t)l * 2048 * 512, tfs2[l], 2048, 512);
    }
    wT(Wfc, tWfc, 512, 512);
    wT(fiw1, tfi1, 512, 2048);
    wT(fiw2, tfi2, 2048, 512);

    pe_kernel<<<16, 256, 0, stream>>>(pe);
    xemb_kernel<<<T_ * N_, 256, 0, stream>>>(x, Wx, bx, pe, xemb);
    nbr_kernel<<<(T_ * N_ * NN_ + 255) / 256, 256, 0, stream>>>(x, nbr, nf, maskf);
    nemb_kernel<<<BM * T_, 256, 0, stream>>>(nf, Wn, bn, pe, A, Ab);

    for (int l = 0; l < L_; ++l) {
        hipMemsetAsync(att_sum, 0, (size_t)N_ * H_ * 256 * 4, stream);
        for (int c = 0; c < NCH; ++c) {
            const u16* Acb = Ab + (size_t)c * RC * D_;
            float*     Acf = A  + (size_t)c * RC * D_;
            if (l == 0) {
                // QKV fused GEMM: N=1536
                gemm_bt<128, 128, 0, 0, 1><<<dim3(12, RC / 128), 256, 0, stream>>>(
                    Acb, tQKV[0], nullptr, QKVb, nullptr, 512, 1536);
                attn_fused_kernel<1><<<CB, 256, 0, stream>>>(
                    QKVb, maskf, c * CB, att_sum, ctxb);
                // fc + residual(n_emb f32) -> Bch f32 (64x64 tiles: 1024 blocks)
                gemm_bt<64, 64, 2, 1, 0><<<dim3(8, RC / 64), 256, 0, stream>>>(
                    ctxb, tWfc, Bch, nullptr, Acf, 512, 512);
                ln_dual_kernel<<<RC / 4, 256, 0, stream>>>(
                    Bch, mlng, mlnb, Bch, Bbch, RC);
                // ffi1 relu -> hid (aliases QKVb/ctxb, both consumed)
                gemm_bt<128, 128, 1, 0, 1><<<dim3(16, RC / 128), 256, 0, stream>>>(
                    Bbch, tfi1, nullptr, hid, nullptr, 512, 2048);
                // ffi2 + residual(res_inter) -> pre-LN into dead f32 n_emb chunk
                gemm_bt<64, 64, 2, 1, 0><<<dim3(8, RC / 64), 256, 0, stream>>>(
                    hid, tfi2, Acf, nullptr, Bch, 2048, 512);
                ln_dual_kernel<<<RC / 4, 256, 0, stream>>>(
                    Acf, fig, fib, nullptr, (u16*)Acb, RC);
            } else {
                // QK only: N=1024 (same 1536-stride output buffer)
                gemm_bt<128, 128, 0, 0, 1><<<dim3(8, RC / 128), 256, 0, stream>>>(
                    Acb, tQKV[1], nullptr, QKVb, nullptr, 512, 1536);
                attn_fused_kernel<0><<<CB, 256, 0, stream>>>(
                    QKVb, maskf, c * CB, att_sum, nullptr);
            }
        }

        // ---- self-attention + si + ffs (updates xemb) ----
        siatt_kernel<<<N_, 256, 0, stream>>>(xemb, att_sum, attf, sib);
        gemm_bt<64, 64, 0, 1, 1><<<dim3(8, 16), 256, 0, stream>>>(
            sib, tWSI[l], xnew, xnb, nullptr, 4096, 512);
        gemm_bt<64, 64, 1, 0, 1><<<dim3(32, 16), 256, 0, stream>>>(
            xnb, tfs1[l], nullptr, hid, nullptr, 512, 2048);
        gemm_bt<64, 64, 2, 1, 0><<<dim3(8, 16), 256, 0, stream>>>(
            hid, tfs2[l], xemb, nullptr, xnew, 2048, 512);
        ln_dual_kernel<<<(N_ * T_) / 4, 256, 0, stream>>>(
            xemb, fsg + l * D_, fsb + l * D_, xemb, nullptr, N_ * T_);
    }

    pred_kernel<<<(N_ * T_ * 2 + 255) / 256, 256, 0, stream>>>(xemb, Wp, bp, osm);
    bcast_kernel<<<(NPRED_ * T_ * N_ * 2 + 255) / 256, 256, 0, stream>>>(osm, (float*)d_out);
}

// Round 9
// 1190.776 us; speedup vs baseline: 41.2753x; 1.0775x over previous
//
#include <hip/hip_runtime.h>
#include <math.h>

// DTYPE COMMITMENTS (evidence-backed): inputs f32, output f32 (rounds 4-7 PASS).
// WS BUDGET: <= ~210 MB decimal; this build ~196 MiB.

#define T_ 16
#define N_ 64
#define NN_ 32
#define D_ 512
#define H_ 8
#define DK_ 64
#define DFF_ 2048
#define L_ 2
#define NPRED_ 20

typedef unsigned short u16;
typedef unsigned int u32;
typedef __attribute__((ext_vector_type(8))) short short8;
typedef __attribute__((ext_vector_type(4))) float f32x4;

__device__ __forceinline__ u16 f2bf(float f) {
    u32 u = __float_as_uint(f);
    u32 r = u + 0x7fffu + ((u >> 16) & 1u);
    return (u16)(r >> 16);
}
__device__ __forceinline__ float bfv(u16 v) {
    return __uint_as_float(((u32)v) << 16);
}
__device__ __forceinline__ float ntn(float v) {
    if (isnan(v)) return 0.0f;
    if (isinf(v)) return v > 0.0f ? 3.4028234663852886e38f : -3.4028234663852886e38f;
    return v;
}
__device__ __forceinline__ float wave_sum(float v) {
    #pragma unroll
    for (int o = 32; o > 0; o >>= 1) v += __shfl_xor(v, o, 64);
    return v;
}
// async 16B HBM->LDS: writes ldsbase + lane*16 (wave-uniform base, per-lane gptr)
__device__ __forceinline__ void gload_lds(const u16* g, u16* l) {
    __builtin_amdgcn_global_load_lds(
        (const __attribute__((address_space(1))) u32*)g,
        (__attribute__((address_space(3))) u32*)l, 16, 0, 0);
}

// ============ weight convert+transpose: in[K][N] f32 -> out[N][K] bf16 ==============
__global__ __launch_bounds__(256) void wconv_kernel(const float* in, u16* out, int K, int N) {
    __shared__ float tile[32][33];
    int kb = blockIdx.y * 32, nb = blockIdx.x * 32;
    int tx = threadIdx.x & 31, ty = threadIdx.x >> 5;
    #pragma unroll
    for (int r = ty; r < 32; r += 8)
        tile[r][tx] = in[(size_t)(kb + r) * N + nb + tx];
    __syncthreads();
    #pragma unroll
    for (int r = ty; r < 32; r += 8)
        out[(size_t)(nb + r) * K + kb + tx] = f2bf(tile[tx][r]);
}

// ============ MFMA GEMM v3: C[MxN] = A[MxK] @ Bt[NxK]^T, global_load_lds staging ====
// Unpadded LDS [rows][64] u16. DMA writes lane l at stored chunk l&7, row group+l>>3;
// lane fetches logical chunk (l&7)^(l>>3)  =>  stored[sc] holds logical sc^(row&7).
// Fragment read of logical chunk (s*4+quad) at row r uses stored ((s*4+quad)^(r&7)),
// r&7 == l16&7 for all fragment rows. Bank check: lanes l16 / l16+8 share a stored
// chunk across different rows -> 2-way (free, m136); quartets hit disjoint banks.
// 4 waves 2x2; EPI: 0 none, 1 relu, 2 +residual f32. Grid (N/TN, M/TM), K%64==0.
template<int TM, int TN, int EPI, int WF32, int WBF16>
__global__ __launch_bounds__(256) void gemm_bt(
    const u16* __restrict__ Ab, const u16* __restrict__ Btb,
    float* __restrict__ Cf, u16* __restrict__ Cb, const float* __restrict__ Rg,
    int K, int ldc)
{
    constexpr int WR = TM / 32, WC = TN / 32;
    constexpr int ITA = TM / 32, ITB = TN / 32;   // global_load_lds per wave
    __shared__ __align__(16) u16 As[TM][64];
    __shared__ __align__(16) u16 Bs[TN][64];
    int tid = threadIdx.x;
    int lane = tid & 63, wave = tid >> 6;
    int quad = lane >> 4, l16 = lane & 15;
    int wm = (wave >> 1) * (TM / 2), wn = (wave & 1) * (TN / 2);
    size_t row0 = (size_t)blockIdx.y * TM;
    size_t col0 = (size_t)blockIdx.x * TN;

    f32x4 acc[WR][WC];
    #pragma unroll
    for (int i = 0; i < WR; ++i)
        #pragma unroll
        for (int j = 0; j < WC; ++j)
            acc[i][j] = (f32x4){0.f, 0.f, 0.f, 0.f};

    int srow = lane >> 3;                  // 0..7 row within 8-row group
    int c8 = (lane & 7) ^ srow;            // logical 16B-chunk this lane fetches
    int h8 = l16 & 7;                      // row&7 of every fragment row this lane reads

    for (int k0 = 0; k0 < K; k0 += 64) {
        __syncthreads();
        #pragma unroll
        for (int it = 0; it < ITA; ++it) {
            int g = wave + it * 4;
            gload_lds(Ab + (row0 + g * 8 + srow) * (size_t)K + k0 + c8 * 8, &As[g * 8][0]);
        }
        #pragma unroll
        for (int it = 0; it < ITB; ++it) {
            int g = wave + it * 4;
            gload_lds(Btb + (col0 + g * 8 + srow) * (size_t)K + k0 + c8 * 8, &Bs[g * 8][0]);
        }
        __syncthreads();
        #pragma unroll
        for (int s = 0; s < 2; ++s) {
            int coff = ((s * 4 + quad) ^ h8) * 8;   // full 3-bit XOR (r8 fix: was split
                                                    // quad^h8 which overflows the row)
            short8 af[WR], bf[WC];
            #pragma unroll
            for (int i = 0; i < WR; ++i)
                af[i] = *(short8*)&As[wm + i * 16 + l16][coff];
            #pragma unroll
            for (int j = 0; j < WC; ++j)
                bf[j] = *(short8*)&Bs[wn + j * 16 + l16][coff];
            #pragma unroll
            for (int i = 0; i < WR; ++i)
                #pragma unroll
                for (int j = 0; j < WC; ++j)
                    acc[i][j] = __builtin_amdgcn_mfma_f32_16x16x32_bf16(
                        af[i], bf[j], acc[i][j], 0, 0, 0);
        }
    }
    // C/D layout (on-target verified): col = lane&15, row = quad*4 + reg
    #pragma unroll
    for (int i = 0; i < WR; ++i)
        #pragma unroll
        for (int j = 0; j < WC; ++j)
            #pragma unroll
            for (int reg = 0; reg < 4; ++reg) {
                size_t row = row0 + wm + i * 16 + quad * 4 + reg;
                size_t col = col0 + wn + j * 16 + l16;
                float v = acc[i][j][reg];
                if (EPI == 2) v += Rg[row * (size_t)ldc + col];
                if (EPI == 1) v = fmaxf(v, 0.f);
                if (WF32)  Cf[row * (size_t)ldc + col] = v;
                if (WBF16) Cb[row * (size_t)ldc + col] = f2bf(v);
            }
}

// ============ fused attention per (b,m): scores+softmax+att_sum+ctx =================
template<int CTX>
__global__ __launch_bounds__(256) void attn_fused_kernel(
    const u16* __restrict__ QKVb, const float* __restrict__ maskf, int bm0,
    float* __restrict__ att_sum, u16* __restrict__ ctxb)
{
    __shared__ __align__(16) u16 sQ[16][520];
    __shared__ __align__(16) u16 sK[16][520];
    __shared__ __align__(16) u16 sV[CTX ? 16 : 1][520];
    __shared__ float s_p[16][17];
    int bm_l = blockIdx.x;
    int tid = threadIdx.x;
    int t = tid >> 4, ch = (tid & 15) * 32;
    const u16* base = QKVb + ((size_t)bm_l * T_ + t) * 1536;
    #pragma unroll
    for (int c = 0; c < 4; ++c) {
        *(uint4*)&sQ[t][ch + c * 8] = *(const uint4*)(base + ch + c * 8);
        *(uint4*)&sK[t][ch + c * 8] = *(const uint4*)(base + 512 + ch + c * 8);
        if (CTX) *(uint4*)&sV[t][ch + c * 8] = *(const uint4*)(base + 1024 + ch + c * 8);
    }
    __syncthreads();

    int q = tid >> 4, k = tid & 15;
    float maskq = maskf[(size_t)(bm0 + bm_l) * T_ + q];
    int b = (bm0 + bm_l) >> 5;

    for (int h = 0; h < H_; ++h) {
        {
            const u32* qu = (const u32*)&sQ[q][0] + h * 32;
            const u32* ku = (const u32*)&sK[k][0] + h * 32;
            float acc = 0.f;
            #pragma unroll
            for (int j = 0; j < 32; ++j) {
                u32 a = qu[j], bb = ku[j];
                acc += bfv((u16)(a & 0xffff)) * bfv((u16)(bb & 0xffff));
                acc += bfv((u16)(a >> 16))    * bfv((u16)(bb >> 16));
            }
            acc *= 0.125f;
            if (maskq == 0.0f) acc = -1e9f;
            s_p[q][k] = acc;
        }
        __syncthreads();
        if (tid < T_) {
            float mx = -3.4e38f;
            #pragma unroll
            for (int kk = 0; kk < 16; ++kk) mx = fmaxf(mx, s_p[tid][kk]);
            float e[16], s = 0.f;
            #pragma unroll
            for (int kk = 0; kk < 16; ++kk) { e[kk] = expf(s_p[tid][kk] - mx); s += e[kk]; }
            float inv = 1.0f / s;
            #pragma unroll
            for (int kk = 0; kk < 16; ++kk) s_p[tid][kk] = e[kk] * inv;
        }
        __syncthreads();
        atomicAdd(&att_sum[(((size_t)b * H_ + h) * T_ + q) * T_ + k], s_p[q][k]);
        if (CTX) {
            #pragma unroll
            for (int rep = 0; rep < 4; ++rep) {
                int i = rep * 256 + tid;
                int tt = i >> 6, dk = i & 63;
                float acc = 0.f;
                #pragma unroll
                for (int kk = 0; kk < 16; ++kk)
                    acc += s_p[tt][kk] * bfv(sV[kk][h * DK_ + dk]);
                ctxb[((size_t)bm_l * T_ + tt) * D_ + h * DK_ + dk] = f2bf(acc);
            }
        }
        __syncthreads();
    }
}

// ============ fused self-attention + combine + si, one block per n ==================
__global__ __launch_bounds__(256) void siatt_kernel(
    const float* __restrict__ xemb, const float* __restrict__ att_sum,
    const float* __restrict__ attf, u16* __restrict__ sib)
{
    __shared__ float sX[16][516];
    __shared__ float sS[16][17];
    __shared__ float sA[H_][16][17];
    int n = blockIdx.x, tid = threadIdx.x;
    int t = tid >> 4, ch = (tid & 15) * 32;
    const float* src = xemb + ((size_t)n * T_ + t) * D_;
    #pragma unroll
    for (int c = 0; c < 8; ++c)
        *(float4*)&sX[t][ch + c * 4] = *(const float4*)(src + ch + c * 4);
    __syncthreads();
    int q = tid >> 4, k = tid & 15;
    {
        float acc = 0.f;
        for (int d = 0; d < D_; ++d) acc += sX[q][d] * sX[k][d];
        sS[q][k] = acc * 0.04419417382415922f;
    }
    __syncthreads();
    if (tid < T_) {
        float mx = -3.4e38f;
        #pragma unroll
        for (int kk = 0; kk < 16; ++kk) mx = fmaxf(mx, sS[tid][kk]);
        float e[16], s = 0.f;
        #pragma unroll
        for (int kk = 0; kk < 16; ++kk) { e[kk] = expf(sS[tid][kk] - mx); s += e[kk]; }
        float inv = 1.0f / s;
        #pragma unroll
        for (int kk = 0; kk < 16; ++kk) sS[tid][kk] = e[kk] * inv;
    }
    __syncthreads();
    float f = attf[0] * (1.0f / 32.0f);
    #pragma unroll
    for (int rep = 0; rep < 8; ++rep) {
        int i = rep * 256 + tid;
        int h = i >> 8, qq = (i >> 4) & 15, tt = i & 15;
        sA[h][qq][tt] = sS[qq][tt] + f * att_sum[((size_t)n * H_ + h) * 256 + qq * 16 + tt];
    }
    __syncthreads();
    for (int rep = 0; rep < 256; ++rep) {
        int i = rep * 256 + tid;
        int qq = i >> 12, h = (i >> 9) & 7, d = i & 511;
        float acc = 0.f;
        #pragma unroll
        for (int tt = 0; tt < 16; ++tt) acc += sA[h][qq][tt] * sX[tt][d];
        sib[(size_t)n * T_ * 4096 + i] = f2bf(acc);
    }
}

// ---------------- positional encoding ------------------------------------------------
__global__ void pe_kernel(float* pe) {
    int i = blockIdx.x * blockDim.x + threadIdx.x;
    if (i >= T_ * 256) return;
    int t = i >> 8, j = i & 255;
    float dv = (float)pow(10000.0, (double)j / 256.0);
    float a = (float)t * dv;
    double ad = (double)a;
    pe[t * D_ + 2 * j]     = (float)sin(ad);
    pe[t * D_ + 2 * j + 1] = (float)cos(ad);
}

// ---------------- x features + embed -------------------------------------------------
__global__ void xemb_kernel(const float* x, const float* Wx, const float* bx,
                            const float* pe, float* xemb) {
    int row = blockIdx.x;              // t*N + n
    int t = row / N_, n = row % N_;
    float x0 = x[row * 6 + 0], x1 = x[row * 6 + 1];
    float x2 = x[row * 6 + 2], x3 = x[row * 6 + 3];
    float x4 = x[row * 6 + 4], x5 = x[row * 6 + 5];
    float vel = sqrtf(x2 * x2 + x3 * x3);
    float ang = atanf(x5 / x4);
    float f0 = ntn(x0), f1 = ntn(x1), f2 = ntn(vel), f3 = ntn(ang);
    for (int d = threadIdx.x; d < D_; d += blockDim.x) {
        xemb[((size_t)n * T_ + t) * D_ + d] =
            f0 * Wx[0 * D_ + d] + f1 * Wx[1 * D_ + d]
          + f2 * Wx[2 * D_ + d] + f3 * Wx[3 * D_ + d]
          + bx[d] + pe[t * D_ + d];
    }
}

// ---------------- neighbor features + mask -------------------------------------------
__global__ void nbr_kernel(const float* x, const float* nbr, float* nf, float* maskf) {
    int idx = blockIdx.x * blockDim.x + threadIdx.x;   // t*N*NN + n*NN + m
    if (idx >= T_ * N_ * NN_) return;
    int m = idx % NN_;
    int tn = idx / NN_;
    int n = tn % N_, t = tn / N_;
    float px = x[((size_t)t * N_ + n) * 6 + 0];
    float py = x[((size_t)t * N_ + n) * 6 + 1];
    float vx, vy;
    if (t == 0) {
        vx = x[((size_t)1 * N_ + n) * 6 + 2];
        vy = x[((size_t)1 * N_ + n) * 6 + 3];
    } else {
        vx = px - x[((size_t)(t - 1) * N_ + n) * 6 + 0];
        vy = py - x[((size_t)(t - 1) * N_ + n) * 6 + 1];
    }
    float nx  = nbr[(size_t)idx * 4 + 0], ny  = nbr[(size_t)idx * 4 + 1];
    float nvx = nbr[(size_t)idx * 4 + 2], nvy = nbr[(size_t)idx * 4 + 3];
    float dpx = nx - px, dpy = ny - py;
    float dvx = nvx - vx, dvy = nvy - vy;
    float dist = sqrtf(dpx * dpx + dpy * dpy);
    maskf[((size_t)n * NN_ + m) * T_ + t] = (dist <= 2.0f) ? 1.0f : 0.0f;
    float vn = sqrtf(vx * vx + vy * vy);
    float bearing = (dpx * vx + dpy * vy) / (dist * vn);
    if (isnan(bearing)) bearing = 0.0f;
    float dvn = sqrtf(dvx * dvx + dvy * dvy);
    float tau = -(dpx * dvx + dpy * dvy) / dvn;
    if (isnan(tau)) tau = 0.0f;
    tau = fminf(fmaxf(tau, 0.0f), 7.0f);
    float mx_ = dpx + tau * dvx, my_ = dpy + tau * dvy;
    float mpd = sqrtf(mx_ * mx_ + my_ * my_);
    nf[(size_t)idx * 3 + 0] = ntn(dist);
    nf[(size_t)idx * 3 + 1] = ntn(bearing);
    nf[(size_t)idx * 3 + 2] = ntn(mpd);
}

// ---------------- neighbor embed: writes f32 A and bf16 Ab ---------------------------
__global__ void nemb_kernel(const float* nf, const float* Wn, const float* bn,
                            const float* pe, float* A, u16* Ab) {
    int row = blockIdx.x;              // (b*NN+m)*T + t
    int t = row % T_;
    int bm = row / T_;
    int m = bm % NN_, b = bm / NN_;
    size_t nfrow = (((size_t)t * N_ + b) * NN_ + m) * 3;
    float f0 = nf[nfrow], f1 = nf[nfrow + 1], f2 = nf[nfrow + 2];
    for (int d = threadIdx.x; d < D_; d += blockDim.x) {
        float v = f0 * Wn[d] + f1 * Wn[D_ + d] + f2 * Wn[2 * D_ + d]
                + bn[d] + pe[t * D_ + d];
        A[(size_t)row * D_ + d] = v;
        Ab[(size_t)row * D_ + d] = f2bf(v);
    }
}

// ---------------- LayerNorm, one wave per row, dual-width output ---------------------
__global__ __launch_bounds__(256) void ln_dual_kernel(
    const float* X, const float* g, const float* b, float* outF, u16* outB, int nrows) {
    int row = blockIdx.x * 4 + (threadIdx.x >> 6);
    if (row >= nrows) return;
    int lane = threadIdx.x & 63;
    const float* p = X + (size_t)row * D_;
    float v[8];
    float s = 0.f;
    #pragma unroll
    for (int r = 0; r < 8; ++r) { v[r] = p[lane + r * 64]; s += v[r]; }
    s = wave_sum(s);
    float mean = s * (1.0f / 512.0f);
    float vs = 0.f;
    #pragma unroll
    for (int r = 0; r < 8; ++r) { float d = v[r] - mean; vs += d * d; }
    vs = wave_sum(vs);
    float rstd = rsqrtf(vs * (1.0f / 512.0f) + 1e-5f);
    #pragma unroll
    for (int r = 0; r < 8; ++r) {
        int d = lane + r * 64;
        float o = (v[r] - mean) * rstd * g[d] + b[d];
        if (outF) outF[(size_t)row * D_ + d] = o;
        if (outB) outB[(size_t)row * D_ + d] = f2bf(o);
    }
}

// ---------------- prediction head + broadcast (f32 out) ------------------------------
__global__ void pred_kernel(const float* xemb, const float* Wp, const float* bp, float* o) {
    int idx = blockIdx.x * blockDim.x + threadIdx.x;
    if (idx >= N_ * T_ * 2) return;
    int c = idx & 1;
    int nt = idx >> 1;
    float acc = bp[c];
    for (int j = 0; j < D_; ++j) acc += xemb[(size_t)nt * D_ + j] * Wp[(size_t)j * 2 + c];
    o[idx] = acc;
}

__global__ void bcast_kernel(const float* o, float* out) {
    int idx = blockIdx.x * blockDim.x + threadIdx.x;   // ((p*T+t)*N+n)*2+c
    if (idx >= NPRED_ * T_ * N_ * 2) return;
    int c = idx & 1;
    int rest = idx >> 1;
    int n = rest % N_;
    rest /= N_;
    int t = rest % T_;
    out[idx] = o[((size_t)n * T_ + t) * 2 + c];
}

extern "C" void kernel_launch(void* const* d_in, const int* in_sizes, int n_in,
                              void* d_out, int out_size, void* d_ws, size_t ws_size,
                              hipStream_t stream) {
    (void)in_sizes; (void)n_in; (void)out_size; (void)ws_size;

    const float* x    = (const float*)d_in[0];
    const float* nbr  = (const float*)d_in[1];
    const float* attf = (const float*)d_in[2];
    const float* Wx   = (const float*)d_in[3];
    const float* bx   = (const float*)d_in[4];
    const float* Wn   = (const float*)d_in[5];
    const float* bn   = (const float*)d_in[6];
    const float* Wp   = (const float*)d_in[7];
    const float* bp   = (const float*)d_in[8];
    const float* WQ   = (const float*)d_in[9];
    const float* WK   = (const float*)d_in[10];
    const float* WV   = (const float*)d_in[11];
    const float* Wfc  = (const float*)d_in[12];
    const float* mlng = (const float*)d_in[13];
    const float* mlnb = (const float*)d_in[14];
    const float* WSI  = (const float*)d_in[15];
    const float* fsw1 = (const float*)d_in[16];
    const float* fsw2 = (const float*)d_in[17];
    const float* fsg  = (const float*)d_in[18];
    const float* fsb  = (const float*)d_in[19];
    const float* fiw1 = (const float*)d_in[20];
    const float* fiw2 = (const float*)d_in[21];
    const float* fig  = (const float*)d_in[22];
    const float* fib  = (const float*)d_in[23];

    char* w = (char*)d_ws;
    size_t off = 0;
    auto alloc = [&](size_t bytes) -> void* {
        void* p = w + off;
        off = (off + bytes + 255) & ~(size_t)255;
        return p;
    };
    const size_t MiB = 1024 * 1024;

    const int BM = N_ * NN_;          // 2048 (b,m) pairs
    const int ROWS_I = BM * T_;       // 32768 neighbor rows
    const int CB = 512;               // bm per chunk
    const int RC = CB * T_;           // 8192 rows per chunk
    const int NCH = ROWS_I / RC;      // 4

    float* pe      = (float*)alloc((size_t)T_ * D_ * 4);
    float* xemb    = (float*)alloc((size_t)N_ * T_ * D_ * 4);
    float* nf      = (float*)alloc((size_t)T_ * N_ * NN_ * 3 * 4);
    float* maskf   = (float*)alloc((size_t)BM * T_ * 4);
    float* A       = (float*)alloc((size_t)ROWS_I * D_ * 4);   // n_emb f32   64 MiB
    u16*   Ab      = (u16*)alloc((size_t)ROWS_I * D_ * 2);     // n_emb bf16  32 MiB
    u16* tQKV[2], *tWSI[2], *tfs1[2], *tfs2[2];
    for (int l = 0; l < 2; ++l) {
        tQKV[l] = (u16*)alloc((size_t)1536 * 512 * 2);
        tWSI[l] = (u16*)alloc((size_t)512 * 4096 * 2);
        tfs1[l] = (u16*)alloc((size_t)2048 * 512 * 2);
        tfs2[l] = (u16*)alloc((size_t)512 * 2048 * 2);
    }
    u16* tWfc = (u16*)alloc((size_t)512 * 512 * 2);
    u16* tfi1 = (u16*)alloc((size_t)2048 * 512 * 2);
    u16* tfi2 = (u16*)alloc((size_t)512 * 2048 * 2);
    char* SCR  = (char*)alloc(36 * MiB);
    u16*   QKVb = (u16*)SCR;
    u16*   ctxb = (u16*)(SCR + 24 * MiB);
    u16*   hid  = (u16*)SCR;
    float* Bch  = (float*)alloc((size_t)RC * D_ * 4);  // res_inter chunk f32  16 MiB
    u16*   Bbch = (u16*)alloc((size_t)RC * D_ * 2);    //                       8 MiB
    float* att_sum = (float*)alloc((size_t)N_ * H_ * 256 * 4);
    u16*   sib     = (u16*)alloc((size_t)N_ * T_ * 4096 * 2);  // 8 MiB
    float* xnew    = (float*)alloc((size_t)N_ * T_ * D_ * 4);
    u16*   xnb     = (u16*)alloc((size_t)N_ * T_ * D_ * 2);
    float* osm     = (float*)alloc((size_t)N_ * T_ * 2 * 4);
    // total ~196 MiB

    auto wT = [&](const float* src, u16* dst, int K, int N) {
        wconv_kernel<<<dim3(N / 32, K / 32), 256, 0, stream>>>(src, dst, K, N);
    };
    for (int l = 0; l < 2; ++l) {
        wT(WQ + (size_t)l * 512 * 512, tQKV[l],                  512, 512);
        wT(WK + (size_t)l * 512 * 512, tQKV[l] + 512 * 512,      512, 512);
        if (l == 0) wT(WV, tQKV[0] + 1024 * 512, 512, 512);      // V dead at l=1
        wT(WSI  + (size_t)l * 4096 * 512, tWSI[l], 4096, 512);
        wT(fsw1 + (size_t)l * 512 * 2048, tfs1[l], 512, 2048);
        wT(fsw2 + (size_t)l * 2048 * 512, tfs2[l], 2048, 512);
    }
    wT(Wfc, tWfc, 512, 512);
    wT(fiw1, tfi1, 512, 2048);
    wT(fiw2, tfi2, 2048, 512);

    pe_kernel<<<16, 256, 0, stream>>>(pe);
    xemb_kernel<<<T_ * N_, 256, 0, stream>>>(x, Wx, bx, pe, xemb);
    nbr_kernel<<<(T_ * N_ * NN_ + 255) / 256, 256, 0, stream>>>(x, nbr, nf, maskf);
    nemb_kernel<<<BM * T_, 256, 0, stream>>>(nf, Wn, bn, pe, A, Ab);

    for (int l = 0; l < L_; ++l) {
        hipMemsetAsync(att_sum, 0, (size_t)N_ * H_ * 256 * 4, stream);
        for (int c = 0; c < NCH; ++c) {
            const u16* Acb = Ab + (size_t)c * RC * D_;
            float*     Acf = A  + (size_t)c * RC * D_;
            if (l == 0) {
                // QKV fused GEMM: N=1536, 128x128 tiles (768 blocks)
                gemm_bt<128, 128, 0, 0, 1><<<dim3(12, RC / 128), 256, 0, stream>>>(
                    Acb, tQKV[0], nullptr, QKVb, nullptr, 512, 1536);
                attn_fused_kernel<1><<<CB, 256, 0, stream>>>(
                    QKVb, maskf, c * CB, att_sum, ctxb);
                // fc + residual: N=512, 128x64 tiles (512 blocks)
                gemm_bt<128, 64, 2, 1, 0><<<dim3(8, RC / 128), 256, 0, stream>>>(
                    ctxb, tWfc, Bch, nullptr, Acf, 512, 512);
                ln_dual_kernel<<<RC / 4, 256, 0, stream>>>(
                    Bch, mlng, mlnb, Bch, Bbch, RC);
                // ffi1 relu: N=2048, 128x128 (1024 blocks); hid aliases QKVb/ctxb
                gemm_bt<128, 128, 1, 0, 1><<<dim3(16, RC / 128), 256, 0, stream>>>(
                    Bbch, tfi1, nullptr, hid, nullptr, 512, 2048);
                // ffi2 + residual: N=512, 128x64
                gemm_bt<128, 64, 2, 1, 0><<<dim3(8, RC / 128), 256, 0, stream>>>(
                    hid, tfi2, Acf, nullptr, Bch, 2048, 512);
                ln_dual_kernel<<<RC / 4, 256, 0, stream>>>(
                    Acf, fig, fib, nullptr, (u16*)Acb, RC);
            } else {
                // QK only: N=1024 (1536-stride output)
                gemm_bt<128, 128, 0, 0, 1><<<dim3(8, RC / 128), 256, 0, stream>>>(
                    Acb, tQKV[1], nullptr, QKVb, nullptr, 512, 1536);
                attn_fused_kernel<0><<<CB, 256, 0, stream>>>(
                    QKVb, maskf, c * CB, att_sum, nullptr);
            }
        }

        // ---- self-attention + si + ffs (updates xemb) ----
        siatt_kernel<<<N_, 256, 0, stream>>>(xemb, att_sum, attf, sib);
        gemm_bt<64, 64, 0, 1, 1><<<dim3(8, 16), 256, 0, stream>>>(
            sib, tWSI[l], xnew, xnb, nullptr, 4096, 512);
        gemm_bt<64, 64, 1, 0, 1><<<dim3(32, 16), 256, 0, stream>>>(
            xnb, tfs1[l], nullptr, hid, nullptr, 512, 2048);
        gemm_bt<64, 64, 2, 1, 0><<<dim3(8, 16), 256, 0, stream>>>(
            hid, tfs2[l], xemb, nullptr, xnew, 2048, 512);
        ln_dual_kernel<<<(N_ * T_) / 4, 256, 0, stream>>>(
            xemb, fsg + l * D_, fsb + l * D_, xemb, nullptr, N_ * T_);
    }

    pred_kernel<<<(N_ * T_ * 2 + 255) / 256, 256, 0, stream>>>(xemb, Wp, bp, osm);
    bcast_kernel<<<(NPRED_ * T_ * N_ * 2 + 255) / 256, 256, 0, stream>>>(osm, (float*)d_out);
}

// Round 10
// 1074.601 us; speedup vs baseline: 45.7375x; 1.1081x over previous
//
#include <hip/hip_runtime.h>
#include <math.h>

// DTYPE COMMITMENTS (evidence-backed): inputs f32, output f32 (rounds 4-9 PASS).
// WS BUDGET: <= ~210 MB decimal; this build ~196 MiB.

#define T_ 16
#define N_ 64
#define NN_ 32
#define D_ 512
#define H_ 8
#define DK_ 64
#define DFF_ 2048
#define L_ 2
#define NPRED_ 20

typedef unsigned short u16;
typedef unsigned int u32;
typedef __attribute__((ext_vector_type(8))) short short8;
typedef __attribute__((ext_vector_type(4))) float f32x4;

__device__ __forceinline__ u16 f2bf(float f) {
    u32 u = __float_as_uint(f);
    u32 r = u + 0x7fffu + ((u >> 16) & 1u);
    return (u16)(r >> 16);
}
__device__ __forceinline__ float bfv(u16 v) {
    return __uint_as_float(((u32)v) << 16);
}
__device__ __forceinline__ float ntn(float v) {
    if (isnan(v)) return 0.0f;
    if (isinf(v)) return v > 0.0f ? 3.4028234663852886e38f : -3.4028234663852886e38f;
    return v;
}
__device__ __forceinline__ float wave_sum(float v) {
    #pragma unroll
    for (int o = 32; o > 0; o >>= 1) v += __shfl_xor(v, o, 64);
    return v;
}
// async 16B HBM->LDS: writes ldsbase + lane*16 (wave-uniform base, per-lane gptr)
__device__ __forceinline__ void gload_lds(const u16* g, u16* l) {
    __builtin_amdgcn_global_load_lds(
        (const __attribute__((address_space(1))) u32*)g,
        (__attribute__((address_space(3))) u32*)l, 16, 0, 0);
}

// ============ weight convert+transpose: in[K][N] f32 -> out[N][K] bf16 ==============
__global__ __launch_bounds__(256) void wconv_kernel(const float* in, u16* out, int K, int N) {
    __shared__ float tile[32][33];
    int kb = blockIdx.y * 32, nb = blockIdx.x * 32;
    int tx = threadIdx.x & 31, ty = threadIdx.x >> 5;
    #pragma unroll
    for (int r = ty; r < 32; r += 8)
        tile[r][tx] = in[(size_t)(kb + r) * N + nb + tx];
    __syncthreads();
    #pragma unroll
    for (int r = ty; r < 32; r += 8)
        out[(size_t)(nb + r) * K + kb + tx] = f2bf(tile[tx][r]);
}

// ============ MFMA GEMM v3 + XCD-band remap =========================================
// Unpadded LDS [rows][64] u16, DMA staging + 3-bit XOR chunk swizzle (r9-verified:
// 0 bank conflicts). Block remap: xcd = id%8 owns contiguous row-bands, columns
// fastest within an XCD -> A row-band fetched once per XCD's L2, B (small) cached
// per-XCD. Pure permutation; speed heuristic only (G16-safe).
// EPI: 0 none, 1 relu, 2 +residual f32. Grid (N/TN, M/TM), gridY%8==0, K%64==0.
template<int TM, int TN, int EPI, int WF32, int WBF16>
__global__ __launch_bounds__(256) void gemm_bt(
    const u16* __restrict__ Ab, const u16* __restrict__ Btb,
    float* __restrict__ Cf, u16* __restrict__ Cb, const float* __restrict__ Rg,
    int K, int ldc)
{
    constexpr int WR = TM / 32, WC = TN / 32;
    constexpr int ITA = TM / 32, ITB = TN / 32;   // global_load_lds per wave
    __shared__ __align__(16) u16 As[TM][64];
    __shared__ __align__(16) u16 Bs[TN][64];
    int tid = threadIdx.x;
    int lane = tid & 63, wave = tid >> 6;
    int quad = lane >> 4, l16 = lane & 15;
    int wm = (wave >> 1) * (TM / 2), wn = (wave & 1) * (TN / 2);

    // XCD-aware remap (uniform): same row-band's column tiles stay on one XCD
    int gx = gridDim.x, gy = gridDim.y;
    int bx, by;
    if ((gy & 7) == 0) {
        int id = blockIdx.y * gx + blockIdx.x;
        int xcd = id & 7;
        int slot = id >> 3;
        bx = slot % gx;
        by = xcd * (gy >> 3) + slot / gx;
    } else {
        bx = blockIdx.x;
        by = blockIdx.y;
    }
    size_t row0 = (size_t)by * TM;
    size_t col0 = (size_t)bx * TN;

    f32x4 acc[WR][WC];
    #pragma unroll
    for (int i = 0; i < WR; ++i)
        #pragma unroll
        for (int j = 0; j < WC; ++j)
            acc[i][j] = (f32x4){0.f, 0.f, 0.f, 0.f};

    int srow = lane >> 3;                  // 0..7 row within 8-row group
    int c8 = (lane & 7) ^ srow;            // logical 16B-chunk this lane fetches
    int h8 = l16 & 7;                      // row&7 of every fragment row this lane reads

    for (int k0 = 0; k0 < K; k0 += 64) {
        __syncthreads();
        #pragma unroll
        for (int it = 0; it < ITA; ++it) {
            int g = wave + it * 4;
            gload_lds(Ab + (row0 + g * 8 + srow) * (size_t)K + k0 + c8 * 8, &As[g * 8][0]);
        }
        #pragma unroll
        for (int it = 0; it < ITB; ++it) {
            int g = wave + it * 4;
            gload_lds(Btb + (col0 + g * 8 + srow) * (size_t)K + k0 + c8 * 8, &Bs[g * 8][0]);
        }
        __syncthreads();
        #pragma unroll
        for (int s = 0; s < 2; ++s) {
            int coff = ((s * 4 + quad) ^ h8) * 8;   // full 3-bit XOR (r9-verified)
            short8 af[WR], bf[WC];
            #pragma unroll
            for (int i = 0; i < WR; ++i)
                af[i] = *(short8*)&As[wm + i * 16 + l16][coff];
            #pragma unroll
            for (int j = 0; j < WC; ++j)
                bf[j] = *(short8*)&Bs[wn + j * 16 + l16][coff];
            #pragma unroll
            for (int i = 0; i < WR; ++i)
                #pragma unroll
                for (int j = 0; j < WC; ++j)
                    acc[i][j] = __builtin_amdgcn_mfma_f32_16x16x32_bf16(
                        af[i], bf[j], acc[i][j], 0, 0, 0);
        }
    }
    // C/D layout (on-target verified): col = lane&15, row = quad*4 + reg
    #pragma unroll
    for (int i = 0; i < WR; ++i)
        #pragma unroll
        for (int j = 0; j < WC; ++j)
            #pragma unroll
            for (int reg = 0; reg < 4; ++reg) {
                size_t row = row0 + wm + i * 16 + quad * 4 + reg;
                size_t col = col0 + wn + j * 16 + l16;
                float v = acc[i][j][reg];
                if (EPI == 2) v += Rg[row * (size_t)ldc + col];
                if (EPI == 1) v = fmaxf(v, 0.f);
                if (WF32)  Cf[row * (size_t)ldc + col] = v;
                if (WBF16) Cb[row * (size_t)ldc + col] = f2bf(v);
            }
}

// ============ fused attention per (b,m): all-heads phases, 3 barriers ===============
// QKVb: [rows][1536] bf16 (Q 0..511, K 512..1023, V 1024..1535; col = h*64+dk).
template<int CTX>
__global__ __launch_bounds__(256) void attn_fused_kernel(
    const u16* __restrict__ QKVb, const float* __restrict__ maskf, int bm0,
    float* __restrict__ att_sum, u16* __restrict__ ctxb)
{
    __shared__ __align__(16) u16 sQ[16][520];
    __shared__ __align__(16) u16 sK[16][520];
    __shared__ __align__(16) u16 sV[CTX ? 16 : 1][520];
    __shared__ float s_p[H_][16][17];
    int bm_l = blockIdx.x;
    int tid = threadIdx.x;
    int t = tid >> 4, ch = (tid & 15) * 32;
    const u16* base = QKVb + ((size_t)bm_l * T_ + t) * 1536;
    #pragma unroll
    for (int c = 0; c < 4; ++c) {
        *(uint4*)&sQ[t][ch + c * 8] = *(const uint4*)(base + ch + c * 8);
        *(uint4*)&sK[t][ch + c * 8] = *(const uint4*)(base + 512 + ch + c * 8);
        if (CTX) *(uint4*)&sV[t][ch + c * 8] = *(const uint4*)(base + 1024 + ch + c * 8);
    }
    __syncthreads();

    int b = (bm0 + bm_l) >> 5;                  // bm = b*NN + m

    // Phase A: scores for all heads (item = h*256 + q*16 + k; h == r per pass)
    #pragma unroll
    for (int r = 0; r < 8; ++r) {
        int h = r;
        int q = (tid >> 4) & 15, k = tid & 15;
        const u32* qu = (const u32*)&sQ[q][0] + h * 32;
        const u32* ku = (const u32*)&sK[k][0] + h * 32;
        float acc = 0.f;
        #pragma unroll
        for (int j = 0; j < 32; ++j) {
            u32 a = qu[j], bb = ku[j];
            acc += bfv((u16)(a & 0xffff)) * bfv((u16)(bb & 0xffff));
            acc += bfv((u16)(a >> 16))    * bfv((u16)(bb >> 16));
        }
        acc *= 0.125f;
        if (maskf[(size_t)(bm0 + bm_l) * T_ + q] == 0.0f) acc = -1e9f;
        s_p[h][q][k] = acc;
    }
    __syncthreads();
    // Phase B: softmax over k for all 128 (h,q) rows
    if (tid < 128) {
        int h = tid >> 4, q = tid & 15;
        float mx = -3.4e38f;
        #pragma unroll
        for (int kk = 0; kk < 16; ++kk) mx = fmaxf(mx, s_p[h][q][kk]);
        float e[16], s = 0.f;
        #pragma unroll
        for (int kk = 0; kk < 16; ++kk) { e[kk] = expf(s_p[h][q][kk] - mx); s += e[kk]; }
        float inv = 1.0f / s;
        #pragma unroll
        for (int kk = 0; kk < 16; ++kk) s_p[h][q][kk] = e[kk] * inv;
    }
    __syncthreads();
    // Phase C: att_sum atomics + ctx
    #pragma unroll
    for (int r = 0; r < 8; ++r) {
        int h = r;
        int q = (tid >> 4) & 15, k = tid & 15;
        atomicAdd(&att_sum[(((size_t)b * H_ + h) * T_ + q) * T_ + k], s_p[h][q][k]);
    }
    if (CTX) {
        #pragma unroll
        for (int rep = 0; rep < 32; ++rep) {
            int i = rep * 256 + tid;            // t*512 + c, c = h*64+dk
            int tt = i >> 9, c = i & 511;
            int h = c >> 6;
            float acc = 0.f;
            #pragma unroll
            for (int kk = 0; kk < 16; ++kk)
                acc += s_p[h][tt][kk] * bfv(sV[kk][c]);
            ctxb[((size_t)bm_l * T_ + tt) * D_ + c] = f2bf(acc);
        }
    }
}

// ============ fused self-attention + combine + si, one block per n ==================
__global__ __launch_bounds__(256) void siatt_kernel(
    const float* __restrict__ xemb, const float* __restrict__ att_sum,
    const float* __restrict__ attf, u16* __restrict__ sib)
{
    __shared__ float sX[16][516];
    __shared__ float sS[16][17];
    __shared__ float sA[H_][16][17];
    int n = blockIdx.x, tid = threadIdx.x;
    int t = tid >> 4, ch = (tid & 15) * 32;
    const float* src = xemb + ((size_t)n * T_ + t) * D_;
    #pragma unroll
    for (int c = 0; c < 8; ++c)
        *(float4*)&sX[t][ch + c * 4] = *(const float4*)(src + ch + c * 4);
    __syncthreads();
    int q = tid >> 4, k = tid & 15;
    {
        float acc = 0.f;
        for (int d = 0; d < D_; ++d) acc += sX[q][d] * sX[k][d];
        sS[q][k] = acc * 0.04419417382415922f;
    }
    __syncthreads();
    if (tid < T_) {
        float mx = -3.4e38f;
        #pragma unroll
        for (int kk = 0; kk < 16; ++kk) mx = fmaxf(mx, sS[tid][kk]);
        float e[16], s = 0.f;
        #pragma unroll
        for (int kk = 0; kk < 16; ++kk) { e[kk] = expf(sS[tid][kk] - mx); s += e[kk]; }
        float inv = 1.0f / s;
        #pragma unroll
        for (int kk = 0; kk < 16; ++kk) sS[tid][kk] = e[kk] * inv;
    }
    __syncthreads();
    float f = attf[0] * (1.0f / 32.0f);
    #pragma unroll
    for (int rep = 0; rep < 8; ++rep) {
        int i = rep * 256 + tid;
        int h = i >> 8, qq = (i >> 4) & 15, tt = i & 15;
        sA[h][qq][tt] = sS[qq][tt] + f * att_sum[((size_t)n * H_ + h) * 256 + qq * 16 + tt];
    }
    __syncthreads();
    for (int rep = 0; rep < 256; ++rep) {
        int i = rep * 256 + tid;
        int qq = i >> 12, h = (i >> 9) & 7, d = i & 511;
        float acc = 0.f;
        #pragma unroll
        for (int tt = 0; tt < 16; ++tt) acc += sA[h][qq][tt] * sX[tt][d];
        sib[(size_t)n * T_ * 4096 + i] = f2bf(acc);
    }
}

// ---------------- positional encoding ------------------------------------------------
__global__ void pe_kernel(float* pe) {
    int i = blockIdx.x * blockDim.x + threadIdx.x;
    if (i >= T_ * 256) return;
    int t = i >> 8, j = i & 255;
    float dv = (float)pow(10000.0, (double)j / 256.0);
    float a = (float)t * dv;
    double ad = (double)a;
    pe[t * D_ + 2 * j]     = (float)sin(ad);
    pe[t * D_ + 2 * j + 1] = (float)cos(ad);
}

// ---------------- x features + embed -------------------------------------------------
__global__ void xemb_kernel(const float* x, const float* Wx, const float* bx,
                            const float* pe, float* xemb) {
    int row = blockIdx.x;              // t*N + n
    int t = row / N_, n = row % N_;
    float x0 = x[row * 6 + 0], x1 = x[row * 6 + 1];
    float x2 = x[row * 6 + 2], x3 = x[row * 6 + 3];
    float x4 = x[row * 6 + 4], x5 = x[row * 6 + 5];
    float vel = sqrtf(x2 * x2 + x3 * x3);
    float ang = atanf(x5 / x4);
    float f0 = ntn(x0), f1 = ntn(x1), f2 = ntn(vel), f3 = ntn(ang);
    for (int d = threadIdx.x; d < D_; d += blockDim.x) {
        xemb[((size_t)n * T_ + t) * D_ + d] =
            f0 * Wx[0 * D_ + d] + f1 * Wx[1 * D_ + d]
          + f2 * Wx[2 * D_ + d] + f3 * Wx[3 * D_ + d]
          + bx[d] + pe[t * D_ + d];
    }
}

// ---------------- neighbor features + mask -------------------------------------------
__global__ void nbr_kernel(const float* x, const float* nbr, float* nf, float* maskf) {
    int idx = blockIdx.x * blockDim.x + threadIdx.x;   // t*N*NN + n*NN + m
    if (idx >= T_ * N_ * NN_) return;
    int m = idx % NN_;
    int tn = idx / NN_;
    int n = tn % N_, t = tn / N_;
    float px = x[((size_t)t * N_ + n) * 6 + 0];
    float py = x[((size_t)t * N_ + n) * 6 + 1];
    float vx, vy;
    if (t == 0) {
        vx = x[((size_t)1 * N_ + n) * 6 + 2];
        vy = x[((size_t)1 * N_ + n) * 6 + 3];
    } else {
        vx = px - x[((size_t)(t - 1) * N_ + n) * 6 + 0];
        vy = py - x[((size_t)(t - 1) * N_ + n) * 6 + 1];
    }
    float nx  = nbr[(size_t)idx * 4 + 0], ny  = nbr[(size_t)idx * 4 + 1];
    float nvx = nbr[(size_t)idx * 4 + 2], nvy = nbr[(size_t)idx * 4 + 3];
    float dpx = nx - px, dpy = ny - py;
    float dvx = nvx - vx, dvy = nvy - vy;
    float dist = sqrtf(dpx * dpx + dpy * dpy);
    maskf[((size_t)n * NN_ + m) * T_ + t] = (dist <= 2.0f) ? 1.0f : 0.0f;
    float vn = sqrtf(vx * vx + vy * vy);
    float bearing = (dpx * vx + dpy * vy) / (dist * vn);
    if (isnan(bearing)) bearing = 0.0f;
    float dvn = sqrtf(dvx * dvx + dvy * dvy);
    float tau = -(dpx * dvx + dpy * dvy) / dvn;
    if (isnan(tau)) tau = 0.0f;
    tau = fminf(fmaxf(tau, 0.0f), 7.0f);
    float mx_ = dpx + tau * dvx, my_ = dpy + tau * dvy;
    float mpd = sqrtf(mx_ * mx_ + my_ * my_);
    nf[(size_t)idx * 3 + 0] = ntn(dist);
    nf[(size_t)idx * 3 + 1] = ntn(bearing);
    nf[(size_t)idx * 3 + 2] = ntn(mpd);
}

// ---------------- neighbor embed: writes f32 A and bf16 Ab ---------------------------
__global__ void nemb_kernel(const float* nf, const float* Wn, const float* bn,
                            const float* pe, float* A, u16* Ab) {
    int row = blockIdx.x;              // (b*NN+m)*T + t
    int t = row % T_;
    int bm = row / T_;
    int m = bm % NN_, b = bm / NN_;
    size_t nfrow = (((size_t)t * N_ + b) * NN_ + m) * 3;
    float f0 = nf[nfrow], f1 = nf[nfrow + 1], f2 = nf[nfrow + 2];
    for (int d = threadIdx.x; d < D_; d += blockDim.x) {
        float v = f0 * Wn[d] + f1 * Wn[D_ + d] + f2 * Wn[2 * D_ + d]
                + bn[d] + pe[t * D_ + d];
        A[(size_t)row * D_ + d] = v;
        Ab[(size_t)row * D_ + d] = f2bf(v);
    }
}

// ---------------- LayerNorm, one wave per row, dual-width output ---------------------
__global__ __launch_bounds__(256) void ln_dual_kernel(
    const float* X, const float* g, const float* b, float* outF, u16* outB, int nrows) {
    int row = blockIdx.x * 4 + (threadIdx.x >> 6);
    if (row >= nrows) return;
    int lane = threadIdx.x & 63;
    const float* p = X + (size_t)row * D_;
    float v[8];
    float s = 0.f;
    #pragma unroll
    for (int r = 0; r < 8; ++r) { v[r] = p[lane + r * 64]; s += v[r]; }
    s = wave_sum(s);
    float mean = s * (1.0f / 512.0f);
    float vs = 0.f;
    #pragma unroll
    for (int r = 0; r < 8; ++r) { float d = v[r] - mean; vs += d * d; }
    vs = wave_sum(vs);
    float rstd = rsqrtf(vs * (1.0f / 512.0f) + 1e-5f);
    #pragma unroll
    for (int r = 0; r < 8; ++r) {
        int d = lane + r * 64;
        float o = (v[r] - mean) * rstd * g[d] + b[d];
        if (outF) outF[(size_t)row * D_ + d] = o;
        if (outB) outB[(size_t)row * D_ + d] = f2bf(o);
    }
}

// ---------------- prediction head + broadcast (f32 out) ------------------------------
__global__ void pred_kernel(const float* xemb, const float* Wp, const float* bp, float* o) {
    int idx = blockIdx.x * blockDim.x + threadIdx.x;
    if (idx >= N_ * T_ * 2) return;
    int c = idx & 1;
    int nt = idx >> 1;
    float acc = bp[c];
    for (int j = 0; j < D_; ++j) acc += xemb[(size_t)nt * D_ + j] * Wp[(size_t)j * 2 + c];
    o[idx] = acc;
}

__global__ void bcast_kernel(const float* o, float* out) {
    int idx = blockIdx.x * blockDim.x + threadIdx.x;   // ((p*T+t)*N+n)*2+c
    if (idx >= NPRED_ * T_ * N_ * 2) return;
    int c = idx & 1;
    int rest = idx >> 1;
    int n = rest % N_;
    rest /= N_;
    int t = rest % T_;
    out[idx] = o[((size_t)n * T_ + t) * 2 + c];
}

extern "C" void kernel_launch(void* const* d_in, const int* in_sizes, int n_in,
                              void* d_out, int out_size, void* d_ws, size_t ws_size,
                              hipStream_t stream) {
    (void)in_sizes; (void)n_in; (void)out_size; (void)ws_size;

    const float* x    = (const float*)d_in[0];
    const float* nbr  = (const float*)d_in[1];
    const float* attf = (const float*)d_in[2];
    const float* Wx   = (const float*)d_in[3];
    const float* bx   = (const float*)d_in[4];
    const float* Wn   = (const float*)d_in[5];
    const float* bn   = (const float*)d_in[6];
    const float* Wp   = (const float*)d_in[7];
    const float* bp   = (const float*)d_in[8];
    const float* WQ   = (const float*)d_in[9];
    const float* WK   = (const float*)d_in[10];
    const float* WV   = (const float*)d_in[11];
    const float* Wfc  = (const float*)d_in[12];
    const float* mlng = (const float*)d_in[13];
    const float* mlnb = (const float*)d_in[14];
    const float* WSI  = (const float*)d_in[15];
    const float* fsw1 = (const float*)d_in[16];
    const float* fsw2 = (const float*)d_in[17];
    const float* fsg  = (const float*)d_in[18];
    const float* fsb  = (const float*)d_in[19];
    const float* fiw1 = (const float*)d_in[20];
    const float* fiw2 = (const float*)d_in[21];
    const float* fig  = (const float*)d_in[22];
    const float* fib  = (const float*)d_in[23];

    char* w = (char*)d_ws;
    size_t off = 0;
    auto alloc = [&](size_t bytes) -> void* {
        void* p = w + off;
        off = (off + bytes + 255) & ~(size_t)255;
        return p;
    };
    const size_t MiB = 1024 * 1024;

    const int BM = N_ * NN_;          // 2048 (b,m) pairs
    const int ROWS_I = BM * T_;       // 32768 neighbor rows
    const int CB = 512;               // bm per chunk
    const int RC = CB * T_;           // 8192 rows per chunk
    const int NCH = ROWS_I / RC;      // 4

    float* pe      = (float*)alloc((size_t)T_ * D_ * 4);
    float* xemb    = (float*)alloc((size_t)N_ * T_ * D_ * 4);
    float* nf      = (float*)alloc((size_t)T_ * N_ * NN_ * 3 * 4);
    float* maskf   = (float*)alloc((size_t)BM * T_ * 4);
    float* A       = (float*)alloc((size_t)ROWS_I * D_ * 4);   // n_emb f32   64 MiB
    u16*   Ab      = (u16*)alloc((size_t)ROWS_I * D_ * 2);     // n_emb bf16  32 MiB
    u16* tQKV[2], *tWSI[2], *tfs1[2], *tfs2[2];
    for (int l = 0; l < 2; ++l) {
        tQKV[l] = (u16*)alloc((size_t)1536 * 512 * 2);
        tWSI[l] = (u16*)alloc((size_t)512 * 4096 * 2);
        tfs1[l] = (u16*)alloc((size_t)2048 * 512 * 2);
        tfs2[l] = (u16*)alloc((size_t)512 * 2048 * 2);
    }
    u16* tWfc = (u16*)alloc((size_t)512 * 512 * 2);
    u16* tfi1 = (u16*)alloc((size_t)2048 * 512 * 2);
    u16* tfi2 = (u16*)alloc((size_t)512 * 2048 * 2);
    char* SCR  = (char*)alloc(36 * MiB);
    u16*   QKVb = (u16*)SCR;
    u16*   ctxb = (u16*)(SCR + 24 * MiB);
    u16*   hid  = (u16*)SCR;
    float* Bch  = (float*)alloc((size_t)RC * D_ * 4);  // res_inter chunk f32  16 MiB
    u16*   Bbch = (u16*)alloc((size_t)RC * D_ * 2);    //                       8 MiB
    float* att_sum = (float*)alloc((size_t)N_ * H_ * 256 * 4);
    u16*   sib     = (u16*)alloc((size_t)N_ * T_ * 4096 * 2);  // 8 MiB
    float* xnew    = (float*)alloc((size_t)N_ * T_ * D_ * 4);
    u16*   xnb     = (u16*)alloc((size_t)N_ * T_ * D_ * 2);
    float* osm     = (float*)alloc((size_t)N_ * T_ * 2 * 4);
    // total ~196 MiB

    auto wT = [&](const float* src, u16* dst, int K, int N) {
        wconv_kernel<<<dim3(N / 32, K / 32), 256, 0, stream>>>(src, dst, K, N);
    };
    for (int l = 0; l < 2; ++l) {
        wT(WQ + (size_t)l * 512 * 512, tQKV[l],                  512, 512);
        wT(WK + (size_t)l * 512 * 512, tQKV[l] + 512 * 512,      512, 512);
        if (l == 0) wT(WV, tQKV[0] + 1024 * 512, 512, 512);      // V dead at l=1
        wT(WSI  + (size_t)l * 4096 * 512, tWSI[l], 4096, 512);
        wT(fsw1 + (size_t)l * 512 * 2048, tfs1[l], 512, 2048);
        wT(fsw2 + (size_t)l * 2048 * 512, tfs2[l], 2048, 512);
    }
    wT(Wfc, tWfc, 512, 512);
    wT(fiw1, tfi1, 512, 2048);
    wT(fiw2, tfi2, 2048, 512);

    pe_kernel<<<16, 256, 0, stream>>>(pe);
    xemb_kernel<<<T_ * N_, 256, 0, stream>>>(x, Wx, bx, pe, xemb);
    nbr_kernel<<<(T_ * N_ * NN_ + 255) / 256, 256, 0, stream>>>(x, nbr, nf, maskf);
    nemb_kernel<<<BM * T_, 256, 0, stream>>>(nf, Wn, bn, pe, A, Ab);

    for (int l = 0; l < L_; ++l) {
        hipMemsetAsync(att_sum, 0, (size_t)N_ * H_ * 256 * 4, stream);
        for (int c = 0; c < NCH; ++c) {
            const u16* Acb = Ab + (size_t)c * RC * D_;
            float*     Acf = A  + (size_t)c * RC * D_;
            if (l == 0) {
                // QKV fused GEMM: N=1536, 128x128 tiles (768 blocks)
                gemm_bt<128, 128, 0, 0, 1><<<dim3(12, RC / 128), 256, 0, stream>>>(
                    Acb, tQKV[0], nullptr, QKVb, nullptr, 512, 1536);
                attn_fused_kernel<1><<<CB, 256, 0, stream>>>(
                    QKVb, maskf, c * CB, att_sum, ctxb);
                // fc + residual: N=512, 128x64 tiles (512 blocks)
                gemm_bt<128, 64, 2, 1, 0><<<dim3(8, RC / 128), 256, 0, stream>>>(
                    ctxb, tWfc, Bch, nullptr, Acf, 512, 512);
                ln_dual_kernel<<<RC / 4, 256, 0, stream>>>(
                    Bch, mlng, mlnb, Bch, Bbch, RC);
                // ffi1 relu: N=2048, 128x128 (1024 blocks); hid aliases QKVb/ctxb
                gemm_bt<128, 128, 1, 0, 1><<<dim3(16, RC / 128), 256, 0, stream>>>(
                    Bbch, tfi1, nullptr, hid, nullptr, 512, 2048);
                // ffi2 + residual: N=512, 128x64
                gemm_bt<128, 64, 2, 1, 0><<<dim3(8, RC / 128), 256, 0, stream>>>(
                    hid, tfi2, Acf, nullptr, Bch, 2048, 512);
                ln_dual_kernel<<<RC / 4, 256, 0, stream>>>(
                    Acf, fig, fib, nullptr, (u16*)Acb, RC);
            } else {
                // QK only: N=1024 (1536-stride output)
                gemm_bt<128, 128, 0, 0, 1><<<dim3(8, RC / 128), 256, 0, stream>>>(
                    Acb, tQKV[1], nullptr, QKVb, nullptr, 512, 1536);
                attn_fused_kernel<0><<<CB, 256, 0, stream>>>(
                    QKVb, maskf, c * CB, att_sum, nullptr);
            }
        }

        // ---- self-attention + si + ffs (updates xemb) ----
        siatt_kernel<<<N_, 256, 0, stream>>>(xemb, att_sum, attf, sib);
        gemm_bt<64, 64, 0, 1, 1><<<dim3(8, 16), 256, 0, stream>>>(
            sib, tWSI[l], xnew, xnb, nullptr, 4096, 512);
        gemm_bt<64, 64, 1, 0, 1><<<dim3(32, 16), 256, 0, stream>>>(
            xnb, tfs1[l], nullptr, hid, nullptr, 512, 2048);
        gemm_bt<64, 64, 2, 1, 0><<<dim3(8, 16), 256, 0, stream>>>(
            hid, tfs2[l], xemb, nullptr, xnew, 2048, 512);
        ln_dual_kernel<<<(N_ * T_) / 4, 256, 0, stream>>>(
            xemb, fsg + l * D_, fsb + l * D_, xemb, nullptr, N_ * T_);
    }

    pred_kernel<<<(N_ * T_ * 2 + 255) / 256, 256, 0, stream>>>(xemb, Wp, bp, osm);
    bcast_kernel<<<(NPRED_ * T_ * N_ * 2 + 255) / 256, 256, 0, stream>>>(osm, (float*)d_out);
}

// Round 11
// 984.988 us; speedup vs baseline: 49.8986x; 1.0910x over previous
//
#include <hip/hip_runtime.h>
#include <math.h>

// DTYPE COMMITMENTS (evidence-backed): inputs f32, output f32 (rounds 4-10 PASS).
// WS BUDGET: <= ~210 MB decimal; this build ~196 MiB.

#define T_ 16
#define N_ 64
#define NN_ 32
#define D_ 512
#define H_ 8
#define DK_ 64
#define DFF_ 2048
#define L_ 2
#define NPRED_ 20

typedef unsigned short u16;
typedef unsigned int u32;
typedef __attribute__((ext_vector_type(8))) short short8;
typedef __attribute__((ext_vector_type(4))) float f32x4;

__device__ __forceinline__ u16 f2bf(float f) {
    u32 u = __float_as_uint(f);
    u32 r = u + 0x7fffu + ((u >> 16) & 1u);
    return (u16)(r >> 16);
}
__device__ __forceinline__ float bfv(u16 v) {
    return __uint_as_float(((u32)v) << 16);
}
__device__ __forceinline__ float ntn(float v) {
    if (isnan(v)) return 0.0f;
    if (isinf(v)) return v > 0.0f ? 3.4028234663852886e38f : -3.4028234663852886e38f;
    return v;
}
__device__ __forceinline__ float wave_sum(float v) {
    #pragma unroll
    for (int o = 32; o > 0; o >>= 1) v += __shfl_xor(v, o, 64);
    return v;
}
// async 16B HBM->LDS: writes ldsbase + lane*16 (wave-uniform base, per-lane gptr)
__device__ __forceinline__ void gload_lds(const u16* g, u16* l) {
    __builtin_amdgcn_global_load_lds(
        (const __attribute__((address_space(1))) u32*)g,
        (__attribute__((address_space(3))) u32*)l, 16, 0, 0);
}

// ============ batched weight convert+transpose: 14 jobs in ONE launch ===============
// in[K][N] f32 -> out[N][K] bf16, 32x32 tiles; job table passed by value.
struct WJob { const float* src; u16* dst; int K; int N; int t0; };
struct WJobs { WJob j[14]; };
__global__ __launch_bounds__(256) void wconv_all(WJobs jobs, int ntiles) {
    int bid = blockIdx.x;
    if (bid >= ntiles) return;
    int ji = 0;
    #pragma unroll 1
    for (int i = 1; i < 14; ++i) if (bid >= jobs.j[i].t0) ji = i;
    const float* in = jobs.j[ji].src;
    u16* out = jobs.j[ji].dst;
    int K = jobs.j[ji].K, N = jobs.j[ji].N;
    int lt = bid - jobs.j[ji].t0;
    int ntx = N >> 5;
    int nb = (lt % ntx) * 32, kb = (lt / ntx) * 32;
    __shared__ float tile[32][33];
    int tx = threadIdx.x & 31, ty = threadIdx.x >> 5;
    #pragma unroll
    for (int r = ty; r < 32; r += 8)
        tile[r][tx] = in[(size_t)(kb + r) * N + nb + tx];
    __syncthreads();
    #pragma unroll
    for (int r = ty; r < 32; r += 8)
        out[(size_t)(nb + r) * K + kb + tx] = f2bf(tile[tx][r]);
}

// ============ MFMA GEMM v3 + XCD-band remap =========================================
// Unpadded LDS [rows][64] u16, DMA staging + 3-bit XOR chunk swizzle (r9-verified:
// 0 bank conflicts). Block remap: xcd = id%8 owns contiguous row-bands, columns
// fastest within an XCD (r10-verified: ffi2 FETCH 140->20 MB).
// EPI: 0 none, 1 relu, 2 +residual f32. Grid (N/TN, M/TM), gridY%8==0, K%64==0.
template<int TM, int TN, int EPI, int WF32, int WBF16>
__global__ __launch_bounds__(256) void gemm_bt(
    const u16* __restrict__ Ab, const u16* __restrict__ Btb,
    float* __restrict__ Cf, u16* __restrict__ Cb, const float* __restrict__ Rg,
    int K, int ldc)
{
    constexpr int WR = TM / 32, WC = TN / 32;
    constexpr int ITA = TM / 32, ITB = TN / 32;   // global_load_lds per wave
    __shared__ __align__(16) u16 As[TM][64];
    __shared__ __align__(16) u16 Bs[TN][64];
    int tid = threadIdx.x;
    int lane = tid & 63, wave = tid >> 6;
    int quad = lane >> 4, l16 = lane & 15;
    int wm = (wave >> 1) * (TM / 2), wn = (wave & 1) * (TN / 2);

    // XCD-aware remap (uniform): same row-band's column tiles stay on one XCD
    int gx = gridDim.x, gy = gridDim.y;
    int bx, by;
    if ((gy & 7) == 0) {
        int id = blockIdx.y * gx + blockIdx.x;
        int xcd = id & 7;
        int slot = id >> 3;
        bx = slot % gx;
        by = xcd * (gy >> 3) + slot / gx;
    } else {
        bx = blockIdx.x;
        by = blockIdx.y;
    }
    size_t row0 = (size_t)by * TM;
    size_t col0 = (size_t)bx * TN;

    f32x4 acc[WR][WC];
    #pragma unroll
    for (int i = 0; i < WR; ++i)
        #pragma unroll
        for (int j = 0; j < WC; ++j)
            acc[i][j] = (f32x4){0.f, 0.f, 0.f, 0.f};

    int srow = lane >> 3;                  // 0..7 row within 8-row group
    int c8 = (lane & 7) ^ srow;            // logical 16B-chunk this lane fetches
    int h8 = l16 & 7;                      // row&7 of every fragment row this lane reads

    for (int k0 = 0; k0 < K; k0 += 64) {
        __syncthreads();
        #pragma unroll
        for (int it = 0; it < ITA; ++it) {
            int g = wave + it * 4;
            gload_lds(Ab + (row0 + g * 8 + srow) * (size_t)K + k0 + c8 * 8, &As[g * 8][0]);
        }
        #pragma unroll
        for (int it = 0; it < ITB; ++it) {
            int g = wave + it * 4;
            gload_lds(Btb + (col0 + g * 8 + srow) * (size_t)K + k0 + c8 * 8, &Bs[g * 8][0]);
        }
        __syncthreads();
        #pragma unroll
        for (int s = 0; s < 2; ++s) {
            int coff = ((s * 4 + quad) ^ h8) * 8;   // full 3-bit XOR (r9-verified)
            short8 af[WR], bf[WC];
            #pragma unroll
            for (int i = 0; i < WR; ++i)
                af[i] = *(short8*)&As[wm + i * 16 + l16][coff];
            #pragma unroll
            for (int j = 0; j < WC; ++j)
                bf[j] = *(short8*)&Bs[wn + j * 16 + l16][coff];
            #pragma unroll
            for (int i = 0; i < WR; ++i)
                #pragma unroll
                for (int j = 0; j < WC; ++j)
                    acc[i][j] = __builtin_amdgcn_mfma_f32_16x16x32_bf16(
                        af[i], bf[j], acc[i][j], 0, 0, 0);
        }
    }
    // C/D layout (on-target verified): col = lane&15, row = quad*4 + reg
    #pragma unroll
    for (int i = 0; i < WR; ++i)
        #pragma unroll
        for (int j = 0; j < WC; ++j)
            #pragma unroll
            for (int reg = 0; reg < 4; ++reg) {
                size_t row = row0 + wm + i * 16 + quad * 4 + reg;
                size_t col = col0 + wn + j * 16 + l16;
                float v = acc[i][j][reg];
                if (EPI == 2) v += Rg[row * (size_t)ldc + col];
                if (EPI == 1) v = fmaxf(v, 0.f);
                if (WF32)  Cf[row * (size_t)ldc + col] = v;
                if (WBF16) Cb[row * (size_t)ldc + col] = f2bf(v);
            }
}

// ============ fused attention per (b,m): all-heads phases, 3 barriers ===============
// QKVb: [rows][1536] bf16 (Q 0..511, K 512..1023, V 1024..1535; col = h*64+dk).
template<int CTX>
__global__ __launch_bounds__(256) void attn_fused_kernel(
    const u16* __restrict__ QKVb, const float* __restrict__ maskf, int bm0,
    float* __restrict__ att_sum, u16* __restrict__ ctxb)
{
    __shared__ __align__(16) u16 sQ[16][520];
    __shared__ __align__(16) u16 sK[16][520];
    __shared__ __align__(16) u16 sV[CTX ? 16 : 1][520];
    __shared__ float s_p[H_][16][17];
    int bm_l = blockIdx.x;
    int tid = threadIdx.x;
    int t = tid >> 4, ch = (tid & 15) * 32;
    const u16* base = QKVb + ((size_t)bm_l * T_ + t) * 1536;
    #pragma unroll
    for (int c = 0; c < 4; ++c) {
        *(uint4*)&sQ[t][ch + c * 8] = *(const uint4*)(base + ch + c * 8);
        *(uint4*)&sK[t][ch + c * 8] = *(const uint4*)(base + 512 + ch + c * 8);
        if (CTX) *(uint4*)&sV[t][ch + c * 8] = *(const uint4*)(base + 1024 + ch + c * 8);
    }
    __syncthreads();

    int b = (bm0 + bm_l) >> 5;                  // bm = b*NN + m

    #pragma unroll
    for (int r = 0; r < 8; ++r) {
        int h = r;
        int q = (tid >> 4) & 15, k = tid & 15;
        const u32* qu = (const u32*)&sQ[q][0] + h * 32;
        const u32* ku = (const u32*)&sK[k][0] + h * 32;
        float acc = 0.f;
        #pragma unroll
        for (int j = 0; j < 32; ++j) {
            u32 a = qu[j], bb = ku[j];
            acc += bfv((u16)(a & 0xffff)) * bfv((u16)(bb & 0xffff));
            acc += bfv((u16)(a >> 16))    * bfv((u16)(bb >> 16));
        }
        acc *= 0.125f;
        if (maskf[(size_t)(bm0 + bm_l) * T_ + q] == 0.0f) acc = -1e9f;
        s_p[h][q][k] = acc;
    }
    __syncthreads();
    if (tid < 128) {
        int h = tid >> 4, q = tid & 15;
        float mx = -3.4e38f;
        #pragma unroll
        for (int kk = 0; kk < 16; ++kk) mx = fmaxf(mx, s_p[h][q][kk]);
        float e[16], s = 0.f;
        #pragma unroll
        for (int kk = 0; kk < 16; ++kk) { e[kk] = expf(s_p[h][q][kk] - mx); s += e[kk]; }
        float inv = 1.0f / s;
        #pragma unroll
        for (int kk = 0; kk < 16; ++kk) s_p[h][q][kk] = e[kk] * inv;
    }
    __syncthreads();
    #pragma unroll
    for (int r = 0; r < 8; ++r) {
        int h = r;
        int q = (tid >> 4) & 15, k = tid & 15;
        atomicAdd(&att_sum[(((size_t)b * H_ + h) * T_ + q) * T_ + k], s_p[h][q][k]);
    }
    if (CTX) {
        #pragma unroll
        for (int rep = 0; rep < 32; ++rep) {
            int i = rep * 256 + tid;            // t*512 + c, c = h*64+dk
            int tt = i >> 9, c = i & 511;
            int h = c >> 6;
            float acc = 0.f;
            #pragma unroll
            for (int kk = 0; kk < 16; ++kk)
                acc += s_p[h][tt][kk] * bfv(sV[kk][c]);
            ctxb[((size_t)bm_l * T_ + tt) * D_ + c] = f2bf(acc);
        }
    }
}

// ============ fused self-attention + combine + si, one block per (n,h) ==============
__global__ __launch_bounds__(256) void siatt_kernel(
    const float* __restrict__ xemb, const float* __restrict__ att_sum,
    const float* __restrict__ attf, u16* __restrict__ sib)
{
    __shared__ float sX[16][516];
    __shared__ float sS[16][17];
    __shared__ float sA[16][17];
    int n = blockIdx.x >> 3, h = blockIdx.x & 7;
    int tid = threadIdx.x;
    int t = tid >> 4, ch = (tid & 15) * 32;
    const float* src = xemb + ((size_t)n * T_ + t) * D_;
    #pragma unroll
    for (int c = 0; c < 8; ++c)
        *(float4*)&sX[t][ch + c * 4] = *(const float4*)(src + ch + c * 4);
    __syncthreads();
    int q = tid >> 4, k = tid & 15;
    {
        float acc = 0.f;
        for (int d = 0; d < D_; ++d) acc += sX[q][d] * sX[k][d];
        sS[q][k] = acc * 0.04419417382415922f;
    }
    __syncthreads();
    if (tid < T_) {
        float mx = -3.4e38f;
        #pragma unroll
        for (int kk = 0; kk < 16; ++kk) mx = fmaxf(mx, sS[tid][kk]);
        float e[16], s = 0.f;
        #pragma unroll
        for (int kk = 0; kk < 16; ++kk) { e[kk] = expf(sS[tid][kk] - mx); s += e[kk]; }
        float inv = 1.0f / s;
        #pragma unroll
        for (int kk = 0; kk < 16; ++kk) sS[tid][kk] = e[kk] * inv;
    }
    __syncthreads();
    float f = attf[0] * (1.0f / 32.0f);
    sA[q][k] = sS[q][k] + f * att_sum[((size_t)n * H_ + h) * 256 + q * 16 + k];
    __syncthreads();
    #pragma unroll
    for (int rep = 0; rep < 32; ++rep) {
        int i = rep * 256 + tid;          // q*512 + d
        int qq = i >> 9, d = i & 511;
        float acc = 0.f;
        #pragma unroll
        for (int tt = 0; tt < 16; ++tt) acc += sA[qq][tt] * sX[tt][d];
        sib[(size_t)n * T_ * 4096 + (size_t)qq * 4096 + h * 512 + d] = f2bf(acc);
    }
}

// ---------------- positional encoding ------------------------------------------------
__global__ void pe_kernel(float* pe) {
    int i = blockIdx.x * blockDim.x + threadIdx.x;
    if (i >= T_ * 256) return;
    int t = i >> 8, j = i & 255;
    float dv = (float)pow(10000.0, (double)j / 256.0);
    float a = (float)t * dv;
    double ad = (double)a;
    pe[t * D_ + 2 * j]     = (float)sin(ad);
    pe[t * D_ + 2 * j + 1] = (float)cos(ad);
}

// ---------------- x features + embed -------------------------------------------------
__global__ void xemb_kernel(const float* x, const float* Wx, const float* bx,
                            const float* pe, float* xemb) {
    int row = blockIdx.x;              // t*N + n
    int t = row / N_, n = row % N_;
    float x0 = x[row * 6 + 0], x1 = x[row * 6 + 1];
    float x2 = x[row * 6 + 2], x3 = x[row * 6 + 3];
    float x4 = x[row * 6 + 4], x5 = x[row * 6 + 5];
    float vel = sqrtf(x2 * x2 + x3 * x3);
    float ang = atanf(x5 / x4);
    float f0 = ntn(x0), f1 = ntn(x1), f2 = ntn(vel), f3 = ntn(ang);
    for (int d = threadIdx.x; d < D_; d += blockDim.x) {
        xemb[((size_t)n * T_ + t) * D_ + d] =
            f0 * Wx[0 * D_ + d] + f1 * Wx[1 * D_ + d]
          + f2 * Wx[2 * D_ + d] + f3 * Wx[3 * D_ + d]
          + bx[d] + pe[t * D_ + d];
    }
}

// ---------------- neighbor features + mask -------------------------------------------
__global__ void nbr_kernel(const float* x, const float* nbr, float* nf, float* maskf) {
    int idx = blockIdx.x * blockDim.x + threadIdx.x;   // t*N*NN + n*NN + m
    if (idx >= T_ * N_ * NN_) return;
    int m = idx % NN_;
    int tn = idx / NN_;
    int n = tn % N_, t = tn / N_;
    float px = x[((size_t)t * N_ + n) * 6 + 0];
    float py = x[((size_t)t * N_ + n) * 6 + 1];
    float vx, vy;
    if (t == 0) {
        vx = x[((size_t)1 * N_ + n) * 6 + 2];
        vy = x[((size_t)1 * N_ + n) * 6 + 3];
    } else {
        vx = px - x[((size_t)(t - 1) * N_ + n) * 6 + 0];
        vy = py - x[((size_t)(t - 1) * N_ + n) * 6 + 1];
    }
    float nx  = nbr[(size_t)idx * 4 + 0], ny  = nbr[(size_t)idx * 4 + 1];
    float nvx = nbr[(size_t)idx * 4 + 2], nvy = nbr[(size_t)idx * 4 + 3];
    float dpx = nx - px, dpy = ny - py;
    float dvx = nvx - vx, dvy = nvy - vy;
    float dist = sqrtf(dpx * dpx + dpy * dpy);
    maskf[((size_t)n * NN_ + m) * T_ + t] = (dist <= 2.0f) ? 1.0f : 0.0f;
    float vn = sqrtf(vx * vx + vy * vy);
    float bearing = (dpx * vx + dpy * vy) / (dist * vn);
    if (isnan(bearing)) bearing = 0.0f;
    float dvn = sqrtf(dvx * dvx + dvy * dvy);
    float tau = -(dpx * dvx + dpy * dvy) / dvn;
    if (isnan(tau)) tau = 0.0f;
    tau = fminf(fmaxf(tau, 0.0f), 7.0f);
    float mx_ = dpx + tau * dvx, my_ = dpy + tau * dvy;
    float mpd = sqrtf(mx_ * mx_ + my_ * my_);
    nf[(size_t)idx * 3 + 0] = ntn(dist);
    nf[(size_t)idx * 3 + 1] = ntn(bearing);
    nf[(size_t)idx * 3 + 2] = ntn(mpd);
}

// ---------------- neighbor embed: writes f32 A and bf16 Ab ---------------------------
__global__ void nemb_kernel(const float* nf, const float* Wn, const float* bn,
                            const float* pe, float* A, u16* Ab) {
    int row = blockIdx.x;              // (b*NN+m)*T + t
    int t = row % T_;
    int bm = row / T_;
    int m = bm % NN_, b = bm / NN_;
    size_t nfrow = (((size_t)t * N_ + b) * NN_ + m) * 3;
    float f0 = nf[nfrow], f1 = nf[nfrow + 1], f2 = nf[nfrow + 2];
    for (int d = threadIdx.x; d < D_; d += blockDim.x) {
        float v = f0 * Wn[d] + f1 * Wn[D_ + d] + f2 * Wn[2 * D_ + d]
                + bn[d] + pe[t * D_ + d];
        A[(size_t)row * D_ + d] = v;
        Ab[(size_t)row * D_ + d] = f2bf(v);
    }
}

// ---------------- LayerNorm, one wave per row, dual-width output ---------------------
__global__ __launch_bounds__(256) void ln_dual_kernel(
    const float* X, const float* g, const float* b, float* outF, u16* outB, int nrows) {
    int row = blockIdx.x * 4 + (threadIdx.x >> 6);
    if (row >= nrows) return;
    int lane = threadIdx.x & 63;
    const float* p = X + (size_t)row * D_;
    float v[8];
    float s = 0.f;
    #pragma unroll
    for (int r = 0; r < 8; ++r) { v[r] = p[lane + r * 64]; s += v[r]; }
    s = wave_sum(s);
    float mean = s * (1.0f / 512.0f);
    float vs = 0.f;
    #pragma unroll
    for (int r = 0; r < 8; ++r) { float d = v[r] - mean; vs += d * d; }
    vs = wave_sum(vs);
    float rstd = rsqrtf(vs * (1.0f / 512.0f) + 1e-5f);
    #pragma unroll
    for (int r = 0; r < 8; ++r) {
        int d = lane + r * 64;
        float o = (v[r] - mean) * rstd * g[d] + b[d];
        if (outF) outF[(size_t)row * D_ + d] = o;
        if (outB) outB[(size_t)row * D_ + d] = f2bf(o);
    }
}

// ---------------- prediction head + broadcast (f32 out) ------------------------------
__global__ void pred_kernel(const float* xemb, const float* Wp, const float* bp, float* o) {
    int idx = blockIdx.x * blockDim.x + threadIdx.x;
    if (idx >= N_ * T_ * 2) return;
    int c = idx & 1;
    int nt = idx >> 1;
    float acc = bp[c];
    for (int j = 0; j < D_; ++j) acc += xemb[(size_t)nt * D_ + j] * Wp[(size_t)j * 2 + c];
    o[idx] = acc;
}

__global__ void bcast_kernel(const float* o, float* out) {
    int idx = blockIdx.x * blockDim.x + threadIdx.x;   // ((p*T+t)*N+n)*2+c
    if (idx >= NPRED_ * T_ * N_ * 2) return;
    int c = idx & 1;
    int rest = idx >> 1;
    int n = rest % N_;
    rest /= N_;
    int t = rest % T_;
    out[idx] = o[((size_t)n * T_ + t) * 2 + c];
}

extern "C" void kernel_launch(void* const* d_in, const int* in_sizes, int n_in,
                              void* d_out, int out_size, void* d_ws, size_t ws_size,
                              hipStream_t stream) {
    (void)in_sizes; (void)n_in; (void)out_size; (void)ws_size;

    const float* x    = (const float*)d_in[0];
    const float* nbr  = (const float*)d_in[1];
    const float* attf = (const float*)d_in[2];
    const float* Wx   = (const float*)d_in[3];
    const float* bx   = (const float*)d_in[4];
    const float* Wn   = (const float*)d_in[5];
    const float* bn   = (const float*)d_in[6];
    const float* Wp   = (const float*)d_in[7];
    const float* bp   = (const float*)d_in[8];
    const float* WQ   = (const float*)d_in[9];
    const float* WK   = (const float*)d_in[10];
    const float* WV   = (const float*)d_in[11];
    const float* Wfc  = (const float*)d_in[12];
    const float* mlng = (const float*)d_in[13];
    const float* mlnb = (const float*)d_in[14];
    const float* WSI  = (const float*)d_in[15];
    const float* fsw1 = (const float*)d_in[16];
    const float* fsw2 = (const float*)d_in[17];
    const float* fsg  = (const float*)d_in[18];
    const float* fsb  = (const float*)d_in[19];
    const float* fiw1 = (const float*)d_in[20];
    const float* fiw2 = (const float*)d_in[21];
    const float* fig  = (const float*)d_in[22];
    const float* fib  = (const float*)d_in[23];

    char* w = (char*)d_ws;
    size_t off = 0;
    auto alloc = [&](size_t bytes) -> void* {
        void* p = w + off;
        off = (off + bytes + 255) & ~(size_t)255;
        return p;
    };
    const size_t MiB = 1024 * 1024;

    const int BM = N_ * NN_;          // 2048 (b,m) pairs
    const int ROWS_I = BM * T_;       // 32768 neighbor rows
    const int CB = 512;               // bm per chunk
    const int RC = CB * T_;           // 8192 rows per chunk
    const int NCH = ROWS_I / RC;      // 4

    float* pe      = (float*)alloc((size_t)T_ * D_ * 4);
    float* xemb    = (float*)alloc((size_t)N_ * T_ * D_ * 4);
    float* nf      = (float*)alloc((size_t)T_ * N_ * NN_ * 3 * 4);
    float* maskf   = (float*)alloc((size_t)BM * T_ * 4);
    float* A       = (float*)alloc((size_t)ROWS_I * D_ * 4);   // n_emb f32   64 MiB
    u16*   Ab      = (u16*)alloc((size_t)ROWS_I * D_ * 2);     // n_emb bf16  32 MiB
    u16* tQKV[2], *tWSI[2], *tfs1[2], *tfs2[2];
    for (int l = 0; l < 2; ++l) {
        tQKV[l] = (u16*)alloc((size_t)1536 * 512 * 2);
        tWSI[l] = (u16*)alloc((size_t)512 * 4096 * 2);
        tfs1[l] = (u16*)alloc((size_t)2048 * 512 * 2);
        tfs2[l] = (u16*)alloc((size_t)512 * 2048 * 2);
    }
    u16* tWfc = (u16*)alloc((size_t)512 * 512 * 2);
    u16* tfi1 = (u16*)alloc((size_t)2048 * 512 * 2);
    u16* tfi2 = (u16*)alloc((size_t)512 * 2048 * 2);
    char* SCR  = (char*)alloc(36 * MiB);
    u16*   QKVb = (u16*)SCR;
    u16*   ctxb = (u16*)(SCR + 24 * MiB);
    u16*   hid  = (u16*)SCR;
    float* Bch  = (float*)alloc((size_t)RC * D_ * 4);  // res_inter chunk f32  16 MiB
    u16*   Bbch = (u16*)alloc((size_t)RC * D_ * 2);    //                       8 MiB
    float* att_sum = (float*)alloc((size_t)N_ * H_ * 256 * 4);
    u16*   sib     = (u16*)alloc((size_t)N_ * T_ * 4096 * 2);  // 8 MiB
    float* xnew    = (float*)alloc((size_t)N_ * T_ * D_ * 4);
    u16*   xnb     = (u16*)alloc((size_t)N_ * T_ * D_ * 2);
    float* osm     = (float*)alloc((size_t)N_ * T_ * 2 * 4);
    // total ~196 MiB

    // ---- batched weight conversion: 14 jobs, one launch ----
    WJobs jobs;
    int ntiles = 0;
    auto addJob = [&](int idx, const float* src, u16* dst, int K, int N) {
        jobs.j[idx] = {src, dst, K, N, ntiles};
        ntiles += (N >> 5) * (K >> 5);
    };
    addJob(0,  WQ,                            tQKV[0],              512, 512);
    addJob(1,  WK,                            tQKV[0] + 512 * 512,  512, 512);
    addJob(2,  WV,                            tQKV[0] + 1024 * 512, 512, 512);   // dead at l=1
    addJob(3,  WQ + (size_t)512 * 512,        tQKV[1],              512, 512);
    addJob(4,  WK + (size_t)512 * 512,        tQKV[1] + 512 * 512,  512, 512);
    addJob(5,  Wfc,                           tWfc,                 512, 512);
    addJob(6,  WSI,                           tWSI[0],              4096, 512);
    addJob(7,  WSI + (size_t)4096 * 512,      tWSI[1],              4096, 512);
    addJob(8,  fsw1,                          tfs1[0],              512, 2048);
    addJob(9,  fsw1 + (size_t)512 * 2048,     tfs1[1],              512, 2048);
    addJob(10, fsw2,                          tfs2[0],              2048, 512);
    addJob(11, fsw2 + (size_t)2048 * 512,     tfs2[1],              2048, 512);
    addJob(12, fiw1,                          tfi1,                 512, 2048);
    addJob(13, fiw2,                          tfi2,                 2048, 512);
    wconv_all<<<ntiles, 256, 0, stream>>>(jobs, ntiles);

    pe_kernel<<<16, 256, 0, stream>>>(pe);
    xemb_kernel<<<T_ * N_, 256, 0, stream>>>(x, Wx, bx, pe, xemb);
    nbr_kernel<<<(T_ * N_ * NN_ + 255) / 256, 256, 0, stream>>>(x, nbr, nf, maskf);
    nemb_kernel<<<BM * T_, 256, 0, stream>>>(nf, Wn, bn, pe, A, Ab);

    for (int l = 0; l < L_; ++l) {
        hipMemsetAsync(att_sum, 0, (size_t)N_ * H_ * 256 * 4, stream);
        for (int c = 0; c < NCH; ++c) {
            const u16* Acb = Ab + (size_t)c * RC * D_;
            float*     Acf = A  + (size_t)c * RC * D_;
            if (l == 0) {
                // QKV fused GEMM: N=1536, 128x128 tiles (768 blocks)
                gemm_bt<128, 128, 0, 0, 1><<<dim3(12, RC / 128), 256, 0, stream>>>(
                    Acb, tQKV[0], nullptr, QKVb, nullptr, 512, 1536);
                attn_fused_kernel<1><<<CB, 256, 0, stream>>>(
                    QKVb, maskf, c * CB, att_sum, ctxb);
                // fc + residual: N=512, 128x64 tiles (512 blocks)
                gemm_bt<128, 64, 2, 1, 0><<<dim3(8, RC / 128), 256, 0, stream>>>(
                    ctxb, tWfc, Bch, nullptr, Acf, 512, 512);
                ln_dual_kernel<<<RC / 4, 256, 0, stream>>>(
                    Bch, mlng, mlnb, Bch, Bbch, RC);
                // ffi1 relu: N=2048, 128x128 (1024 blocks); hid aliases QKVb/ctxb
                gemm_bt<128, 128, 1, 0, 1><<<dim3(16, RC / 128), 256, 0, stream>>>(
                    Bbch, tfi1, nullptr, hid, nullptr, 512, 2048);
                // ffi2 + residual: N=512, 128x64
                gemm_bt<128, 64, 2, 1, 0><<<dim3(8, RC / 128), 256, 0, stream>>>(
                    hid, tfi2, Acf, nullptr, Bch, 2048, 512);
                ln_dual_kernel<<<RC / 4, 256, 0, stream>>>(
                    Acf, fig, fib, nullptr, (u16*)Acb, RC);
            } else {
                // QK only: N=1024 (1536-stride output)
                gemm_bt<128, 128, 0, 0, 1><<<dim3(8, RC / 128), 256, 0, stream>>>(
                    Acb, tQKV[1], nullptr, QKVb, nullptr, 512, 1536);
                attn_fused_kernel<0><<<CB, 256, 0, stream>>>(
                    QKVb, maskf, c * CB, att_sum, nullptr);
            }
        }

        // ---- self-attention + si + ffs (updates xemb); 32-row tiles: >=256 blocks ----
        siatt_kernel<<<N_ * H_, 256, 0, stream>>>(xemb, att_sum, attf, sib);
        gemm_bt<32, 64, 0, 1, 1><<<dim3(8, 32), 256, 0, stream>>>(
            sib, tWSI[l], xnew, xnb, nullptr, 4096, 512);
        gemm_bt<32, 64, 1, 0, 1><<<dim3(32, 32), 256, 0, stream>>>(
            xnb, tfs1[l], nullptr, hid, nullptr, 512, 2048);
        gemm_bt<32, 64, 2, 1, 0><<<dim3(8, 32), 256, 0, stream>>>(
            hid, tfs2[l], xemb, nullptr, xnew, 2048, 512);
        ln_dual_kernel<<<(N_ * T_) / 4, 256, 0, stream>>>(
            xemb, fsg + l * D_, fsb + l * D_, xemb, nullptr, N_ * T_);
    }

    pred_kernel<<<(N_ * T_ * 2 + 255) / 256, 256, 0, stream>>>(xemb, Wp, bp, osm);
    bcast_kernel<<<(NPRED_ * T_ * N_ * 2 + 255) / 256, 256, 0, stream>>>(osm, (float*)d_out);
}

// Round 12
// 897.275 us; speedup vs baseline: 54.7765x; 1.0978x over previous
//
#include <hip/hip_runtime.h>
#include <math.h>

// DTYPE COMMITMENTS (evidence-backed): inputs f32, output f32 (rounds 4-11 PASS).
// WS BUDGET: <= ~210 MB decimal; this build ~182 MiB (f32 n_emb dropped, NCH=2).

#define T_ 16
#define N_ 64
#define NN_ 32
#define D_ 512
#define H_ 8
#define DK_ 64
#define DFF_ 2048
#define L_ 2
#define NPRED_ 20

typedef unsigned short u16;
typedef unsigned int u32;
typedef __attribute__((ext_vector_type(8))) short short8;
typedef __attribute__((ext_vector_type(4))) float f32x4;

__device__ __forceinline__ u16 f2bf(float f) {
    u32 u = __float_as_uint(f);
    u32 r = u + 0x7fffu + ((u >> 16) & 1u);
    return (u16)(r >> 16);
}
__device__ __forceinline__ float bfv(u16 v) {
    return __uint_as_float(((u32)v) << 16);
}
__device__ __forceinline__ float ntn(float v) {
    if (isnan(v)) return 0.0f;
    if (isinf(v)) return v > 0.0f ? 3.4028234663852886e38f : -3.4028234663852886e38f;
    return v;
}
__device__ __forceinline__ float wave_sum(float v) {
    #pragma unroll
    for (int o = 32; o > 0; o >>= 1) v += __shfl_xor(v, o, 64);
    return v;
}
// async 16B HBM->LDS: writes ldsbase + lane*16 (wave-uniform base, per-lane gptr)
__device__ __forceinline__ void gload_lds(const u16* g, u16* l) {
    __builtin_amdgcn_global_load_lds(
        (const __attribute__((address_space(1))) u32*)g,
        (__attribute__((address_space(3))) u32*)l, 16, 0, 0);
}

// ============ batched weight convert+transpose: 14 jobs in ONE launch ===============
struct WJob { const float* src; u16* dst; int K; int N; int t0; };
struct WJobs { WJob j[14]; };
__global__ __launch_bounds__(256) void wconv_all(WJobs jobs, int ntiles) {
    int bid = blockIdx.x;
    if (bid >= ntiles) return;
    int ji = 0;
    #pragma unroll 1
    for (int i = 1; i < 14; ++i) if (bid >= jobs.j[i].t0) ji = i;
    const float* in = jobs.j[ji].src;
    u16* out = jobs.j[ji].dst;
    int K = jobs.j[ji].K, N = jobs.j[ji].N;
    int lt = bid - jobs.j[ji].t0;
    int ntx = N >> 5;
    int nb = (lt % ntx) * 32, kb = (lt / ntx) * 32;
    __shared__ float tile[32][33];
    int tx = threadIdx.x & 31, ty = threadIdx.x >> 5;
    #pragma unroll
    for (int r = ty; r < 32; r += 8)
        tile[r][tx] = in[(size_t)(kb + r) * N + nb + tx];
    __syncthreads();
    #pragma unroll
    for (int r = ty; r < 32; r += 8)
        out[(size_t)(nb + r) * K + kb + tx] = f2bf(tile[tx][r]);
}

// ============ MFMA GEMM v3 + XCD-band remap =========================================
// DMA staging + 3-bit XOR chunk swizzle (r9: 0 bank conflicts); XCD remap (r10:
// ffi2 FETCH 140->20 MB). EPI: 0 none, 1 relu, 2 +res f32, 3 +res bf16.
// In-place allowed for EPI=2 with Rg==Cf (same-thread read-then-write).
// Grid (N/TN, M/TM), gridY%8==0 for remap, K%64==0.
template<int TM, int TN, int EPI, int WF32, int WBF16>
__global__ __launch_bounds__(256) void gemm_bt(
    const u16* __restrict__ Ab, const u16* __restrict__ Btb,
    float* __restrict__ Cf, u16* __restrict__ Cb, const void* __restrict__ Rg,
    int K, int ldc)
{
    constexpr int WR = TM / 32, WC = TN / 32;
    constexpr int ITA = TM / 32, ITB = TN / 32;
    __shared__ __align__(16) u16 As[TM][64];
    __shared__ __align__(16) u16 Bs[TN][64];
    int tid = threadIdx.x;
    int lane = tid & 63, wave = tid >> 6;
    int quad = lane >> 4, l16 = lane & 15;
    int wm = (wave >> 1) * (TM / 2), wn = (wave & 1) * (TN / 2);

    int gx = gridDim.x, gy = gridDim.y;
    int bx, by;
    if ((gy & 7) == 0) {
        int id = blockIdx.y * gx + blockIdx.x;
        int xcd = id & 7;
        int slot = id >> 3;
        bx = slot % gx;
        by = xcd * (gy >> 3) + slot / gx;
    } else {
        bx = blockIdx.x;
        by = blockIdx.y;
    }
    size_t row0 = (size_t)by * TM;
    size_t col0 = (size_t)bx * TN;

    f32x4 acc[WR][WC];
    #pragma unroll
    for (int i = 0; i < WR; ++i)
        #pragma unroll
        for (int j = 0; j < WC; ++j)
            acc[i][j] = (f32x4){0.f, 0.f, 0.f, 0.f};

    int srow = lane >> 3;
    int c8 = (lane & 7) ^ srow;
    int h8 = l16 & 7;

    for (int k0 = 0; k0 < K; k0 += 64) {
        __syncthreads();
        #pragma unroll
        for (int it = 0; it < ITA; ++it) {
            int g = wave + it * 4;
            gload_lds(Ab + (row0 + g * 8 + srow) * (size_t)K + k0 + c8 * 8, &As[g * 8][0]);
        }
        #pragma unroll
        for (int it = 0; it < ITB; ++it) {
            int g = wave + it * 4;
            gload_lds(Btb + (col0 + g * 8 + srow) * (size_t)K + k0 + c8 * 8, &Bs[g * 8][0]);
        }
        __syncthreads();
        #pragma unroll
        for (int s = 0; s < 2; ++s) {
            int coff = ((s * 4 + quad) ^ h8) * 8;   // full 3-bit XOR (r9-verified)
            short8 af[WR], bf[WC];
            #pragma unroll
            for (int i = 0; i < WR; ++i)
                af[i] = *(short8*)&As[wm + i * 16 + l16][coff];
            #pragma unroll
            for (int j = 0; j < WC; ++j)
                bf[j] = *(short8*)&Bs[wn + j * 16 + l16][coff];
            #pragma unroll
            for (int i = 0; i < WR; ++i)
                #pragma unroll
                for (int j = 0; j < WC; ++j)
                    acc[i][j] = __builtin_amdgcn_mfma_f32_16x16x32_bf16(
                        af[i], bf[j], acc[i][j], 0, 0, 0);
        }
    }
    // C/D layout (on-target verified): col = lane&15, row = quad*4 + reg
    #pragma unroll
    for (int i = 0; i < WR; ++i)
        #pragma unroll
        for (int j = 0; j < WC; ++j)
            #pragma unroll
            for (int reg = 0; reg < 4; ++reg) {
                size_t row = row0 + wm + i * 16 + quad * 4 + reg;
                size_t col = col0 + wn + j * 16 + l16;
                float v = acc[i][j][reg];
                if (EPI == 2) v += ((const float*)Rg)[row * (size_t)ldc + col];
                if (EPI == 3) v += bfv(((const u16*)Rg)[row * (size_t)ldc + col]);
                if (EPI == 1) v = fmaxf(v, 0.f);
                if (WF32)  Cf[row * (size_t)ldc + col] = v;
                if (WBF16) Cb[row * (size_t)ldc + col] = f2bf(v);
            }
}

// ============ fused attention per (b,m): all-heads phases, 3 barriers ===============
// QKVb: [rows][1536] bf16 (Q 0..511, K 512..1023, V 1024..1535; col = h*64+dk).
template<int CTX>
__global__ __launch_bounds__(256) void attn_fused_kernel(
    const u16* __restrict__ QKVb, const float* __restrict__ maskf, int bm0,
    float* __restrict__ att_sum, u16* __restrict__ ctxb)
{
    __shared__ __align__(16) u16 sQ[16][520];
    __shared__ __align__(16) u16 sK[16][520];
    __shared__ __align__(16) u16 sV[CTX ? 16 : 1][520];
    __shared__ float s_p[H_][16][17];
    int bm_l = blockIdx.x;
    int tid = threadIdx.x;
    int t = tid >> 4, ch = (tid & 15) * 32;
    const u16* base = QKVb + ((size_t)bm_l * T_ + t) * 1536;
    #pragma unroll
    for (int c = 0; c < 4; ++c) {
        *(uint4*)&sQ[t][ch + c * 8] = *(const uint4*)(base + ch + c * 8);
        *(uint4*)&sK[t][ch + c * 8] = *(const uint4*)(base + 512 + ch + c * 8);
        if (CTX) *(uint4*)&sV[t][ch + c * 8] = *(const uint4*)(base + 1024 + ch + c * 8);
    }
    __syncthreads();

    int b = (bm0 + bm_l) >> 5;                  // bm = b*NN + m

    #pragma unroll
    for (int r = 0; r < 8; ++r) {
        int h = r;
        int q = (tid >> 4) & 15, k = tid & 15;
        const u32* qu = (const u32*)&sQ[q][0] + h * 32;
        const u32* ku = (const u32*)&sK[k][0] + h * 32;
        float acc = 0.f;
        #pragma unroll
        for (int j = 0; j < 32; ++j) {
            u32 a = qu[j], bb = ku[j];
            acc += bfv((u16)(a & 0xffff)) * bfv((u16)(bb & 0xffff));
            acc += bfv((u16)(a >> 16))    * bfv((u16)(bb >> 16));
        }
        acc *= 0.125f;
        if (maskf[(size_t)(bm0 + bm_l) * T_ + q] == 0.0f) acc = -1e9f;
        s_p[h][q][k] = acc;
    }
    __syncthreads();
    if (tid < 128) {
        int h = tid >> 4, q = tid & 15;
        float mx = -3.4e38f;
        #pragma unroll
        for (int kk = 0; kk < 16; ++kk) mx = fmaxf(mx, s_p[h][q][kk]);
        float e[16], s = 0.f;
        #pragma unroll
        for (int kk = 0; kk < 16; ++kk) { e[kk] = expf(s_p[h][q][kk] - mx); s += e[kk]; }
        float inv = 1.0f / s;
        #pragma unroll
        for (int kk = 0; kk < 16; ++kk) s_p[h][q][kk] = e[kk] * inv;
    }
    __syncthreads();
    #pragma unroll
    for (int r = 0; r < 8; ++r) {
        int h = r;
        int q = (tid >> 4) & 15, k = tid & 15;
        atomicAdd(&att_sum[(((size_t)b * H_ + h) * T_ + q) * T_ + k], s_p[h][q][k]);
    }
    if (CTX) {
        #pragma unroll
        for (int rep = 0; rep < 32; ++rep) {
            int i = rep * 256 + tid;            // t*512 + c, c = h*64+dk
            int tt = i >> 9, c = i & 511;
            int h = c >> 6;
            float acc = 0.f;
            #pragma unroll
            for (int kk = 0; kk < 16; ++kk)
                acc += s_p[h][tt][kk] * bfv(sV[kk][c]);
            ctxb[((size_t)bm_l * T_ + tt) * D_ + c] = f2bf(acc);
        }
    }
}

// ============ fused self-attention + combine + si, one block per (n,h) ==============
__global__ __launch_bounds__(256) void siatt_kernel(
    const float* __restrict__ xemb, const float* __restrict__ att_sum,
    const float* __restrict__ attf, u16* __restrict__ sib)
{
    __shared__ float sX[16][516];
    __shared__ float sS[16][17];
    __shared__ float sA[16][17];
    int n = blockIdx.x >> 3, h = blockIdx.x & 7;
    int tid = threadIdx.x;
    int t = tid >> 4, ch = (tid & 15) * 32;
    const float* src = xemb + ((size_t)n * T_ + t) * D_;
    #pragma unroll
    for (int c = 0; c < 8; ++c)
        *(float4*)&sX[t][ch + c * 4] = *(const float4*)(src + ch + c * 4);
    __syncthreads();
    int q = tid >> 4, k = tid & 15;
    {
        float acc = 0.f;
        for (int d = 0; d < D_; ++d) acc += sX[q][d] * sX[k][d];
        sS[q][k] = acc * 0.04419417382415922f;
    }
    __syncthreads();
    if (tid < T_) {
        float mx = -3.4e38f;
        #pragma unroll
        for (int kk = 0; kk < 16; ++kk) mx = fmaxf(mx, sS[tid][kk]);
        float e[16], s = 0.f;
        #pragma unroll
        for (int kk = 0; kk < 16; ++kk) { e[kk] = expf(sS[tid][kk] - mx); s += e[kk]; }
        float inv = 1.0f / s;
        #pragma unroll
        for (int kk = 0; kk < 16; ++kk) sS[tid][kk] = e[kk] * inv;
    }
    __syncthreads();
    float f = attf[0] * (1.0f / 32.0f);
    sA[q][k] = sS[q][k] + f * att_sum[((size_t)n * H_ + h) * 256 + q * 16 + k];
    __syncthreads();
    #pragma unroll
    for (int rep = 0; rep < 32; ++rep) {
        int i = rep * 256 + tid;          // q*512 + d
        int qq = i >> 9, d = i & 511;
        float acc = 0.f;
        #pragma unroll
        for (int tt = 0; tt < 16; ++tt) acc += sA[qq][tt] * sX[tt][d];
        sib[(size_t)n * T_ * 4096 + (size_t)qq * 4096 + h * 512 + d] = f2bf(acc);
    }
}

// ---------------- positional encoding ------------------------------------------------
__global__ void pe_kernel(float* pe) {
    int i = blockIdx.x * blockDim.x + threadIdx.x;
    if (i >= T_ * 256) return;
    int t = i >> 8, j = i & 255;
    float dv = (float)pow(10000.0, (double)j / 256.0);
    float a = (float)t * dv;
    double ad = (double)a;
    pe[t * D_ + 2 * j]     = (float)sin(ad);
    pe[t * D_ + 2 * j + 1] = (float)cos(ad);
}

// ---------------- x features + embed -------------------------------------------------
__global__ void xemb_kernel(const float* x, const float* Wx, const float* bx,
                            const float* pe, float* xemb) {
    int row = blockIdx.x;              // t*N + n
    int t = row / N_, n = row % N_;
    float x0 = x[row * 6 + 0], x1 = x[row * 6 + 1];
    float x2 = x[row * 6 + 2], x3 = x[row * 6 + 3];
    float x4 = x[row * 6 + 4], x5 = x[row * 6 + 5];
    float vel = sqrtf(x2 * x2 + x3 * x3);
    float ang = atanf(x5 / x4);
    float f0 = ntn(x0), f1 = ntn(x1), f2 = ntn(vel), f3 = ntn(ang);
    for (int d = threadIdx.x; d < D_; d += blockDim.x) {
        xemb[((size_t)n * T_ + t) * D_ + d] =
            f0 * Wx[0 * D_ + d] + f1 * Wx[1 * D_ + d]
          + f2 * Wx[2 * D_ + d] + f3 * Wx[3 * D_ + d]
          + bx[d] + pe[t * D_ + d];
    }
}

// ---------------- neighbor features + mask -------------------------------------------
__global__ void nbr_kernel(const float* x, const float* nbr, float* nf, float* maskf) {
    int idx = blockIdx.x * blockDim.x + threadIdx.x;   // t*N*NN + n*NN + m
    if (idx >= T_ * N_ * NN_) return;
    int m = idx % NN_;
    int tn = idx / NN_;
    int n = tn % N_, t = tn / N_;
    float px = x[((size_t)t * N_ + n) * 6 + 0];
    float py = x[((size_t)t * N_ + n) * 6 + 1];
    float vx, vy;
    if (t == 0) {
        vx = x[((size_t)1 * N_ + n) * 6 + 2];
        vy = x[((size_t)1 * N_ + n) * 6 + 3];
    } else {
        vx = px - x[((size_t)(t - 1) * N_ + n) * 6 + 0];
        vy = py - x[((size_t)(t - 1) * N_ + n) * 6 + 1];
    }
    float nx  = nbr[(size_t)idx * 4 + 0], ny  = nbr[(size_t)idx * 4 + 1];
    float nvx = nbr[(size_t)idx * 4 + 2], nvy = nbr[(size_t)idx * 4 + 3];
    float dpx = nx - px, dpy = ny - py;
    float dvx = nvx - vx, dvy = nvy - vy;
    float dist = sqrtf(dpx * dpx + dpy * dpy);
    maskf[((size_t)n * NN_ + m) * T_ + t] = (dist <= 2.0f) ? 1.0f : 0.0f;
    float vn = sqrtf(vx * vx + vy * vy);
    float bearing = (dpx * vx + dpy * vy) / (dist * vn);
    if (isnan(bearing)) bearing = 0.0f;
    float dvn = sqrtf(dvx * dvx + dvy * dvy);
    float tau = -(dpx * dvx + dpy * dvy) / dvn;
    if (isnan(tau)) tau = 0.0f;
    tau = fminf(fmaxf(tau, 0.0f), 7.0f);
    float mx_ = dpx + tau * dvx, my_ = dpy + tau * dvy;
    float mpd = sqrtf(mx_ * mx_ + my_ * my_);
    nf[(size_t)idx * 3 + 0] = ntn(dist);
    nf[(size_t)idx * 3 + 1] = ntn(bearing);
    nf[(size_t)idx * 3 + 2] = ntn(mpd);
}

// ---------------- neighbor embed: bf16 n_emb only ------------------------------------
__global__ void nemb_kernel(const float* nf, const float* Wn, const float* bn,
                            const float* pe, u16* Ab) {
    int row = blockIdx.x;              // (b*NN+m)*T + t
    int t = row % T_;
    int bm = row / T_;
    int m = bm % NN_, b = bm / NN_;
    size_t nfrow = (((size_t)t * N_ + b) * NN_ + m) * 3;
    float f0 = nf[nfrow], f1 = nf[nfrow + 1], f2 = nf[nfrow + 2];
    for (int d = threadIdx.x; d < D_; d += blockDim.x) {
        float v = f0 * Wn[d] + f1 * Wn[D_ + d] + f2 * Wn[2 * D_ + d]
                + bn[d] + pe[t * D_ + d];
        Ab[(size_t)row * D_ + d] = f2bf(v);
    }
}

// ---------------- LayerNorm, one wave per row, dual-width output ---------------------
__global__ __launch_bounds__(256) void ln_dual_kernel(
    const float* X, const float* g, const float* b, float* outF, u16* outB, int nrows) {
    int row = blockIdx.x * 4 + (threadIdx.x >> 6);
    if (row >= nrows) return;
    int lane = threadIdx.x & 63;
    const float* p = X + (size_t)row * D_;
    float v[8];
    float s = 0.f;
    #pragma unroll
    for (int r = 0; r < 8; ++r) { v[r] = p[lane + r * 64]; s += v[r]; }
    s = wave_sum(s);
    float mean = s * (1.0f / 512.0f);
    float vs = 0.f;
    #pragma unroll
    for (int r = 0; r < 8; ++r) { float d = v[r] - mean; vs += d * d; }
    vs = wave_sum(vs);
    float rstd = rsqrtf(vs * (1.0f / 512.0f) + 1e-5f);
    #pragma unroll
    for (int r = 0; r < 8; ++r) {
        int d = lane + r * 64;
        float o = (v[r] - mean) * rstd * g[d] + b[d];
        if (outF) outF[(size_t)row * D_ + d] = o;
        if (outB) outB[(size_t)row * D_ + d] = f2bf(o);
    }
}

// ---------------- prediction head + broadcast fused (f32 out) ------------------------
__global__ void predbcast_kernel(const float* xemb, const float* Wp, const float* bp,
                                 float* out) {
    int idx = blockIdx.x * blockDim.x + threadIdx.x;   // (n*T+t)*2 + c
    if (idx >= N_ * T_ * 2) return;
    int c = idx & 1;
    int nt = idx >> 1;
    int n = nt / T_, t = nt % T_;
    float acc = bp[c];
    for (int j = 0; j < D_; ++j) acc += xemb[(size_t)nt * D_ + j] * Wp[(size_t)j * 2 + c];
    #pragma unroll
    for (int p = 0; p < NPRED_; ++p)
        out[(((size_t)p * T_ + t) * N_ + n) * 2 + c] = acc;
}

extern "C" void kernel_launch(void* const* d_in, const int* in_sizes, int n_in,
                              void* d_out, int out_size, void* d_ws, size_t ws_size,
                              hipStream_t stream) {
    (void)in_sizes; (void)n_in; (void)out_size; (void)ws_size;

    const float* x    = (const float*)d_in[0];
    const float* nbr  = (const float*)d_in[1];
    const float* attf = (const float*)d_in[2];
    const float* Wx   = (const float*)d_in[3];
    const float* bx   = (const float*)d_in[4];
    const float* Wn   = (const float*)d_in[5];
    const float* bn   = (const float*)d_in[6];
    const float* Wp   = (const float*)d_in[7];
    const float* bp   = (const float*)d_in[8];
    const float* WQ   = (const float*)d_in[9];
    const float* WK   = (const float*)d_in[10];
    const float* WV   = (const float*)d_in[11];
    const float* Wfc  = (const float*)d_in[12];
    const float* mlng = (const float*)d_in[13];
    const float* mlnb = (const float*)d_in[14];
    const float* WSI  = (const float*)d_in[15];
    const float* fsw1 = (const float*)d_in[16];
    const float* fsw2 = (const float*)d_in[17];
    const float* fsg  = (const float*)d_in[18];
    const float* fsb  = (const float*)d_in[19];
    const float* fiw1 = (const float*)d_in[20];
    const float* fiw2 = (const float*)d_in[21];
    const float* fig  = (const float*)d_in[22];
    const float* fib  = (const float*)d_in[23];

    char* w = (char*)d_ws;
    size_t off = 0;
    auto alloc = [&](size_t bytes) -> void* {
        void* p = w + off;
        off = (off + bytes + 255) & ~(size_t)255;
        return p;
    };
    const size_t MiB = 1024 * 1024;

    const int BM = N_ * NN_;          // 2048 (b,m) pairs
    const int ROWS_I = BM * T_;       // 32768 neighbor rows
    const int CB = 1024;              // bm per chunk (NCH=2)
    const int RC = CB * T_;           // 16384 rows per chunk
    const int NCH = ROWS_I / RC;      // 2

    float* pe      = (float*)alloc((size_t)T_ * D_ * 4);
    float* xemb    = (float*)alloc((size_t)N_ * T_ * D_ * 4);
    float* nf      = (float*)alloc((size_t)T_ * N_ * NN_ * 3 * 4);
    float* maskf   = (float*)alloc((size_t)BM * T_ * 4);
    u16*   Ab      = (u16*)alloc((size_t)ROWS_I * D_ * 2);     // n_emb bf16  32 MiB
    u16* tQKV[2], *tWSI[2], *tfs1[2], *tfs2[2];
    for (int l = 0; l < 2; ++l) {
        tQKV[l] = (u16*)alloc((size_t)1536 * 512 * 2);
        tWSI[l] = (u16*)alloc((size_t)512 * 4096 * 2);
        tfs1[l] = (u16*)alloc((size_t)2048 * 512 * 2);
        tfs2[l] = (u16*)alloc((size_t)512 * 2048 * 2);
    }
    u16* tWfc = (u16*)alloc((size_t)512 * 512 * 2);
    u16* tfi1 = (u16*)alloc((size_t)2048 * 512 * 2);
    u16* tfi2 = (u16*)alloc((size_t)512 * 2048 * 2);
    // scratch union: QKVb 48 MiB + ctxb 16 MiB  vs  hid 64 MiB (RC x 2048 bf16)
    char* SCR  = (char*)alloc(64 * MiB);
    u16*   QKVb = (u16*)SCR;
    u16*   ctxb = (u16*)(SCR + 48 * MiB);
    u16*   hid  = (u16*)SCR;
    float* Bch  = (float*)alloc((size_t)RC * D_ * 4);  // res_inter chunk f32  32 MiB
    u16*   Bbch = (u16*)alloc((size_t)RC * D_ * 2);    //                      16 MiB
    float* att_sum = (float*)alloc((size_t)N_ * H_ * 256 * 4);
    u16*   sib     = (u16*)alloc((size_t)N_ * T_ * 4096 * 2);  // 8 MiB
    float* xnew    = (float*)alloc((size_t)N_ * T_ * D_ * 4);
    u16*   xnb     = (u16*)alloc((size_t)N_ * T_ * D_ * 2);
    // total ~182 MiB

    // ---- batched weight conversion: 14 jobs, one launch ----
    WJobs jobs;
    int ntiles = 0;
    auto addJob = [&](int idx, const float* src, u16* dst, int K, int N) {
        jobs.j[idx] = {src, dst, K, N, ntiles};
        ntiles += (N >> 5) * (K >> 5);
    };
    addJob(0,  WQ,                            tQKV[0],              512, 512);
    addJob(1,  WK,                            tQKV[0] + 512 * 512,  512, 512);
    addJob(2,  WV,                            tQKV[0] + 1024 * 512, 512, 512);   // dead at l=1
    addJob(3,  WQ + (size_t)512 * 512,        tQKV[1],              512, 512);
    addJob(4,  WK + (size_t)512 * 512,        tQKV[1] + 512 * 512,  512, 512);
    addJob(5,  Wfc,                           tWfc,                 512, 512);
    addJob(6,  WSI,                           tWSI[0],              4096, 512);
    addJob(7,  WSI + (size_t)4096 * 512,      tWSI[1],              4096, 512);
    addJob(8,  fsw1,                          tfs1[0],              512, 2048);
    addJob(9,  fsw1 + (size_t)512 * 2048,     tfs1[1],              512, 2048);
    addJob(10, fsw2,                          tfs2[0],              2048, 512);
    addJob(11, fsw2 + (size_t)2048 * 512,     tfs2[1],              2048, 512);
    addJob(12, fiw1,                          tfi1,                 512, 2048);
    addJob(13, fiw2,                          tfi2,                 2048, 512);
    wconv_all<<<ntiles, 256, 0, stream>>>(jobs, ntiles);

    pe_kernel<<<16, 256, 0, stream>>>(pe);
    xemb_kernel<<<T_ * N_, 256, 0, stream>>>(x, Wx, bx, pe, xemb);
    nbr_kernel<<<(T_ * N_ * NN_ + 255) / 256, 256, 0, stream>>>(x, nbr, nf, maskf);
    nemb_kernel<<<BM * T_, 256, 0, stream>>>(nf, Wn, bn, pe, Ab);

    for (int l = 0; l < L_; ++l) {
        hipMemsetAsync(att_sum, 0, (size_t)N_ * H_ * 256 * 4, stream);
        for (int c = 0; c < NCH; ++c) {
            u16* Acb = Ab + (size_t)c * RC * D_;
            if (l == 0) {
                // QKV fused GEMM: N=1536, 128x128 (1536 blocks)
                gemm_bt<128, 128, 0, 0, 1><<<dim3(12, RC / 128), 256, 0, stream>>>(
                    Acb, tQKV[0], nullptr, QKVb, nullptr, 512, 1536);
                attn_fused_kernel<1><<<CB, 256, 0, stream>>>(
                    QKVb, maskf, c * CB, att_sum, ctxb);
                // fc + residual(n_emb bf16): N=512, 128x64 (1024 blocks)
                gemm_bt<128, 64, 3, 1, 0><<<dim3(8, RC / 128), 256, 0, stream>>>(
                    ctxb, tWfc, Bch, nullptr, Acb, 512, 512);
                ln_dual_kernel<<<RC / 4, 256, 0, stream>>>(
                    Bch, mlng, mlnb, Bch, Bbch, RC);         // Bch = res_inter f32
                // ffi1 relu: N=2048, 128x128 (2048 blocks); hid aliases QKVb/ctxb
                gemm_bt<128, 128, 1, 0, 1><<<dim3(16, RC / 128), 256, 0, stream>>>(
                    Bbch, tfi1, nullptr, hid, nullptr, 512, 2048);
                // ffi2 + residual(res_inter), IN-PLACE into Bch (pre-LN)
                gemm_bt<128, 64, 2, 1, 0><<<dim3(8, RC / 128), 256, 0, stream>>>(
                    hid, tfi2, Bch, nullptr, Bch, 2048, 512);
                ln_dual_kernel<<<RC / 4, 256, 0, stream>>>(
                    Bch, fig, fib, nullptr, Acb, RC);        // new n_emb (bf16)
            } else {
                // QK only: N=1024 (1536-stride output)
                gemm_bt<128, 128, 0, 0, 1><<<dim3(8, RC / 128), 256, 0, stream>>>(
                    Acb, tQKV[1], nullptr, QKVb, nullptr, 512, 1536);
                attn_fused_kernel<0><<<CB, 256, 0, stream>>>(
                    QKVb, maskf, c * CB, att_sum, nullptr);
            }
        }

        // ---- self-attention + si + ffs (updates xemb) ----
        siatt_kernel<<<N_ * H_, 256, 0, stream>>>(xemb, att_sum, attf, sib);
        gemm_bt<32, 64, 0, 1, 1><<<dim3(8, 32), 256, 0, stream>>>(
            sib, tWSI[l], xnew, xnb, nullptr, 4096, 512);
        gemm_bt<32, 64, 1, 0, 1><<<dim3(32, 32), 256, 0, stream>>>(
            xnb, tfs1[l], nullptr, hid, nullptr, 512, 2048);
        gemm_bt<32, 64, 2, 1, 0><<<dim3(8, 32), 256, 0, stream>>>(
            hid, tfs2[l], xemb, nullptr, xnew, 2048, 512);
        ln_dual_kernel<<<(N_ * T_) / 4, 256, 0, stream>>>(
            xemb, fsg + l * D_, fsb + l * D_, xemb, nullptr, N_ * T_);
    }

    predbcast_kernel<<<(N_ * T_ * 2 + 255) / 256, 256, 0, stream>>>(
        xemb, Wp, bp, (float*)d_out);
}

// Round 13
// 842.405 us; speedup vs baseline: 58.3444x; 1.0651x over previous
//
#include <hip/hip_runtime.h>
#include <math.h>

// DTYPE COMMITMENTS (evidence-backed): inputs f32, output f32 (rounds 4-12 PASS).
// WS BUDGET: <= ~210 MB decimal; this build ~182 MiB.

#define T_ 16
#define N_ 64
#define NN_ 32
#define D_ 512
#define H_ 8
#define DK_ 64
#define DFF_ 2048
#define L_ 2
#define NPRED_ 20

typedef unsigned short u16;
typedef unsigned int u32;
typedef __attribute__((ext_vector_type(8))) short short8;
typedef __attribute__((ext_vector_type(4))) float f32x4;

__device__ __forceinline__ u16 f2bf(float f) {
    u32 u = __float_as_uint(f);
    u32 r = u + 0x7fffu + ((u >> 16) & 1u);
    return (u16)(r >> 16);
}
__device__ __forceinline__ float bfv(u16 v) {
    return __uint_as_float(((u32)v) << 16);
}
__device__ __forceinline__ float ntn(float v) {
    if (isnan(v)) return 0.0f;
    if (isinf(v)) return v > 0.0f ? 3.4028234663852886e38f : -3.4028234663852886e38f;
    return v;
}
__device__ __forceinline__ float wave_sum(float v) {
    #pragma unroll
    for (int o = 32; o > 0; o >>= 1) v += __shfl_xor(v, o, 64);
    return v;
}
// async 16B HBM->LDS: writes ldsbase + lane*16 (wave-uniform base, per-lane gptr)
__device__ __forceinline__ void gload_lds(const u16* g, u16* l) {
    __builtin_amdgcn_global_load_lds(
        (const __attribute__((address_space(1))) u32*)g,
        (__attribute__((address_space(3))) u32*)l, 16, 0, 0);
}

// ============ batched weight convert+transpose: 14 jobs in ONE launch ===============
struct WJob { const float* src; u16* dst; int K; int N; int t0; };
struct WJobs { WJob j[14]; };
__global__ __launch_bounds__(256) void wconv_all(WJobs jobs, int ntiles) {
    int bid = blockIdx.x;
    if (bid >= ntiles) return;
    int ji = 0;
    #pragma unroll 1
    for (int i = 1; i < 14; ++i) if (bid >= jobs.j[i].t0) ji = i;
    const float* in = jobs.j[ji].src;
    u16* out = jobs.j[ji].dst;
    int K = jobs.j[ji].K, N = jobs.j[ji].N;
    int lt = bid - jobs.j[ji].t0;
    int ntx = N >> 5;
    int nb = (lt % ntx) * 32, kb = (lt / ntx) * 32;
    __shared__ float tile[32][33];
    int tx = threadIdx.x & 31, ty = threadIdx.x >> 5;
    #pragma unroll
    for (int r = ty; r < 32; r += 8)
        tile[r][tx] = in[(size_t)(kb + r) * N + nb + tx];
    __syncthreads();
    #pragma unroll
    for (int r = ty; r < 32; r += 8)
        out[(size_t)(nb + r) * K + kb + tx] = f2bf(tile[tx][r]);
}

// ============ MFMA GEMM v3 + XCD-band remap =========================================
// DMA staging + 3-bit XOR chunk swizzle (r9: 0 bank conflicts); XCD remap (r10:
// ffi2 FETCH 140->20 MB). EPI: 0 none, 1 relu, 2 +res f32, 3 +res bf16.
// In-place allowed for EPI=2 with Rg==Cf (same-thread read-then-write).
// Grid (N/TN, M/TM), gridY%8==0 for remap, K%64==0.
template<int TM, int TN, int EPI, int WF32, int WBF16>
__global__ __launch_bounds__(256) void gemm_bt(
    const u16* __restrict__ Ab, const u16* __restrict__ Btb,
    float* __restrict__ Cf, u16* __restrict__ Cb, const void* __restrict__ Rg,
    int K, int ldc)
{
    constexpr int WR = TM / 32, WC = TN / 32;
    constexpr int ITA = TM / 32, ITB = TN / 32;
    __shared__ __align__(16) u16 As[TM][64];
    __shared__ __align__(16) u16 Bs[TN][64];
    int tid = threadIdx.x;
    int lane = tid & 63, wave = tid >> 6;
    int quad = lane >> 4, l16 = lane & 15;
    int wm = (wave >> 1) * (TM / 2), wn = (wave & 1) * (TN / 2);

    int gx = gridDim.x, gy = gridDim.y;
    int bx, by;
    if ((gy & 7) == 0) {
        int id = blockIdx.y * gx + blockIdx.x;
        int xcd = id & 7;
        int slot = id >> 3;
        bx = slot % gx;
        by = xcd * (gy >> 3) + slot / gx;
    } else {
        bx = blockIdx.x;
        by = blockIdx.y;
    }
    size_t row0 = (size_t)by * TM;
    size_t col0 = (size_t)bx * TN;

    f32x4 acc[WR][WC];
    #pragma unroll
    for (int i = 0; i < WR; ++i)
        #pragma unroll
        for (int j = 0; j < WC; ++j)
            acc[i][j] = (f32x4){0.f, 0.f, 0.f, 0.f};

    int srow = lane >> 3;
    int c8 = (lane & 7) ^ srow;
    int h8 = l16 & 7;

    for (int k0 = 0; k0 < K; k0 += 64) {
        __syncthreads();
        #pragma unroll
        for (int it = 0; it < ITA; ++it) {
            int g = wave + it * 4;
            gload_lds(Ab + (row0 + g * 8 + srow) * (size_t)K + k0 + c8 * 8, &As[g * 8][0]);
        }
        #pragma unroll
        for (int it = 0; it < ITB; ++it) {
            int g = wave + it * 4;
            gload_lds(Btb + (col0 + g * 8 + srow) * (size_t)K + k0 + c8 * 8, &Bs[g * 8][0]);
        }
        __syncthreads();
        #pragma unroll
        for (int s = 0; s < 2; ++s) {
            int coff = ((s * 4 + quad) ^ h8) * 8;   // full 3-bit XOR (r9-verified)
            short8 af[WR], bf[WC];
            #pragma unroll
            for (int i = 0; i < WR; ++i)
                af[i] = *(short8*)&As[wm + i * 16 + l16][coff];
            #pragma unroll
            for (int j = 0; j < WC; ++j)
                bf[j] = *(short8*)&Bs[wn + j * 16 + l16][coff];
            #pragma unroll
            for (int i = 0; i < WR; ++i)
                #pragma unroll
                for (int j = 0; j < WC; ++j)
                    acc[i][j] = __builtin_amdgcn_mfma_f32_16x16x32_bf16(
                        af[i], bf[j], acc[i][j], 0, 0, 0);
        }
    }
    // C/D layout (on-target verified): col = lane&15, row = quad*4 + reg
    #pragma unroll
    for (int i = 0; i < WR; ++i)
        #pragma unroll
        for (int j = 0; j < WC; ++j)
            #pragma unroll
            for (int reg = 0; reg < 4; ++reg) {
                size_t row = row0 + wm + i * 16 + quad * 4 + reg;
                size_t col = col0 + wn + j * 16 + l16;
                float v = acc[i][j][reg];
                if (EPI == 2) v += ((const float*)Rg)[row * (size_t)ldc + col];
                if (EPI == 3) v += bfv(((const u16*)Rg)[row * (size_t)ldc + col]);
                if (EPI == 1) v = fmaxf(v, 0.f);
                if (WF32)  Cf[row * (size_t)ldc + col] = v;
                if (WBF16) Cb[row * (size_t)ldc + col] = f2bf(v);
            }
}

// ============ fused attention per (b,m): all-heads phases, 3 barriers ===============
// QKVb: [rows][LD] bf16 (Q 0..511, K 512..1023, V 1024..1535 when CTX; col=h*64+dk).
template<int CTX, int LD>
__global__ __launch_bounds__(256) void attn_fused_kernel(
    const u16* __restrict__ QKVb, const float* __restrict__ maskf, int bm0,
    float* __restrict__ att_sum, u16* __restrict__ ctxb)
{
    __shared__ __align__(16) u16 sQ[16][520];
    __shared__ __align__(16) u16 sK[16][520];
    __shared__ __align__(16) u16 sV[CTX ? 16 : 1][520];
    __shared__ float s_p[H_][16][17];
    int bm_l = blockIdx.x;
    int tid = threadIdx.x;
    int t = tid >> 4, ch = (tid & 15) * 32;
    const u16* base = QKVb + ((size_t)bm_l * T_ + t) * LD;
    #pragma unroll
    for (int c = 0; c < 4; ++c) {
        *(uint4*)&sQ[t][ch + c * 8] = *(const uint4*)(base + ch + c * 8);
        *(uint4*)&sK[t][ch + c * 8] = *(const uint4*)(base + 512 + ch + c * 8);
        if (CTX) *(uint4*)&sV[t][ch + c * 8] = *(const uint4*)(base + 1024 + ch + c * 8);
    }
    __syncthreads();

    int b = (bm0 + bm_l) >> 5;                  // bm = b*NN + m

    #pragma unroll
    for (int r = 0; r < 8; ++r) {
        int h = r;
        int q = (tid >> 4) & 15, k = tid & 15;
        const u32* qu = (const u32*)&sQ[q][0] + h * 32;
        const u32* ku = (const u32*)&sK[k][0] + h * 32;
        float acc = 0.f;
        #pragma unroll
        for (int j = 0; j < 32; ++j) {
            u32 a = qu[j], bb = ku[j];
            acc += bfv((u16)(a & 0xffff)) * bfv((u16)(bb & 0xffff));
            acc += bfv((u16)(a >> 16))    * bfv((u16)(bb >> 16));
        }
        acc *= 0.125f;
        if (maskf[(size_t)(bm0 + bm_l) * T_ + q] == 0.0f) acc = -1e9f;
        s_p[h][q][k] = acc;
    }
    __syncthreads();
    if (tid < 128) {
        int h = tid >> 4, q = tid & 15;
        float mx = -3.4e38f;
        #pragma unroll
        for (int kk = 0; kk < 16; ++kk) mx = fmaxf(mx, s_p[h][q][kk]);
        float e[16], s = 0.f;
        #pragma unroll
        for (int kk = 0; kk < 16; ++kk) { e[kk] = expf(s_p[h][q][kk] - mx); s += e[kk]; }
        float inv = 1.0f / s;
        #pragma unroll
        for (int kk = 0; kk < 16; ++kk) s_p[h][q][kk] = e[kk] * inv;
    }
    __syncthreads();
    #pragma unroll
    for (int r = 0; r < 8; ++r) {
        int h = r;
        int q = (tid >> 4) & 15, k = tid & 15;
        atomicAdd(&att_sum[(((size_t)b * H_ + h) * T_ + q) * T_ + k], s_p[h][q][k]);
    }
    if (CTX) {
        #pragma unroll
        for (int rep = 0; rep < 32; ++rep) {
            int i = rep * 256 + tid;            // t*512 + c, c = h*64+dk
            int tt = i >> 9, c = i & 511;
            int h = c >> 6;
            float acc = 0.f;
            #pragma unroll
            for (int kk = 0; kk < 16; ++kk)
                acc += s_p[h][tt][kk] * bfv(sV[kk][c]);
            ctxb[((size_t)bm_l * T_ + tt) * D_ + c] = f2bf(acc);
        }
    }
}

// ============ fused self-attention + combine + si, one block per (n,h) ==============
__global__ __launch_bounds__(256) void siatt_kernel(
    const float* __restrict__ xemb, const float* __restrict__ att_sum,
    const float* __restrict__ attf, u16* __restrict__ sib)
{
    __shared__ float sX[16][516];
    __shared__ float sS[16][17];
    __shared__ float sA[16][17];
    int n = blockIdx.x >> 3, h = blockIdx.x & 7;
    int tid = threadIdx.x;
    int t = tid >> 4, ch = (tid & 15) * 32;
    const float* src = xemb + ((size_t)n * T_ + t) * D_;
    #pragma unroll
    for (int c = 0; c < 8; ++c)
        *(float4*)&sX[t][ch + c * 4] = *(const float4*)(src + ch + c * 4);
    __syncthreads();
    int q = tid >> 4, k = tid & 15;
    {
        float acc = 0.f;
        for (int d = 0; d < D_; ++d) acc += sX[q][d] * sX[k][d];
        sS[q][k] = acc * 0.04419417382415922f;
    }
    __syncthreads();
    if (tid < T_) {
        float mx = -3.4e38f;
        #pragma unroll
        for (int kk = 0; kk < 16; ++kk) mx = fmaxf(mx, sS[tid][kk]);
        float e[16], s = 0.f;
        #pragma unroll
        for (int kk = 0; kk < 16; ++kk) { e[kk] = expf(sS[tid][kk] - mx); s += e[kk]; }
        float inv = 1.0f / s;
        #pragma unroll
        for (int kk = 0; kk < 16; ++kk) sS[tid][kk] = e[kk] * inv;
    }
    __syncthreads();
    float f = attf[0] * (1.0f / 32.0f);
    sA[q][k] = sS[q][k] + f * att_sum[((size_t)n * H_ + h) * 256 + q * 16 + k];
    __syncthreads();
    #pragma unroll
    for (int rep = 0; rep < 32; ++rep) {
        int i = rep * 256 + tid;          // q*512 + d
        int qq = i >> 9, d = i & 511;
        float acc = 0.f;
        #pragma unroll
        for (int tt = 0; tt < 16; ++tt) acc += sA[qq][tt] * sX[tt][d];
        sib[(size_t)n * T_ * 4096 + (size_t)qq * 4096 + h * 512 + d] = f2bf(acc);
    }
}

// ---------------- positional encoding ------------------------------------------------
__global__ void pe_kernel(float* pe) {
    int i = blockIdx.x * blockDim.x + threadIdx.x;
    if (i >= T_ * 256) return;
    int t = i >> 8, j = i & 255;
    float dv = (float)pow(10000.0, (double)j / 256.0);
    float a = (float)t * dv;
    double ad = (double)a;
    pe[t * D_ + 2 * j]     = (float)sin(ad);
    pe[t * D_ + 2 * j + 1] = (float)cos(ad);
}

// ---------------- x features + embed -------------------------------------------------
__global__ void xemb_kernel(const float* x, const float* Wx, const float* bx,
                            const float* pe, float* xemb) {
    int row = blockIdx.x;              // t*N + n
    int t = row / N_, n = row % N_;
    float x0 = x[row * 6 + 0], x1 = x[row * 6 + 1];
    float x2 = x[row * 6 + 2], x3 = x[row * 6 + 3];
    float x4 = x[row * 6 + 4], x5 = x[row * 6 + 5];
    float vel = sqrtf(x2 * x2 + x3 * x3);
    float ang = atanf(x5 / x4);
    float f0 = ntn(x0), f1 = ntn(x1), f2 = ntn(vel), f3 = ntn(ang);
    for (int d = threadIdx.x; d < D_; d += blockDim.x) {
        xemb[((size_t)n * T_ + t) * D_ + d] =
            f0 * Wx[0 * D_ + d] + f1 * Wx[1 * D_ + d]
          + f2 * Wx[2 * D_ + d] + f3 * Wx[3 * D_ + d]
          + bx[d] + pe[t * D_ + d];
    }
}

// ---------------- neighbor features + mask -------------------------------------------
__global__ void nbr_kernel(const float* x, const float* nbr, float* nf, float* maskf) {
    int idx = blockIdx.x * blockDim.x + threadIdx.x;   // t*N*NN + n*NN + m
    if (idx >= T_ * N_ * NN_) return;
    int m = idx % NN_;
    int tn = idx / NN_;
    int n = tn % N_, t = tn / N_;
    float px = x[((size_t)t * N_ + n) * 6 + 0];
    float py = x[((size_t)t * N_ + n) * 6 + 1];
    float vx, vy;
    if (t == 0) {
        vx = x[((size_t)1 * N_ + n) * 6 + 2];
        vy = x[((size_t)1 * N_ + n) * 6 + 3];
    } else {
        vx = px - x[((size_t)(t - 1) * N_ + n) * 6 + 0];
        vy = py - x[((size_t)(t - 1) * N_ + n) * 6 + 1];
    }
    float nx  = nbr[(size_t)idx * 4 + 0], ny  = nbr[(size_t)idx * 4 + 1];
    float nvx = nbr[(size_t)idx * 4 + 2], nvy = nbr[(size_t)idx * 4 + 3];
    float dpx = nx - px, dpy = ny - py;
    float dvx = nvx - vx, dvy = nvy - vy;
    float dist = sqrtf(dpx * dpx + dpy * dpy);
    maskf[((size_t)n * NN_ + m) * T_ + t] = (dist <= 2.0f) ? 1.0f : 0.0f;
    float vn = sqrtf(vx * vx + vy * vy);
    float bearing = (dpx * vx + dpy * vy) / (dist * vn);
    if (isnan(bearing)) bearing = 0.0f;
    float dvn = sqrtf(dvx * dvx + dvy * dvy);
    float tau = -(dpx * dvx + dpy * dvy) / dvn;
    if (isnan(tau)) tau = 0.0f;
    tau = fminf(fmaxf(tau, 0.0f), 7.0f);
    float mx_ = dpx + tau * dvx, my_ = dpy + tau * dvy;
    float mpd = sqrtf(mx_ * mx_ + my_ * my_);
    nf[(size_t)idx * 3 + 0] = ntn(dist);
    nf[(size_t)idx * 3 + 1] = ntn(bearing);
    nf[(size_t)idx * 3 + 2] = ntn(mpd);
}

// ---------------- neighbor embed: bf16 n_emb only ------------------------------------
__global__ void nemb_kernel(const float* nf, const float* Wn, const float* bn,
                            const float* pe, u16* Ab) {
    int row = blockIdx.x;              // (b*NN+m)*T + t
    int t = row % T_;
    int bm = row / T_;
    int m = bm % NN_, b = bm / NN_;
    size_t nfrow = (((size_t)t * N_ + b) * NN_ + m) * 3;
    float f0 = nf[nfrow], f1 = nf[nfrow + 1], f2 = nf[nfrow + 2];
    for (int d = threadIdx.x; d < D_; d += blockDim.x) {
        float v = f0 * Wn[d] + f1 * Wn[D_ + d] + f2 * Wn[2 * D_ + d]
                + bn[d] + pe[t * D_ + d];
        Ab[(size_t)row * D_ + d] = f2bf(v);
    }
}

// ---------------- LayerNorm, one wave per row, dual-width output ---------------------
__global__ __launch_bounds__(256) void ln_dual_kernel(
    const float* X, const float* g, const float* b, float* outF, u16* outB, int nrows) {
    int row = blockIdx.x * 4 + (threadIdx.x >> 6);
    if (row >= nrows) return;
    int lane = threadIdx.x & 63;
    const float* p = X + (size_t)row * D_;
    float v[8];
    float s = 0.f;
    #pragma unroll
    for (int r = 0; r < 8; ++r) { v[r] = p[lane + r * 64]; s += v[r]; }
    s = wave_sum(s);
    float mean = s * (1.0f / 512.0f);
    float vs = 0.f;
    #pragma unroll
    for (int r = 0; r < 8; ++r) { float d = v[r] - mean; vs += d * d; }
    vs = wave_sum(vs);
    float rstd = rsqrtf(vs * (1.0f / 512.0f) + 1e-5f);
    #pragma unroll
    for (int r = 0; r < 8; ++r) {
        int d = lane + r * 64;
        float o = (v[r] - mean) * rstd * g[d] + b[d];
        if (outF) outF[(size_t)row * D_ + d] = o;
        if (outB) outB[(size_t)row * D_ + d] = f2bf(o);
    }
}

// ---------------- prediction head + broadcast fused (f32 out) ------------------------
__global__ void predbcast_kernel(const float* xemb, const float* Wp, const float* bp,
                                 float* out) {
    int idx = blockIdx.x * blockDim.x + threadIdx.x;   // (n*T+t)*2 + c
    if (idx >= N_ * T_ * 2) return;
    int c = idx & 1;
    int nt = idx >> 1;
    int n = nt / T_, t = nt % T_;
    float acc = bp[c];
    for (int j = 0; j < D_; ++j) acc += xemb[(size_t)nt * D_ + j] * Wp[(size_t)j * 2 + c];
    #pragma unroll
    for (int p = 0; p < NPRED_; ++p)
        out[(((size_t)p * T_ + t) * N_ + n) * 2 + c] = acc;
}

extern "C" void kernel_launch(void* const* d_in, const int* in_sizes, int n_in,
                              void* d_out, int out_size, void* d_ws, size_t ws_size,
                              hipStream_t stream) {
    (void)in_sizes; (void)n_in; (void)out_size; (void)ws_size;

    const float* x    = (const float*)d_in[0];
    const float* nbr  = (const float*)d_in[1];
    const float* attf = (const float*)d_in[2];
    const float* Wx   = (const float*)d_in[3];
    const float* bx   = (const float*)d_in[4];
    const float* Wn   = (const float*)d_in[5];
    const float* bn   = (const float*)d_in[6];
    const float* Wp   = (const float*)d_in[7];
    const float* bp   = (const float*)d_in[8];
    const float* WQ   = (const float*)d_in[9];
    const float* WK   = (const float*)d_in[10];
    const float* WV   = (const float*)d_in[11];
    const float* Wfc  = (const float*)d_in[12];
    const float* mlng = (const float*)d_in[13];
    const float* mlnb = (const float*)d_in[14];
    const float* WSI  = (const float*)d_in[15];
    const float* fsw1 = (const float*)d_in[16];
    const float* fsw2 = (const float*)d_in[17];
    const float* fsg  = (const float*)d_in[18];
    const float* fsb  = (const float*)d_in[19];
    const float* fiw1 = (const float*)d_in[20];
    const float* fiw2 = (const float*)d_in[21];
    const float* fig  = (const float*)d_in[22];
    const float* fib  = (const float*)d_in[23];

    char* w = (char*)d_ws;
    size_t off = 0;
    auto alloc = [&](size_t bytes) -> void* {
        void* p = w + off;
        off = (off + bytes + 255) & ~(size_t)255;
        return p;
    };
    const size_t MiB = 1024 * 1024;

    const int BM = N_ * NN_;          // 2048 (b,m) pairs
    const int ROWS_I = BM * T_;       // 32768 neighbor rows
    const int CB = 1024;              // bm per chunk (NCH=2, l=0 only)
    const int RC = CB * T_;           // 16384 rows per chunk
    const int NCH = ROWS_I / RC;      // 2

    float* pe      = (float*)alloc((size_t)T_ * D_ * 4);
    float* xemb    = (float*)alloc((size_t)N_ * T_ * D_ * 4);
    float* nf      = (float*)alloc((size_t)T_ * N_ * NN_ * 3 * 4);
    float* maskf   = (float*)alloc((size_t)BM * T_ * 4);
    u16*   Ab      = (u16*)alloc((size_t)ROWS_I * D_ * 2);     // n_emb bf16  32 MiB
    u16* tQKV[2], *tWSI[2], *tfs1[2], *tfs2[2];
    for (int l = 0; l < 2; ++l) {
        tQKV[l] = (u16*)alloc((size_t)1536 * 512 * 2);
        tWSI[l] = (u16*)alloc((size_t)512 * 4096 * 2);
        tfs1[l] = (u16*)alloc((size_t)2048 * 512 * 2);
        tfs2[l] = (u16*)alloc((size_t)512 * 2048 * 2);
    }
    u16* tWfc = (u16*)alloc((size_t)512 * 512 * 2);
    u16* tfi1 = (u16*)alloc((size_t)2048 * 512 * 2);
    u16* tfi2 = (u16*)alloc((size_t)512 * 2048 * 2);
    // scratch union: l0 chunk: QKVb 48 + ctxb 16 | hid 64 ; l1: QK full 64 MiB
    char* SCR  = (char*)alloc(64 * MiB);
    u16*   QKVb = (u16*)SCR;
    u16*   ctxb = (u16*)(SCR + 48 * MiB);
    u16*   hid  = (u16*)SCR;
    float* Bch  = (float*)alloc((size_t)RC * D_ * 4);  // res_inter chunk f32  32 MiB
    u16*   Bbch = (u16*)alloc((size_t)RC * D_ * 2);    //                      16 MiB
    float* att_sum = (float*)alloc((size_t)N_ * H_ * 256 * 4);
    u16*   sib     = (u16*)alloc((size_t)N_ * T_ * 4096 * 2);  // 8 MiB
    float* xnew    = (float*)alloc((size_t)N_ * T_ * D_ * 4);
    u16*   xnb     = (u16*)alloc((size_t)N_ * T_ * D_ * 2);
    // total ~182 MiB

    // ---- batched weight conversion: 14 jobs, one launch ----
    WJobs jobs;
    int ntiles = 0;
    auto addJob = [&](int idx, const float* src, u16* dst, int K, int N) {
        jobs.j[idx] = {src, dst, K, N, ntiles};
        ntiles += (N >> 5) * (K >> 5);
    };
    addJob(0,  WQ,                            tQKV[0],              512, 512);
    addJob(1,  WK,                            tQKV[0] + 512 * 512,  512, 512);
    addJob(2,  WV,                            tQKV[0] + 1024 * 512, 512, 512);   // dead at l=1
    addJob(3,  WQ + (size_t)512 * 512,        tQKV[1],              512, 512);
    addJob(4,  WK + (size_t)512 * 512,        tQKV[1] + 512 * 512,  512, 512);
    addJob(5,  Wfc,                           tWfc,                 512, 512);
    addJob(6,  WSI,                           tWSI[0],              4096, 512);
    addJob(7,  WSI + (size_t)4096 * 512,      tWSI[1],              4096, 512);
    addJob(8,  fsw1,                          tfs1[0],              512, 2048);
    addJob(9,  fsw1 + (size_t)512 * 2048,     tfs1[1],              512, 2048);
    addJob(10, fsw2,                          tfs2[0],              2048, 512);
    addJob(11, fsw2 + (size_t)2048 * 512,     tfs2[1],              2048, 512);
    addJob(12, fiw1,                          tfi1,                 512, 2048);
    addJob(13, fiw2,                          tfi2,                 2048, 512);
    wconv_all<<<ntiles, 256, 0, stream>>>(jobs, ntiles);

    pe_kernel<<<16, 256, 0, stream>>>(pe);
    xemb_kernel<<<T_ * N_, 256, 0, stream>>>(x, Wx, bx, pe, xemb);
    nbr_kernel<<<(T_ * N_ * NN_ + 255) / 256, 256, 0, stream>>>(x, nbr, nf, maskf);
    nemb_kernel<<<BM * T_, 256, 0, stream>>>(nf, Wn, bn, pe, Ab);

    for (int l = 0; l < L_; ++l) {
        hipMemsetAsync(att_sum, 0, (size_t)N_ * H_ * 256 * 4, stream);
        if (l == 0) {
            for (int c = 0; c < NCH; ++c) {
                u16* Acb = Ab + (size_t)c * RC * D_;
                // QKV fused GEMM: N=1536, 128x128 (1536 blocks)
                gemm_bt<128, 128, 0, 0, 1><<<dim3(12, RC / 128), 256, 0, stream>>>(
                    Acb, tQKV[0], nullptr, QKVb, nullptr, 512, 1536);
                attn_fused_kernel<1, 1536><<<CB, 256, 0, stream>>>(
                    QKVb, maskf, c * CB, att_sum, ctxb);
                // fc + residual(n_emb bf16): N=512, 128x128 (512 blocks, 32 MFMA/wave)
                gemm_bt<128, 128, 3, 1, 0><<<dim3(4, RC / 128), 256, 0, stream>>>(
                    ctxb, tWfc, Bch, nullptr, Acb, 512, 512);
                ln_dual_kernel<<<RC / 4, 256, 0, stream>>>(
                    Bch, mlng, mlnb, Bch, Bbch, RC);         // Bch = res_inter f32
                // ffi1 relu: N=2048, 128x128 (2048 blocks); hid aliases QKVb/ctxb
                gemm_bt<128, 128, 1, 0, 1><<<dim3(16, RC / 128), 256, 0, stream>>>(
                    Bbch, tfi1, nullptr, hid, nullptr, 512, 2048);
                // ffi2 + residual(res_inter), IN-PLACE into Bch: 128x128 (512 blocks)
                gemm_bt<128, 128, 2, 1, 0><<<dim3(4, RC / 128), 256, 0, stream>>>(
                    hid, tfi2, Bch, nullptr, Bch, 2048, 512);
                ln_dual_kernel<<<RC / 4, 256, 0, stream>>>(
                    Bch, fig, fib, nullptr, Acb, RC);        // new n_emb (bf16)
            }
        } else {
            // l=1: unchunked QK (N=1024, ldc=1024; 64 MiB = SCR) + one attn pass
            gemm_bt<128, 128, 0, 0, 1><<<dim3(8, ROWS_I / 128), 256, 0, stream>>>(
                Ab, tQKV[1], nullptr, QKVb, nullptr, 512, 1024);
            attn_fused_kernel<0, 1024><<<BM, 256, 0, stream>>>(
                QKVb, maskf, 0, att_sum, nullptr);
        }

        // ---- self-attention + si + ffs (updates xemb) ----
        siatt_kernel<<<N_ * H_, 256, 0, stream>>>(xemb, att_sum, attf, sib);
        gemm_bt<32, 64, 0, 1, 1><<<dim3(8, 32), 256, 0, stream>>>(
            sib, tWSI[l], xnew, xnb, nullptr, 4096, 512);
        gemm_bt<32, 64, 1, 0, 1><<<dim3(32, 32), 256, 0, stream>>>(
            xnb, tfs1[l], nullptr, hid, nullptr, 512, 2048);
        gemm_bt<32, 64, 2, 1, 0><<<dim3(8, 32), 256, 0, stream>>>(
            hid, tfs2[l], xemb, nullptr, xnew, 2048, 512);
        ln_dual_kernel<<<(N_ * T_) / 4, 256, 0, stream>>>(
            xemb, fsg + l * D_, fsb + l * D_, xemb, nullptr, N_ * T_);
    }

    predbcast_kernel<<<(N_ * T_ * 2 + 255) / 256, 256, 0, stream>>>(
        xemb, Wp, bp, (float*)d_out);
}

// Round 14
// 836.379 us; speedup vs baseline: 58.7647x; 1.0072x over previous
//
#include <hip/hip_runtime.h>
#include <math.h>

// DTYPE COMMITMENTS (evidence-backed): inputs f32, output f32 (rounds 4-13 PASS).
// WS BUDGET: <= ~210 MB decimal; this build ~170 MiB (f32 pre-LN chain dropped).

#define T_ 16
#define N_ 64
#define NN_ 32
#define D_ 512
#define H_ 8
#define DK_ 64
#define DFF_ 2048
#define L_ 2
#define NPRED_ 20

typedef unsigned short u16;
typedef unsigned int u32;
typedef __attribute__((ext_vector_type(8))) short short8;
typedef __attribute__((ext_vector_type(4))) float f32x4;

__device__ __forceinline__ u16 f2bf(float f) {
    u32 u = __float_as_uint(f);
    u32 r = u + 0x7fffu + ((u >> 16) & 1u);
    return (u16)(r >> 16);
}
__device__ __forceinline__ float bfv(u16 v) {
    return __uint_as_float(((u32)v) << 16);
}
__device__ __forceinline__ float ntn(float v) {
    if (isnan(v)) return 0.0f;
    if (isinf(v)) return v > 0.0f ? 3.4028234663852886e38f : -3.4028234663852886e38f;
    return v;
}
__device__ __forceinline__ float wave_sum(float v) {
    #pragma unroll
    for (int o = 32; o > 0; o >>= 1) v += __shfl_xor(v, o, 64);
    return v;
}
// async 16B HBM->LDS: writes ldsbase + lane*16 (wave-uniform base, per-lane gptr)
__device__ __forceinline__ void gload_lds(const u16* g, u16* l) {
    __builtin_amdgcn_global_load_lds(
        (const __attribute__((address_space(1))) u32*)g,
        (__attribute__((address_space(3))) u32*)l, 16, 0, 0);
}

// ============ batched weight convert+transpose: 14 jobs in ONE launch ===============
struct WJob { const float* src; u16* dst; int K; int N; int t0; };
struct WJobs { WJob j[14]; };
__global__ __launch_bounds__(256) void wconv_all(WJobs jobs, int ntiles) {
    int bid = blockIdx.x;
    if (bid >= ntiles) return;
    int ji = 0;
    #pragma unroll 1
    for (int i = 1; i < 14; ++i) if (bid >= jobs.j[i].t0) ji = i;
    const float* in = jobs.j[ji].src;
    u16* out = jobs.j[ji].dst;
    int K = jobs.j[ji].K, N = jobs.j[ji].N;
    int lt = bid - jobs.j[ji].t0;
    int ntx = N >> 5;
    int nb = (lt % ntx) * 32, kb = (lt / ntx) * 32;
    __shared__ float tile[32][33];
    int tx = threadIdx.x & 31, ty = threadIdx.x >> 5;
    #pragma unroll
    for (int r = ty; r < 32; r += 8)
        tile[r][tx] = in[(size_t)(kb + r) * N + nb + tx];
    __syncthreads();
    #pragma unroll
    for (int r = ty; r < 32; r += 8)
        out[(size_t)(nb + r) * K + kb + tx] = f2bf(tile[tx][r]);
}

// ============ MFMA GEMM v3 + XCD-band remap =========================================
// DMA staging + 3-bit XOR chunk swizzle (r9: 0 bank conflicts); XCD remap (r10:
// ffi2 FETCH 140->20 MB). EPI: 0 none, 1 relu, 2 +res f32, 3 +res bf16.
// In-place allowed for EPI=2/3 with Rg==C (same-thread read-then-write).
// Grid (N/TN, M/TM), gridY%8==0 for remap, K%64==0.
template<int TM, int TN, int EPI, int WF32, int WBF16>
__global__ __launch_bounds__(256) void gemm_bt(
    const u16* __restrict__ Ab, const u16* __restrict__ Btb,
    float* __restrict__ Cf, u16* __restrict__ Cb, const void* __restrict__ Rg,
    int K, int ldc)
{
    constexpr int WR = TM / 32, WC = TN / 32;
    constexpr int ITA = TM / 32, ITB = TN / 32;
    __shared__ __align__(16) u16 As[TM][64];
    __shared__ __align__(16) u16 Bs[TN][64];
    int tid = threadIdx.x;
    int lane = tid & 63, wave = tid >> 6;
    int quad = lane >> 4, l16 = lane & 15;
    int wm = (wave >> 1) * (TM / 2), wn = (wave & 1) * (TN / 2);

    int gx = gridDim.x, gy = gridDim.y;
    int bx, by;
    if ((gy & 7) == 0) {
        int id = blockIdx.y * gx + blockIdx.x;
        int xcd = id & 7;
        int slot = id >> 3;
        bx = slot % gx;
        by = xcd * (gy >> 3) + slot / gx;
    } else {
        bx = blockIdx.x;
        by = blockIdx.y;
    }
    size_t row0 = (size_t)by * TM;
    size_t col0 = (size_t)bx * TN;

    f32x4 acc[WR][WC];
    #pragma unroll
    for (int i = 0; i < WR; ++i)
        #pragma unroll
        for (int j = 0; j < WC; ++j)
            acc[i][j] = (f32x4){0.f, 0.f, 0.f, 0.f};

    int srow = lane >> 3;
    int c8 = (lane & 7) ^ srow;
    int h8 = l16 & 7;

    for (int k0 = 0; k0 < K; k0 += 64) {
        __syncthreads();
        #pragma unroll
        for (int it = 0; it < ITA; ++it) {
            int g = wave + it * 4;
            gload_lds(Ab + (row0 + g * 8 + srow) * (size_t)K + k0 + c8 * 8, &As[g * 8][0]);
        }
        #pragma unroll
        for (int it = 0; it < ITB; ++it) {
            int g = wave + it * 4;
            gload_lds(Btb + (col0 + g * 8 + srow) * (size_t)K + k0 + c8 * 8, &Bs[g * 8][0]);
        }
        __syncthreads();
        #pragma unroll
        for (int s = 0; s < 2; ++s) {
            int coff = ((s * 4 + quad) ^ h8) * 8;   // full 3-bit XOR (r9-verified)
            short8 af[WR], bf[WC];
            #pragma unroll
            for (int i = 0; i < WR; ++i)
                af[i] = *(short8*)&As[wm + i * 16 + l16][coff];
            #pragma unroll
            for (int j = 0; j < WC; ++j)
                bf[j] = *(short8*)&Bs[wn + j * 16 + l16][coff];
            #pragma unroll
            for (int i = 0; i < WR; ++i)
                #pragma unroll
                for (int j = 0; j < WC; ++j)
                    acc[i][j] = __builtin_amdgcn_mfma_f32_16x16x32_bf16(
                        af[i], bf[j], acc[i][j], 0, 0, 0);
        }
    }
    // C/D layout (on-target verified): col = lane&15, row = quad*4 + reg
    #pragma unroll
    for (int i = 0; i < WR; ++i)
        #pragma unroll
        for (int j = 0; j < WC; ++j)
            #pragma unroll
            for (int reg = 0; reg < 4; ++reg) {
                size_t row = row0 + wm + i * 16 + quad * 4 + reg;
                size_t col = col0 + wn + j * 16 + l16;
                float v = acc[i][j][reg];
                if (EPI == 2) v += ((const float*)Rg)[row * (size_t)ldc + col];
                if (EPI == 3) v += bfv(((const u16*)Rg)[row * (size_t)ldc + col]);
                if (EPI == 1) v = fmaxf(v, 0.f);
                if (WF32)  Cf[row * (size_t)ldc + col] = v;
                if (WBF16) Cb[row * (size_t)ldc + col] = f2bf(v);
            }
}

// ============ fused attention per (b,m): all-heads phases, 3 barriers ===============
// QKVb: [rows][LD] bf16 (Q 0..511, K 512..1023, V 1024..1535 when CTX; col=h*64+dk).
template<int CTX, int LD>
__global__ __launch_bounds__(256) void attn_fused_kernel(
    const u16* __restrict__ QKVb, const float* __restrict__ maskf, int bm0,
    float* __restrict__ att_sum, u16* __restrict__ ctxb)
{
    __shared__ __align__(16) u16 sQ[16][520];
    __shared__ __align__(16) u16 sK[16][520];
    __shared__ __align__(16) u16 sV[CTX ? 16 : 1][520];
    __shared__ float s_p[H_][16][17];
    int bm_l = blockIdx.x;
    int tid = threadIdx.x;
    int t = tid >> 4, ch = (tid & 15) * 32;
    const u16* base = QKVb + ((size_t)bm_l * T_ + t) * LD;
    #pragma unroll
    for (int c = 0; c < 4; ++c) {
        *(uint4*)&sQ[t][ch + c * 8] = *(const uint4*)(base + ch + c * 8);
        *(uint4*)&sK[t][ch + c * 8] = *(const uint4*)(base + 512 + ch + c * 8);
        if (CTX) *(uint4*)&sV[t][ch + c * 8] = *(const uint4*)(base + 1024 + ch + c * 8);
    }
    __syncthreads();

    int b = (bm0 + bm_l) >> 5;                  // bm = b*NN + m

    #pragma unroll
    for (int r = 0; r < 8; ++r) {
        int h = r;
        int q = (tid >> 4) & 15, k = tid & 15;
        const u32* qu = (const u32*)&sQ[q][0] + h * 32;
        const u32* ku = (const u32*)&sK[k][0] + h * 32;
        float acc = 0.f;
        #pragma unroll
        for (int j = 0; j < 32; ++j) {
            u32 a = qu[j], bb = ku[j];
            acc += bfv((u16)(a & 0xffff)) * bfv((u16)(bb & 0xffff));
            acc += bfv((u16)(a >> 16))    * bfv((u16)(bb >> 16));
        }
        acc *= 0.125f;
        if (maskf[(size_t)(bm0 + bm_l) * T_ + q] == 0.0f) acc = -1e9f;
        s_p[h][q][k] = acc;
    }
    __syncthreads();
    if (tid < 128) {
        int h = tid >> 4, q = tid & 15;
        float mx = -3.4e38f;
        #pragma unroll
        for (int kk = 0; kk < 16; ++kk) mx = fmaxf(mx, s_p[h][q][kk]);
        float e[16], s = 0.f;
        #pragma unroll
        for (int kk = 0; kk < 16; ++kk) { e[kk] = expf(s_p[h][q][kk] - mx); s += e[kk]; }
        float inv = 1.0f / s;
        #pragma unroll
        for (int kk = 0; kk < 16; ++kk) s_p[h][q][kk] = e[kk] * inv;
    }
    __syncthreads();
    #pragma unroll
    for (int r = 0; r < 8; ++r) {
        int h = r;
        int q = (tid >> 4) & 15, k = tid & 15;
        atomicAdd(&att_sum[(((size_t)b * H_ + h) * T_ + q) * T_ + k], s_p[h][q][k]);
    }
    if (CTX) {
        #pragma unroll
        for (int rep = 0; rep < 32; ++rep) {
            int i = rep * 256 + tid;            // t*512 + c, c = h*64+dk
            int tt = i >> 9, c = i & 511;
            int h = c >> 6;
            float acc = 0.f;
            #pragma unroll
            for (int kk = 0; kk < 16; ++kk)
                acc += s_p[h][tt][kk] * bfv(sV[kk][c]);
            ctxb[((size_t)bm_l * T_ + tt) * D_ + c] = f2bf(acc);
        }
    }
}

// ============ fused self-attention + combine + si, one block per (n,h) ==============
__global__ __launch_bounds__(256) void siatt_kernel(
    const float* __restrict__ xemb, const float* __restrict__ att_sum,
    const float* __restrict__ attf, u16* __restrict__ sib)
{
    __shared__ float sX[16][516];
    __shared__ float sS[16][17];
    __shared__ float sA[16][17];
    int n = blockIdx.x >> 3, h = blockIdx.x & 7;
    int tid = threadIdx.x;
    int t = tid >> 4, ch = (tid & 15) * 32;
    const float* src = xemb + ((size_t)n * T_ + t) * D_;
    #pragma unroll
    for (int c = 0; c < 8; ++c)
        *(float4*)&sX[t][ch + c * 4] = *(const float4*)(src + ch + c * 4);
    __syncthreads();
    int q = tid >> 4, k = tid & 15;
    {
        float acc = 0.f;
        for (int d = 0; d < D_; ++d) acc += sX[q][d] * sX[k][d];
        sS[q][k] = acc * 0.04419417382415922f;
    }
    __syncthreads();
    if (tid < T_) {
        float mx = -3.4e38f;
        #pragma unroll
        for (int kk = 0; kk < 16; ++kk) mx = fmaxf(mx, sS[tid][kk]);
        float e[16], s = 0.f;
        #pragma unroll
        for (int kk = 0; kk < 16; ++kk) { e[kk] = expf(sS[tid][kk] - mx); s += e[kk]; }
        float inv = 1.0f / s;
        #pragma unroll
        for (int kk = 0; kk < 16; ++kk) sS[tid][kk] = e[kk] * inv;
    }
    __syncthreads();
    float f = attf[0] * (1.0f / 32.0f);
    sA[q][k] = sS[q][k] + f * att_sum[((size_t)n * H_ + h) * 256 + q * 16 + k];
    __syncthreads();
    #pragma unroll
    for (int rep = 0; rep < 32; ++rep) {
        int i = rep * 256 + tid;          // q*512 + d
        int qq = i >> 9, d = i & 511;
        float acc = 0.f;
        #pragma unroll
        for (int tt = 0; tt < 16; ++tt) acc += sA[qq][tt] * sX[tt][d];
        sib[(size_t)n * T_ * 4096 + (size_t)qq * 4096 + h * 512 + d] = f2bf(acc);
    }
}

// ---------------- positional encoding ------------------------------------------------
__global__ void pe_kernel(float* pe) {
    int i = blockIdx.x * blockDim.x + threadIdx.x;
    if (i >= T_ * 256) return;
    int t = i >> 8, j = i & 255;
    float dv = (float)pow(10000.0, (double)j / 256.0);
    float a = (float)t * dv;
    double ad = (double)a;
    pe[t * D_ + 2 * j]     = (float)sin(ad);
    pe[t * D_ + 2 * j + 1] = (float)cos(ad);
}

// ---------------- x features + embed -------------------------------------------------
__global__ void xemb_kernel(const float* x, const float* Wx, const float* bx,
                            const float* pe, float* xemb) {
    int row = blockIdx.x;              // t*N + n
    int t = row / N_, n = row % N_;
    float x0 = x[row * 6 + 0], x1 = x[row * 6 + 1];
    float x2 = x[row * 6 + 2], x3 = x[row * 6 + 3];
    float x4 = x[row * 6 + 4], x5 = x[row * 6 + 5];
    float vel = sqrtf(x2 * x2 + x3 * x3);
    float ang = atanf(x5 / x4);
    float f0 = ntn(x0), f1 = ntn(x1), f2 = ntn(vel), f3 = ntn(ang);
    for (int d = threadIdx.x; d < D_; d += blockDim.x) {
        xemb[((size_t)n * T_ + t) * D_ + d] =
            f0 * Wx[0 * D_ + d] + f1 * Wx[1 * D_ + d]
          + f2 * Wx[2 * D_ + d] + f3 * Wx[3 * D_ + d]
          + bx[d] + pe[t * D_ + d];
    }
}

// ---------------- neighbor features + mask -------------------------------------------
__global__ void nbr_kernel(const float* x, const float* nbr, float* nf, float* maskf) {
    int idx = blockIdx.x * blockDim.x + threadIdx.x;   // t*N*NN + n*NN + m
    if (idx >= T_ * N_ * NN_) return;
    int m = idx % NN_;
    int tn = idx / NN_;
    int n = tn % N_, t = tn / N_;
    float px = x[((size_t)t * N_ + n) * 6 + 0];
    float py = x[((size_t)t * N_ + n) * 6 + 1];
    float vx, vy;
    if (t == 0) {
        vx = x[((size_t)1 * N_ + n) * 6 + 2];
        vy = x[((size_t)1 * N_ + n) * 6 + 3];
    } else {
        vx = px - x[((size_t)(t - 1) * N_ + n) * 6 + 0];
        vy = py - x[((size_t)(t - 1) * N_ + n) * 6 + 1];
    }
    float nx  = nbr[(size_t)idx * 4 + 0], ny  = nbr[(size_t)idx * 4 + 1];
    float nvx = nbr[(size_t)idx * 4 + 2], nvy = nbr[(size_t)idx * 4 + 3];
    float dpx = nx - px, dpy = ny - py;
    float dvx = nvx - vx, dvy = nvy - vy;
    float dist = sqrtf(dpx * dpx + dpy * dpy);
    maskf[((size_t)n * NN_ + m) * T_ + t] = (dist <= 2.0f) ? 1.0f : 0.0f;
    float vn = sqrtf(vx * vx + vy * vy);
    float bearing = (dpx * vx + dpy * vy) / (dist * vn);
    if (isnan(bearing)) bearing = 0.0f;
    float dvn = sqrtf(dvx * dvx + dvy * dvy);
    float tau = -(dpx * dvx + dpy * dvy) / dvn;
    if (isnan(tau)) tau = 0.0f;
    tau = fminf(fmaxf(tau, 0.0f), 7.0f);
    float mx_ = dpx + tau * dvx, my_ = dpy + tau * dvy;
    float mpd = sqrtf(mx_ * mx_ + my_ * my_);
    nf[(size_t)idx * 3 + 0] = ntn(dist);
    nf[(size_t)idx * 3 + 1] = ntn(bearing);
    nf[(size_t)idx * 3 + 2] = ntn(mpd);
}

// ---------------- neighbor embed: bf16 n_emb only ------------------------------------
__global__ void nemb_kernel(const float* nf, const float* Wn, const float* bn,
                            const float* pe, u16* Ab) {
    int row = blockIdx.x;              // (b*NN+m)*T + t
    int t = row % T_;
    int bm = row / T_;
    int m = bm % NN_, b = bm / NN_;
    size_t nfrow = (((size_t)t * N_ + b) * NN_ + m) * 3;
    float f0 = nf[nfrow], f1 = nf[nfrow + 1], f2 = nf[nfrow + 2];
    for (int d = threadIdx.x; d < D_; d += blockDim.x) {
        float v = f0 * Wn[d] + f1 * Wn[D_ + d] + f2 * Wn[2 * D_ + d]
                + bn[d] + pe[t * D_ + d];
        Ab[(size_t)row * D_ + d] = f2bf(v);
    }
}

// ---------------- LayerNorm, one wave per row; input f32 or bf16; dual out -----------
template<int INBF>
__global__ __launch_bounds__(256) void ln_kernel(
    const void* X, const float* g, const float* b, float* outF, u16* outB, int nrows) {
    int row = blockIdx.x * 4 + (threadIdx.x >> 6);
    if (row >= nrows) return;
    int lane = threadIdx.x & 63;
    float v[8];
    float s = 0.f;
    #pragma unroll
    for (int r = 0; r < 8; ++r) {
        int d = lane + r * 64;
        v[r] = INBF ? bfv(((const u16*)X)[(size_t)row * D_ + d])
                    : ((const float*)X)[(size_t)row * D_ + d];
        s += v[r];
    }
    s = wave_sum(s);
    float mean = s * (1.0f / 512.0f);
    float vs = 0.f;
    #pragma unroll
    for (int r = 0; r < 8; ++r) { float d = v[r] - mean; vs += d * d; }
    vs = wave_sum(vs);
    float rstd = rsqrtf(vs * (1.0f / 512.0f) + 1e-5f);
    #pragma unroll
    for (int r = 0; r < 8; ++r) {
        int d = lane + r * 64;
        float o = (v[r] - mean) * rstd * g[d] + b[d];
        if (outF) outF[(size_t)row * D_ + d] = o;
        if (outB) outB[(size_t)row * D_ + d] = f2bf(o);
    }
}

// ---------------- prediction head + broadcast fused (f32 out) ------------------------
__global__ void predbcast_kernel(const float* xemb, const float* Wp, const float* bp,
                                 float* out) {
    int idx = blockIdx.x * blockDim.x + threadIdx.x;   // (n*T+t)*2 + c
    if (idx >= N_ * T_ * 2) return;
    int c = idx & 1;
    int nt = idx >> 1;
    int n = nt / T_, t = nt % T_;
    float acc = bp[c];
    for (int j = 0; j < D_; ++j) acc += xemb[(size_t)nt * D_ + j] * Wp[(size_t)j * 2 + c];
    #pragma unroll
    for (int p = 0; p < NPRED_; ++p)
        out[(((size_t)p * T_ + t) * N_ + n) * 2 + c] = acc;
}

extern "C" void kernel_launch(void* const* d_in, const int* in_sizes, int n_in,
                              void* d_out, int out_size, void* d_ws, size_t ws_size,
                              hipStream_t stream) {
    (void)in_sizes; (void)n_in; (void)out_size; (void)ws_size;

    const float* x    = (const float*)d_in[0];
    const float* nbr  = (const float*)d_in[1];
    const float* attf = (const float*)d_in[2];
    const float* Wx   = (const float*)d_in[3];
    const float* bx   = (const float*)d_in[4];
    const float* Wn   = (const float*)d_in[5];
    const float* bn   = (const float*)d_in[6];
    const float* Wp   = (const float*)d_in[7];
    const float* bp   = (const float*)d_in[8];
    const float* WQ   = (const float*)d_in[9];
    const float* WK   = (const float*)d_in[10];
    const float* WV   = (const float*)d_in[11];
    const float* Wfc  = (const float*)d_in[12];
    const float* mlng = (const float*)d_in[13];
    const float* mlnb = (const float*)d_in[14];
    const float* WSI  = (const float*)d_in[15];
    const float* fsw1 = (const float*)d_in[16];
    const float* fsw2 = (const float*)d_in[17];
    const float* fsg  = (const float*)d_in[18];
    const float* fsb  = (const float*)d_in[19];
    const float* fiw1 = (const float*)d_in[20];
    const float* fiw2 = (const float*)d_in[21];
    const float* fig  = (const float*)d_in[22];
    const float* fib  = (const float*)d_in[23];

    char* w = (char*)d_ws;
    size_t off = 0;
    auto alloc = [&](size_t bytes) -> void* {
        void* p = w + off;
        off = (off + bytes + 255) & ~(size_t)255;
        return p;
    };
    const size_t MiB = 1024 * 1024;

    const int BM = N_ * NN_;          // 2048 (b,m) pairs
    const int ROWS_I = BM * T_;       // 32768 neighbor rows
    const int CB = 1024;              // bm per chunk (NCH=2, l=0 only)
    const int RC = CB * T_;           // 16384 rows per chunk
    const int NCH = ROWS_I / RC;      // 2

    float* pe      = (float*)alloc((size_t)T_ * D_ * 4);
    float* xemb    = (float*)alloc((size_t)N_ * T_ * D_ * 4);
    float* nf      = (float*)alloc((size_t)T_ * N_ * NN_ * 3 * 4);
    float* maskf   = (float*)alloc((size_t)BM * T_ * 4);
    u16*   Ab      = (u16*)alloc((size_t)ROWS_I * D_ * 2);     // n_emb bf16  32 MiB
    u16* tQKV[2], *tWSI[2], *tfs1[2], *tfs2[2];
    for (int l = 0; l < 2; ++l) {
        tQKV[l] = (u16*)alloc((size_t)1536 * 512 * 2);
        tWSI[l] = (u16*)alloc((size_t)512 * 4096 * 2);
        tfs1[l] = (u16*)alloc((size_t)2048 * 512 * 2);
        tfs2[l] = (u16*)alloc((size_t)512 * 2048 * 2);
    }
    u16* tWfc = (u16*)alloc((size_t)512 * 512 * 2);
    u16* tfi1 = (u16*)alloc((size_t)2048 * 512 * 2);
    u16* tfi2 = (u16*)alloc((size_t)512 * 2048 * 2);
    // scratch union: l0 chunk: QKVb 48 + ctxb 16 | hid 64 ; l1: QK full 64 MiB
    char* SCR  = (char*)alloc(64 * MiB);
    u16*   QKVb = (u16*)SCR;
    u16*   ctxb = (u16*)(SCR + 48 * MiB);
    u16*   hid  = (u16*)SCR;
    u16*   BbA    = (u16*)alloc((size_t)RC * D_ * 2);  // pre-LN bf16 chunk    16 MiB
    u16*   Bb_res = (u16*)alloc((size_t)RC * D_ * 2);  // res_inter bf16       16 MiB
    float* att_sum = (float*)alloc((size_t)N_ * H_ * 256 * 4);
    u16*   sib     = (u16*)alloc((size_t)N_ * T_ * 4096 * 2);  // 8 MiB
    float* xnew    = (float*)alloc((size_t)N_ * T_ * D_ * 4);
    u16*   xnb     = (u16*)alloc((size_t)N_ * T_ * D_ * 2);
    // total ~170 MiB

    // ---- batched weight conversion: 14 jobs, one launch ----
    WJobs jobs;
    int ntiles = 0;
    auto addJob = [&](int idx, const float* src, u16* dst, int K, int N) {
        jobs.j[idx] = {src, dst, K, N, ntiles};
        ntiles += (N >> 5) * (K >> 5);
    };
    addJob(0,  WQ,                            tQKV[0],              512, 512);
    addJob(1,  WK,                            tQKV[0] + 512 * 512,  512, 512);
    addJob(2,  WV,                            tQKV[0] + 1024 * 512, 512, 512);   // dead at l=1
    addJob(3,  WQ + (size_t)512 * 512,        tQKV[1],              512, 512);
    addJob(4,  WK + (size_t)512 * 512,        tQKV[1] + 512 * 512,  512, 512);
    addJob(5,  Wfc,                           tWfc,                 512, 512);
    addJob(6,  WSI,                           tWSI[0],              4096, 512);
    addJob(7,  WSI + (size_t)4096 * 512,      tWSI[1],              4096, 512);
    addJob(8,  fsw1,                          tfs1[0],              512, 2048);
    addJob(9,  fsw1 + (size_t)512 * 2048,     tfs1[1],              512, 2048);
    addJob(10, fsw2,                          tfs2[0],              2048, 512);
    addJob(11, fsw2 + (size_t)2048 * 512,     tfs2[1],              2048, 512);
    addJob(12, fiw1,                          tfi1,                 512, 2048);
    addJob(13, fiw2,                          tfi2,                 2048, 512);
    wconv_all<<<ntiles, 256, 0, stream>>>(jobs, ntiles);

    pe_kernel<<<16, 256, 0, stream>>>(pe);
    xemb_kernel<<<T_ * N_, 256, 0, stream>>>(x, Wx, bx, pe, xemb);
    nbr_kernel<<<(T_ * N_ * NN_ + 255) / 256, 256, 0, stream>>>(x, nbr, nf, maskf);
    nemb_kernel<<<BM * T_, 256, 0, stream>>>(nf, Wn, bn, pe, Ab);

    for (int l = 0; l < L_; ++l) {
        hipMemsetAsync(att_sum, 0, (size_t)N_ * H_ * 256 * 4, stream);
        if (l == 0) {
            for (int c = 0; c < NCH; ++c) {
                u16* Acb = Ab + (size_t)c * RC * D_;
                // QKV fused GEMM: N=1536, 128x128 (1536 blocks)
                gemm_bt<128, 128, 0, 0, 1><<<dim3(12, RC / 128), 256, 0, stream>>>(
                    Acb, tQKV[0], nullptr, QKVb, nullptr, 512, 1536);
                attn_fused_kernel<1, 1536><<<CB, 256, 0, stream>>>(
                    QKVb, maskf, c * CB, att_sum, ctxb);
                // fc + residual(n_emb bf16) -> pre-LN bf16 (saves f32 round trip)
                gemm_bt<128, 128, 3, 0, 1><<<dim3(4, RC / 128), 256, 0, stream>>>(
                    ctxb, tWfc, nullptr, BbA, Acb, 512, 512);
                ln_kernel<1><<<RC / 4, 256, 0, stream>>>(
                    BbA, mlng, mlnb, nullptr, Bb_res, RC);   // res_inter bf16
                // ffi1 relu: N=2048, 128x128 (2048 blocks); hid aliases QKVb/ctxb
                gemm_bt<128, 128, 1, 0, 1><<<dim3(16, RC / 128), 256, 0, stream>>>(
                    Bb_res, tfi1, nullptr, hid, nullptr, 512, 2048);
                // ffi2 + residual(res_inter bf16) -> pre-LN bf16
                gemm_bt<128, 128, 3, 0, 1><<<dim3(4, RC / 128), 256, 0, stream>>>(
                    hid, tfi2, nullptr, BbA, Bb_res, 2048, 512);
                ln_kernel<1><<<RC / 4, 256, 0, stream>>>(
                    BbA, fig, fib, nullptr, Acb, RC);        // new n_emb (bf16)
            }
        } else {
            // l=1: unchunked QK (N=1024, ldc=1024; 64 MiB = SCR) + one attn pass
            gemm_bt<128, 128, 0, 0, 1><<<dim3(8, ROWS_I / 128), 256, 0, stream>>>(
                Ab, tQKV[1], nullptr, QKVb, nullptr, 512, 1024);
            attn_fused_kernel<0, 1024><<<BM, 256, 0, stream>>>(
                QKVb, maskf, 0, att_sum, nullptr);
        }

        // ---- self-attention + si + ffs (updates xemb; f32 chain unchanged) ----
        siatt_kernel<<<N_ * H_, 256, 0, stream>>>(xemb, att_sum, attf, sib);
        gemm_bt<32, 64, 0, 1, 1><<<dim3(8, 32), 256, 0, stream>>>(
            sib, tWSI[l], xnew, xnb, nullptr, 4096, 512);
        gemm_bt<32, 64, 1, 0, 1><<<dim3(32, 32), 256, 0, stream>>>(
            xnb, tfs1[l], nullptr, hid, nullptr, 512, 2048);
        gemm_bt<32, 64, 2, 1, 0><<<dim3(8, 32), 256, 0, stream>>>(
            hid, tfs2[l], xemb, nullptr, xnew, 2048, 512);
        ln_kernel<0><<<(N_ * T_) / 4, 256, 0, stream>>>(
            xemb, fsg + l * D_, fsb + l * D_, xemb, nullptr, N_ * T_);
    }

    predbcast_kernel<<<(N_ * T_ * 2 + 255) / 256, 256, 0, stream>>>(
        xemb, Wp, bp, (float*)d_out);
}

// Round 15
// 826.805 us; speedup vs baseline: 59.4452x; 1.0116x over previous
//
#include <hip/hip_runtime.h>
#include <math.h>

// DTYPE COMMITMENTS (evidence-backed): inputs f32, output f32 (rounds 4-14 PASS).
// WS BUDGET: <= ~210 MB decimal; this build ~170 MiB.

#define T_ 16
#define N_ 64
#define NN_ 32
#define D_ 512
#define H_ 8
#define DK_ 64
#define DFF_ 2048
#define L_ 2
#define NPRED_ 20

typedef unsigned short u16;
typedef unsigned int u32;
typedef __attribute__((ext_vector_type(8))) short short8;
typedef __attribute__((ext_vector_type(4))) float f32x4;

__device__ __forceinline__ u16 f2bf(float f) {
    u32 u = __float_as_uint(f);
    u32 r = u + 0x7fffu + ((u >> 16) & 1u);
    return (u16)(r >> 16);
}
__device__ __forceinline__ float bfv(u16 v) {
    return __uint_as_float(((u32)v) << 16);
}
__device__ __forceinline__ float ntn(float v) {
    if (isnan(v)) return 0.0f;
    if (isinf(v)) return v > 0.0f ? 3.4028234663852886e38f : -3.4028234663852886e38f;
    return v;
}
__device__ __forceinline__ float wave_sum(float v) {
    #pragma unroll
    for (int o = 32; o > 0; o >>= 1) v += __shfl_xor(v, o, 64);
    return v;
}
// async 16B HBM->LDS: writes ldsbase + lane*16 (wave-uniform base, per-lane gptr)
__device__ __forceinline__ void gload_lds(const u16* g, u16* l) {
    __builtin_amdgcn_global_load_lds(
        (const __attribute__((address_space(1))) u32*)g,
        (__attribute__((address_space(3))) u32*)l, 16, 0, 0);
}

// ============ batched weight convert+transpose: 14 jobs in ONE launch ===============
struct WJob { const float* src; u16* dst; int K; int N; int t0; };
struct WJobs { WJob j[14]; };
__global__ __launch_bounds__(256) void wconv_all(WJobs jobs, int ntiles) {
    int bid = blockIdx.x;
    if (bid >= ntiles) return;
    int ji = 0;
    #pragma unroll 1
    for (int i = 1; i < 14; ++i) if (bid >= jobs.j[i].t0) ji = i;
    const float* in = jobs.j[ji].src;
    u16* out = jobs.j[ji].dst;
    int K = jobs.j[ji].K, N = jobs.j[ji].N;
    int lt = bid - jobs.j[ji].t0;
    int ntx = N >> 5;
    int nb = (lt % ntx) * 32, kb = (lt / ntx) * 32;
    __shared__ float tile[32][33];
    int tx = threadIdx.x & 31, ty = threadIdx.x >> 5;
    #pragma unroll
    for (int r = ty; r < 32; r += 8)
        tile[r][tx] = in[(size_t)(kb + r) * N + nb + tx];
    __syncthreads();
    #pragma unroll
    for (int r = ty; r < 32; r += 8)
        out[(size_t)(nb + r) * K + kb + tx] = f2bf(tile[tx][r]);
}

// ============ MFMA GEMM v3 + XCD-band remap =========================================
// DMA staging + 3-bit XOR chunk swizzle (r9: 0 bank conflicts); XCD remap (r10:
// ffi2 FETCH 140->20 MB). EPI: 0 none, 1 relu, 2 +res f32, 3 +res bf16.
// In-place allowed for EPI=2/3 with Rg==C (same-thread read-then-write).
// Grid (N/TN, M/TM), gridY%8==0 for remap, K%64==0.
template<int TM, int TN, int EPI, int WF32, int WBF16>
__global__ __launch_bounds__(256) void gemm_bt(
    const u16* __restrict__ Ab, const u16* __restrict__ Btb,
    float* __restrict__ Cf, u16* __restrict__ Cb, const void* __restrict__ Rg,
    int K, int ldc)
{
    constexpr int WR = TM / 32, WC = TN / 32;
    constexpr int ITA = TM / 32, ITB = TN / 32;
    __shared__ __align__(16) u16 As[TM][64];
    __shared__ __align__(16) u16 Bs[TN][64];
    int tid = threadIdx.x;
    int lane = tid & 63, wave = tid >> 6;
    int quad = lane >> 4, l16 = lane & 15;
    int wm = (wave >> 1) * (TM / 2), wn = (wave & 1) * (TN / 2);

    int gx = gridDim.x, gy = gridDim.y;
    int bx, by;
    if ((gy & 7) == 0) {
        int id = blockIdx.y * gx + blockIdx.x;
        int xcd = id & 7;
        int slot = id >> 3;
        bx = slot % gx;
        by = xcd * (gy >> 3) + slot / gx;
    } else {
        bx = blockIdx.x;
        by = blockIdx.y;
    }
    size_t row0 = (size_t)by * TM;
    size_t col0 = (size_t)bx * TN;

    f32x4 acc[WR][WC];
    #pragma unroll
    for (int i = 0; i < WR; ++i)
        #pragma unroll
        for (int j = 0; j < WC; ++j)
            acc[i][j] = (f32x4){0.f, 0.f, 0.f, 0.f};

    int srow = lane >> 3;
    int c8 = (lane & 7) ^ srow;
    int h8 = l16 & 7;

    for (int k0 = 0; k0 < K; k0 += 64) {
        __syncthreads();
        #pragma unroll
        for (int it = 0; it < ITA; ++it) {
            int g = wave + it * 4;
            gload_lds(Ab + (row0 + g * 8 + srow) * (size_t)K + k0 + c8 * 8, &As[g * 8][0]);
        }
        #pragma unroll
        for (int it = 0; it < ITB; ++it) {
            int g = wave + it * 4;
            gload_lds(Btb + (col0 + g * 8 + srow) * (size_t)K + k0 + c8 * 8, &Bs[g * 8][0]);
        }
        __syncthreads();
        #pragma unroll
        for (int s = 0; s < 2; ++s) {
            int coff = ((s * 4 + quad) ^ h8) * 8;   // full 3-bit XOR (r9-verified)
            short8 af[WR], bf[WC];
            #pragma unroll
            for (int i = 0; i < WR; ++i)
                af[i] = *(short8*)&As[wm + i * 16 + l16][coff];
            #pragma unroll
            for (int j = 0; j < WC; ++j)
                bf[j] = *(short8*)&Bs[wn + j * 16 + l16][coff];
            #pragma unroll
            for (int i = 0; i < WR; ++i)
                #pragma unroll
                for (int j = 0; j < WC; ++j)
                    acc[i][j] = __builtin_amdgcn_mfma_f32_16x16x32_bf16(
                        af[i], bf[j], acc[i][j], 0, 0, 0);
        }
    }
    // C/D layout (on-target verified): col = lane&15, row = quad*4 + reg
    #pragma unroll
    for (int i = 0; i < WR; ++i)
        #pragma unroll
        for (int j = 0; j < WC; ++j)
            #pragma unroll
            for (int reg = 0; reg < 4; ++reg) {
                size_t row = row0 + wm + i * 16 + quad * 4 + reg;
                size_t col = col0 + wn + j * 16 + l16;
                float v = acc[i][j][reg];
                if (EPI == 2) v += ((const float*)Rg)[row * (size_t)ldc + col];
                if (EPI == 3) v += bfv(((const u16*)Rg)[row * (size_t)ldc + col]);
                if (EPI == 1) v = fmaxf(v, 0.f);
                if (WF32)  Cf[row * (size_t)ldc + col] = v;
                if (WBF16) Cb[row * (size_t)ldc + col] = f2bf(v);
            }
}

// ============ fused attention per (b,m): all-heads phases, 3 barriers ===============
// QKVb: [rows][LD] bf16 (Q 0..511, K 512..1023, V 1024..1535 when CTX; col=h*64+dk).
// r15: ctx phase vectorized — u32 paired sV reads + u32 ctxb writes (same math/order).
template<int CTX, int LD>
__global__ __launch_bounds__(256) void attn_fused_kernel(
    const u16* __restrict__ QKVb, const float* __restrict__ maskf, int bm0,
    float* __restrict__ att_sum, u16* __restrict__ ctxb)
{
    __shared__ __align__(16) u16 sQ[16][520];
    __shared__ __align__(16) u16 sK[16][520];
    __shared__ __align__(16) u16 sV[CTX ? 16 : 1][520];
    __shared__ float s_p[H_][16][17];
    int bm_l = blockIdx.x;
    int tid = threadIdx.x;
    int t = tid >> 4, ch = (tid & 15) * 32;
    const u16* base = QKVb + ((size_t)bm_l * T_ + t) * LD;
    #pragma unroll
    for (int c = 0; c < 4; ++c) {
        *(uint4*)&sQ[t][ch + c * 8] = *(const uint4*)(base + ch + c * 8);
        *(uint4*)&sK[t][ch + c * 8] = *(const uint4*)(base + 512 + ch + c * 8);
        if (CTX) *(uint4*)&sV[t][ch + c * 8] = *(const uint4*)(base + 1024 + ch + c * 8);
    }
    __syncthreads();

    int b = (bm0 + bm_l) >> 5;                  // bm = b*NN + m

    #pragma unroll
    for (int r = 0; r < 8; ++r) {
        int h = r;
        int q = (tid >> 4) & 15, k = tid & 15;
        const u32* qu = (const u32*)&sQ[q][0] + h * 32;
        const u32* ku = (const u32*)&sK[k][0] + h * 32;
        float acc = 0.f;
        #pragma unroll
        for (int j = 0; j < 32; ++j) {
            u32 a = qu[j], bb = ku[j];
            acc += bfv((u16)(a & 0xffff)) * bfv((u16)(bb & 0xffff));
            acc += bfv((u16)(a >> 16))    * bfv((u16)(bb >> 16));
        }
        acc *= 0.125f;
        if (maskf[(size_t)(bm0 + bm_l) * T_ + q] == 0.0f) acc = -1e9f;
        s_p[h][q][k] = acc;
    }
    __syncthreads();
    if (tid < 128) {
        int h = tid >> 4, q = tid & 15;
        float mx = -3.4e38f;
        #pragma unroll
        for (int kk = 0; kk < 16; ++kk) mx = fmaxf(mx, s_p[h][q][kk]);
        float e[16], s = 0.f;
        #pragma unroll
        for (int kk = 0; kk < 16; ++kk) { e[kk] = expf(s_p[h][q][kk] - mx); s += e[kk]; }
        float inv = 1.0f / s;
        #pragma unroll
        for (int kk = 0; kk < 16; ++kk) s_p[h][q][kk] = e[kk] * inv;
    }
    __syncthreads();
    #pragma unroll
    for (int r = 0; r < 8; ++r) {
        int h = r;
        int q = (tid >> 4) & 15, k = tid & 15;
        atomicAdd(&att_sum[(((size_t)b * H_ + h) * T_ + q) * T_ + k], s_p[h][q][k]);
    }
    if (CTX) {
        // 2 consecutive cols per step: paired u32 sV reads, u32 ctxb writes
        #pragma unroll
        for (int rep = 0; rep < 16; ++rep) {
            int i2 = rep * 256 + tid;           // t*256 + c2, c2 = (h*64+dk)/2
            int tt = i2 >> 8, c2 = i2 & 255;
            int h = c2 >> 5;
            const float* pr = &s_p[h][tt][0];
            float a0 = 0.f, a1 = 0.f;
            #pragma unroll
            for (int kk = 0; kk < 16; ++kk) {
                u32 vv = *((const u32*)&sV[kk][0] + c2);
                float p = pr[kk];
                a0 += p * bfv((u16)(vv & 0xffff));
                a1 += p * bfv((u16)(vv >> 16));
            }
            u32 o = (u32)f2bf(a0) | ((u32)f2bf(a1) << 16);
            *((u32*)(ctxb + ((size_t)bm_l * T_ + tt) * D_) + c2) = o;
        }
    }
}

// ============ fused self-attention + combine + si, one block per (n,h) ==============
// r15: si phase vectorized — 2 d's per step, u32 store (same math/order).
__global__ __launch_bounds__(256) void siatt_kernel(
    const float* __restrict__ xemb, const float* __restrict__ att_sum,
    const float* __restrict__ attf, u16* __restrict__ sib)
{
    __shared__ float sX[16][516];
    __shared__ float sS[16][17];
    __shared__ float sA[16][17];
    int n = blockIdx.x >> 3, h = blockIdx.x & 7;
    int tid = threadIdx.x;
    int t = tid >> 4, ch = (tid & 15) * 32;
    const float* src = xemb + ((size_t)n * T_ + t) * D_;
    #pragma unroll
    for (int c = 0; c < 8; ++c)
        *(float4*)&sX[t][ch + c * 4] = *(const float4*)(src + ch + c * 4);
    __syncthreads();
    int q = tid >> 4, k = tid & 15;
    {
        float acc = 0.f;
        for (int d = 0; d < D_; ++d) acc += sX[q][d] * sX[k][d];
        sS[q][k] = acc * 0.04419417382415922f;
    }
    __syncthreads();
    if (tid < T_) {
        float mx = -3.4e38f;
        #pragma unroll
        for (int kk = 0; kk < 16; ++kk) mx = fmaxf(mx, sS[tid][kk]);
        float e[16], s = 0.f;
        #pragma unroll
        for (int kk = 0; kk < 16; ++kk) { e[kk] = expf(sS[tid][kk] - mx); s += e[kk]; }
        float inv = 1.0f / s;
        #pragma unroll
        for (int kk = 0; kk < 16; ++kk) sS[tid][kk] = e[kk] * inv;
    }
    __syncthreads();
    float f = attf[0] * (1.0f / 32.0f);
    sA[q][k] = sS[q][k] + f * att_sum[((size_t)n * H_ + h) * 256 + q * 16 + k];
    __syncthreads();
    #pragma unroll
    for (int rep = 0; rep < 16; ++rep) {
        int i2 = rep * 256 + tid;          // q*256 + d2
        int qq = i2 >> 8, d2 = (i2 & 255) * 2;
        const float* ar = &sA[qq][0];
        float a0 = 0.f, a1 = 0.f;
        #pragma unroll
        for (int tt = 0; tt < 16; ++tt) {
            float p = ar[tt];
            a0 += p * sX[tt][d2];
            a1 += p * sX[tt][d2 + 1];
        }
        u32 o = (u32)f2bf(a0) | ((u32)f2bf(a1) << 16);
        *((u32*)(sib + (size_t)n * T_ * 4096 + (size_t)qq * 4096 + h * 512) + (d2 >> 1)) = o;
    }
}

// ---------------- positional encoding ------------------------------------------------
__global__ void pe_kernel(float* pe) {
    int i = blockIdx.x * blockDim.x + threadIdx.x;
    if (i >= T_ * 256) return;
    int t = i >> 8, j = i & 255;
    float dv = (float)pow(10000.0, (double)j / 256.0);
    float a = (float)t * dv;
    double ad = (double)a;
    pe[t * D_ + 2 * j]     = (float)sin(ad);
    pe[t * D_ + 2 * j + 1] = (float)cos(ad);
}

// ---------------- x features + embed -------------------------------------------------
__global__ void xemb_kernel(const float* x, const float* Wx, const float* bx,
                            const float* pe, float* xemb) {
    int row = blockIdx.x;              // t*N + n
    int t = row / N_, n = row % N_;
    float x0 = x[row * 6 + 0], x1 = x[row * 6 + 1];
    float x2 = x[row * 6 + 2], x3 = x[row * 6 + 3];
    float x4 = x[row * 6 + 4], x5 = x[row * 6 + 5];
    float vel = sqrtf(x2 * x2 + x3 * x3);
    float ang = atanf(x5 / x4);
    float f0 = ntn(x0), f1 = ntn(x1), f2 = ntn(vel), f3 = ntn(ang);
    for (int d = threadIdx.x; d < D_; d += blockDim.x) {
        xemb[((size_t)n * T_ + t) * D_ + d] =
            f0 * Wx[0 * D_ + d] + f1 * Wx[1 * D_ + d]
          + f2 * Wx[2 * D_ + d] + f3 * Wx[3 * D_ + d]
          + bx[d] + pe[t * D_ + d];
    }
}

// ---------------- neighbor features + mask -------------------------------------------
__global__ void nbr_kernel(const float* x, const float* nbr, float* nf, float* maskf) {
    int idx = blockIdx.x * blockDim.x + threadIdx.x;   // t*N*NN + n*NN + m
    if (idx >= T_ * N_ * NN_) return;
    int m = idx % NN_;
    int tn = idx / NN_;
    int n = tn % N_, t = tn / N_;
    float px = x[((size_t)t * N_ + n) * 6 + 0];
    float py = x[((size_t)t * N_ + n) * 6 + 1];
    float vx, vy;
    if (t == 0) {
        vx = x[((size_t)1 * N_ + n) * 6 + 2];
        vy = x[((size_t)1 * N_ + n) * 6 + 3];
    } else {
        vx = px - x[((size_t)(t - 1) * N_ + n) * 6 + 0];
        vy = py - x[((size_t)(t - 1) * N_ + n) * 6 + 1];
    }
    float nx  = nbr[(size_t)idx * 4 + 0], ny  = nbr[(size_t)idx * 4 + 1];
    float nvx = nbr[(size_t)idx * 4 + 2], nvy = nbr[(size_t)idx * 4 + 3];
    float dpx = nx - px, dpy = ny - py;
    float dvx = nvx - vx, dvy = nvy - vy;
    float dist = sqrtf(dpx * dpx + dpy * dpy);
    maskf[((size_t)n * NN_ + m) * T_ + t] = (dist <= 2.0f) ? 1.0f : 0.0f;
    float vn = sqrtf(vx * vx + vy * vy);
    float bearing = (dpx * vx + dpy * vy) / (dist * vn);
    if (isnan(bearing)) bearing = 0.0f;
    float dvn = sqrtf(dvx * dvx + dvy * dvy);
    float tau = -(dpx * dvx + dpy * dvy) / dvn;
    if (isnan(tau)) tau = 0.0f;
    tau = fminf(fmaxf(tau, 0.0f), 7.0f);
    float mx_ = dpx + tau * dvx, my_ = dpy + tau * dvy;
    float mpd = sqrtf(mx_ * mx_ + my_ * my_);
    nf[(size_t)idx * 3 + 0] = ntn(dist);
    nf[(size_t)idx * 3 + 1] = ntn(bearing);
    nf[(size_t)idx * 3 + 2] = ntn(mpd);
}

// ---------------- neighbor embed: bf16 n_emb only ------------------------------------
__global__ void nemb_kernel(const float* nf, const float* Wn, const float* bn,
                            const float* pe, u16* Ab) {
    int row = blockIdx.x;              // (b*NN+m)*T + t
    int t = row % T_;
    int bm = row / T_;
    int m = bm % NN_, b = bm / NN_;
    size_t nfrow = (((size_t)t * N_ + b) * NN_ + m) * 3;
    float f0 = nf[nfrow], f1 = nf[nfrow + 1], f2 = nf[nfrow + 2];
    for (int d = threadIdx.x; d < D_; d += blockDim.x) {
        float v = f0 * Wn[d] + f1 * Wn[D_ + d] + f2 * Wn[2 * D_ + d]
                + bn[d] + pe[t * D_ + d];
        Ab[(size_t)row * D_ + d] = f2bf(v);
    }
}

// ---------------- LayerNorm, one wave per row; input f32 or bf16; dual out -----------
template<int INBF>
__global__ __launch_bounds__(256) void ln_kernel(
    const void* X, const float* g, const float* b, float* outF, u16* outB, int nrows) {
    int row = blockIdx.x * 4 + (threadIdx.x >> 6);
    if (row >= nrows) return;
    int lane = threadIdx.x & 63;
    float v[8];
    float s = 0.f;
    #pragma unroll
    for (int r = 0; r < 8; ++r) {
        int d = lane + r * 64;
        v[r] = INBF ? bfv(((const u16*)X)[(size_t)row * D_ + d])
                    : ((const float*)X)[(size_t)row * D_ + d];
        s += v[r];
    }
    s = wave_sum(s);
    float mean = s * (1.0f / 512.0f);
    float vs = 0.f;
    #pragma unroll
    for (int r = 0; r < 8; ++r) { float d = v[r] - mean; vs += d * d; }
    vs = wave_sum(vs);
    float rstd = rsqrtf(vs * (1.0f / 512.0f) + 1e-5f);
    #pragma unroll
    for (int r = 0; r < 8; ++r) {
        int d = lane + r * 64;
        float o = (v[r] - mean) * rstd * g[d] + b[d];
        if (outF) outF[(size_t)row * D_ + d] = o;
        if (outB) outB[(size_t)row * D_ + d] = f2bf(o);
    }
}

// ---------------- prediction head + broadcast fused (f32 out) ------------------------
__global__ void predbcast_kernel(const float* xemb, const float* Wp, const float* bp,
                                 float* out) {
    int idx = blockIdx.x * blockDim.x + threadIdx.x;   // (n*T+t)*2 + c
    if (idx >= N_ * T_ * 2) return;
    int c = idx & 1;
    int nt = idx >> 1;
    int n = nt / T_, t = nt % T_;
    float acc = bp[c];
    for (int j = 0; j < D_; ++j) acc += xemb[(size_t)nt * D_ + j] * Wp[(size_t)j * 2 + c];
    #pragma unroll
    for (int p = 0; p < NPRED_; ++p)
        out[(((size_t)p * T_ + t) * N_ + n) * 2 + c] = acc;
}

extern "C" void kernel_launch(void* const* d_in, const int* in_sizes, int n_in,
                              void* d_out, int out_size, void* d_ws, size_t ws_size,
                              hipStream_t stream) {
    (void)in_sizes; (void)n_in; (void)out_size; (void)ws_size;

    const float* x    = (const float*)d_in[0];
    const float* nbr  = (const float*)d_in[1];
    const float* attf = (const float*)d_in[2];
    const float* Wx   = (const float*)d_in[3];
    const float* bx   = (const float*)d_in[4];
    const float* Wn   = (const float*)d_in[5];
    const float* bn   = (const float*)d_in[6];
    const float* Wp   = (const float*)d_in[7];
    const float* bp   = (const float*)d_in[8];
    const float* WQ   = (const float*)d_in[9];
    const float* WK   = (const float*)d_in[10];
    const float* WV   = (const float*)d_in[11];
    const float* Wfc  = (const float*)d_in[12];
    const float* mlng = (const float*)d_in[13];
    const float* mlnb = (const float*)d_in[14];
    const float* WSI  = (const float*)d_in[15];
    const float* fsw1 = (const float*)d_in[16];
    const float* fsw2 = (const float*)d_in[17];
    const float* fsg  = (const float*)d_in[18];
    const float* fsb  = (const float*)d_in[19];
    const float* fiw1 = (const float*)d_in[20];
    const float* fiw2 = (const float*)d_in[21];
    const float* fig  = (const float*)d_in[22];
    const float* fib  = (const float*)d_in[23];

    char* w = (char*)d_ws;
    size_t off = 0;
    auto alloc = [&](size_t bytes) -> void* {
        void* p = w + off;
        off = (off + bytes + 255) & ~(size_t)255;
        return p;
    };
    const size_t MiB = 1024 * 1024;

    const int BM = N_ * NN_;          // 2048 (b,m) pairs
    const int ROWS_I = BM * T_;       // 32768 neighbor rows
    const int CB = 1024;              // bm per chunk (NCH=2, l=0 only)
    const int RC = CB * T_;           // 16384 rows per chunk
    const int NCH = ROWS_I / RC;      // 2

    float* pe      = (float*)alloc((size_t)T_ * D_ * 4);
    float* xemb    = (float*)alloc((size_t)N_ * T_ * D_ * 4);
    float* nf      = (float*)alloc((size_t)T_ * N_ * NN_ * 3 * 4);
    float* maskf   = (float*)alloc((size_t)BM * T_ * 4);
    u16*   Ab      = (u16*)alloc((size_t)ROWS_I * D_ * 2);     // n_emb bf16  32 MiB
    u16* tQKV[2], *tWSI[2], *tfs1[2], *tfs2[2];
    for (int l = 0; l < 2; ++l) {
        tQKV[l] = (u16*)alloc((size_t)1536 * 512 * 2);
        tWSI[l] = (u16*)alloc((size_t)512 * 4096 * 2);
        tfs1[l] = (u16*)alloc((size_t)2048 * 512 * 2);
        tfs2[l] = (u16*)alloc((size_t)512 * 2048 * 2);
    }
    u16* tWfc = (u16*)alloc((size_t)512 * 512 * 2);
    u16* tfi1 = (u16*)alloc((size_t)2048 * 512 * 2);
    u16* tfi2 = (u16*)alloc((size_t)512 * 2048 * 2);
    // scratch union: l0 chunk: QKVb 48 + ctxb 16 | hid 64 ; l1: QK full 64 MiB
    char* SCR  = (char*)alloc(64 * MiB);
    u16*   QKVb = (u16*)SCR;
    u16*   ctxb = (u16*)(SCR + 48 * MiB);
    u16*   hid  = (u16*)SCR;
    u16*   BbA    = (u16*)alloc((size_t)RC * D_ * 2);  // pre-LN bf16 chunk    16 MiB
    u16*   Bb_res = (u16*)alloc((size_t)RC * D_ * 2);  // res_inter bf16       16 MiB
    float* att_sum = (float*)alloc((size_t)N_ * H_ * 256 * 4);
    u16*   sib     = (u16*)alloc((size_t)N_ * T_ * 4096 * 2);  // 8 MiB
    float* xnew    = (float*)alloc((size_t)N_ * T_ * D_ * 4);
    u16*   xnb     = (u16*)alloc((size_t)N_ * T_ * D_ * 2);
    // total ~170 MiB

    // ---- batched weight conversion: 14 jobs, one launch ----
    WJobs jobs;
    int ntiles = 0;
    auto addJob = [&](int idx, const float* src, u16* dst, int K, int N) {
        jobs.j[idx] = {src, dst, K, N, ntiles};
        ntiles += (N >> 5) * (K >> 5);
    };
    addJob(0,  WQ,                            tQKV[0],              512, 512);
    addJob(1,  WK,                            tQKV[0] + 512 * 512,  512, 512);
    addJob(2,  WV,                            tQKV[0] + 1024 * 512, 512, 512);   // dead at l=1
    addJob(3,  WQ + (size_t)512 * 512,        tQKV[1],              512, 512);
    addJob(4,  WK + (size_t)512 * 512,        tQKV[1] + 512 * 512,  512, 512);
    addJob(5,  Wfc,                           tWfc,                 512, 512);
    addJob(6,  WSI,                           tWSI[0],              4096, 512);
    addJob(7,  WSI + (size_t)4096 * 512,      tWSI[1],              4096, 512);
    addJob(8,  fsw1,                          tfs1[0],              512, 2048);
    addJob(9,  fsw1 + (size_t)512 * 2048,     tfs1[1],              512, 2048);
    addJob(10, fsw2,                          tfs2[0],              2048, 512);
    addJob(11, fsw2 + (size_t)2048 * 512,     tfs2[1],              2048, 512);
    addJob(12, fiw1,                          tfi1,                 512, 2048);
    addJob(13, fiw2,                          tfi2,                 2048, 512);
    wconv_all<<<ntiles, 256, 0, stream>>>(jobs, ntiles);

    pe_kernel<<<16, 256, 0, stream>>>(pe);
    xemb_kernel<<<T_ * N_, 256, 0, stream>>>(x, Wx, bx, pe, xemb);
    nbr_kernel<<<(T_ * N_ * NN_ + 255) / 256, 256, 0, stream>>>(x, nbr, nf, maskf);
    nemb_kernel<<<BM * T_, 256, 0, stream>>>(nf, Wn, bn, pe, Ab);

    for (int l = 0; l < L_; ++l) {
        hipMemsetAsync(att_sum, 0, (size_t)N_ * H_ * 256 * 4, stream);
        if (l == 0) {
            for (int c = 0; c < NCH; ++c) {
                u16* Acb = Ab + (size_t)c * RC * D_;
                // QKV fused GEMM: N=1536, 128x128 (1536 blocks)
                gemm_bt<128, 128, 0, 0, 1><<<dim3(12, RC / 128), 256, 0, stream>>>(
                    Acb, tQKV[0], nullptr, QKVb, nullptr, 512, 1536);
                attn_fused_kernel<1, 1536><<<CB, 256, 0, stream>>>(
                    QKVb, maskf, c * CB, att_sum, ctxb);
                // fc + residual(n_emb bf16) -> pre-LN bf16
                gemm_bt<128, 128, 3, 0, 1><<<dim3(4, RC / 128), 256, 0, stream>>>(
                    ctxb, tWfc, nullptr, BbA, Acb, 512, 512);
                ln_kernel<1><<<RC / 4, 256, 0, stream>>>(
                    BbA, mlng, mlnb, nullptr, Bb_res, RC);   // res_inter bf16
                // ffi1 relu: N=2048, 128x128 (2048 blocks); hid aliases QKVb/ctxb
                gemm_bt<128, 128, 1, 0, 1><<<dim3(16, RC / 128), 256, 0, stream>>>(
                    Bb_res, tfi1, nullptr, hid, nullptr, 512, 2048);
                // ffi2 + residual(res_inter bf16) -> pre-LN bf16
                gemm_bt<128, 128, 3, 0, 1><<<dim3(4, RC / 128), 256, 0, stream>>>(
                    hid, tfi2, nullptr, BbA, Bb_res, 2048, 512);
                ln_kernel<1><<<RC / 4, 256, 0, stream>>>(
                    BbA, fig, fib, nullptr, Acb, RC);        // new n_emb (bf16)
            }
        } else {
            // l=1: unchunked QK (N=1024, ldc=1024; 64 MiB = SCR) + one attn pass
            gemm_bt<128, 128, 0, 0, 1><<<dim3(8, ROWS_I / 128), 256, 0, stream>>>(
                Ab, tQKV[1], nullptr, QKVb, nullptr, 512, 1024);
            attn_fused_kernel<0, 1024><<<BM, 256, 0, stream>>>(
                QKVb, maskf, 0, att_sum, nullptr);
        }

        // ---- self-attention + si + ffs (updates xemb; f32 chain unchanged) ----
        siatt_kernel<<<N_ * H_, 256, 0, stream>>>(xemb, att_sum, attf, sib);
        gemm_bt<32, 64, 0, 1, 1><<<dim3(8, 32), 256, 0, stream>>>(
            sib, tWSI[l], xnew, xnb, nullptr, 4096, 512);
        gemm_bt<32, 64, 1, 0, 1><<<dim3(32, 32), 256, 0, stream>>>(
            xnb, tfs1[l], nullptr, hid, nullptr, 512, 2048);
        gemm_bt<32, 64, 2, 1, 0><<<dim3(8, 32), 256, 0, stream>>>(
            hid, tfs2[l], xemb, nullptr, xnew, 2048, 512);
        ln_kernel<0><<<(N_ * T_) / 4, 256, 0, stream>>>(
            xemb, fsg + l * D_, fsb + l * D_, xemb, nullptr, N_ * T_);
    }

    predbcast_kernel<<<(N_ * T_ * 2 + 255) / 256, 256, 0, stream>>>(
        xemb, Wp, bp, (float*)d_out);
}